// Round 2
// baseline (3149.614 us; speedup 1.0000x reference)
//
#include <hip/hip_runtime.h>
#include <hip/hip_bf16.h>

typedef unsigned short u16;
typedef __attribute__((ext_vector_type(8))) short bf16x8;
typedef __attribute__((ext_vector_type(4))) float f32x4;

#define MFMA(a,b,c) __builtin_amdgcn_mfma_f32_16x16x32_bf16((a),(b),(c),0,0,0)

__device__ __forceinline__ float bf2f(u16 u){
  union { float f; unsigned int i; } c; c.i = ((unsigned int)u) << 16; return c.f;
}
__device__ __forceinline__ u16 f2bf(float f){
  __hip_bfloat16 h = __float2bfloat16(f);
  u16 u; __builtin_memcpy(&u, &h, 2); return u;
}
// 8 consecutive f32 -> bf16x8 fragment
__device__ __forceinline__ bf16x8 ld8f(const float* p){
  bf16x8 r;
  #pragma unroll
  for (int i = 0; i < 8; i++) r[i] = (short)f2bf(p[i]);
  return r;
}

// y[N][ystride(=M)] (bf16) = x[N][K=128 (stride xstride)] @ w[M][128]^T + b[M]
// x dtype: XBF ? bf16 : f32. w,b are f32. One block = 64 rows (4 waves x 16).
template<int XBF>
__global__ __launch_bounds__(256) void linear_kernel(
    const void* __restrict__ xA_, const float* __restrict__ wA, const float* __restrict__ bA, u16* __restrict__ yA,
    const void* __restrict__ xB_, const float* __restrict__ wB, const float* __restrict__ bB, u16* __restrict__ yB,
    int xstride, int ystride, int M)
{
  const void* x_ = blockIdx.y ? xB_ : xA_;
  const float* w = blockIdx.y ? wB : wA;
  const float* b = blockIdx.y ? bB : bA;
  u16* y = blockIdx.y ? yB : yA;
  const int lane = threadIdx.x & 63, wid = threadIdx.x >> 6;
  const int g = lane >> 4, l15 = lane & 15;
  const int row0 = blockIdx.x * 64 + wid * 16;

  bf16x8 a[4];
  if (XBF) {
    const u16* xr = (const u16*)x_ + (size_t)(row0 + l15) * xstride;
    #pragma unroll
    for (int kk = 0; kk < 4; kk++) a[kk] = *(const bf16x8*)(xr + kk * 32 + g * 8);
  } else {
    const float* xr = (const float*)x_ + (size_t)(row0 + l15) * xstride;
    #pragma unroll
    for (int kk = 0; kk < 4; kk++) a[kk] = ld8f(xr + kk * 32 + g * 8);
  }

  const f32x4 fz = {0.f, 0.f, 0.f, 0.f};
  for (int j0 = 0; j0 < M; j0 += 16) {
    f32x4 acc = fz;
    const float* wr_ = w + (size_t)(j0 + l15) * 128;
    #pragma unroll
    for (int kk = 0; kk < 4; kk++)
      acc = MFMA(a[kk], ld8f(wr_ + kk * 32 + g * 8), acc);
    float bv = b[j0 + l15];
    #pragma unroll
    for (int r = 0; r < 4; r++)
      y[(size_t)(row0 + g * 4 + r) * ystride + j0 + l15] = f2bf(acc[r] + bv);
  }
}

// vt[128][N] = v[N][128 (row stride vstride)]^T ; bf16; 64x64 tiles via LDS
__global__ __launch_bounds__(256) void transpose_kernel(
    const u16* __restrict__ vA, const u16* __restrict__ vB,
    u16* __restrict__ vtA, u16* __restrict__ vtB, int vstride, int N)
{
  __shared__ __align__(16) u16 t[64][72];
  const u16* v = blockIdx.z ? vB : vA;
  u16* vt = blockIdx.z ? vtB : vtA;
  const int r0 = blockIdx.x * 64, c0 = blockIdx.y * 64;
  const int tid = threadIdx.x;
  #pragma unroll
  for (int i = 0; i < 2; i++) {
    int ch = tid + i * 256; int r = ch >> 3, c = (ch & 7) * 8;
    *(bf16x8*)&t[r][c] = *(const bf16x8*)(v + (size_t)(r0 + r) * vstride + c0 + c);
  }
  __syncthreads();
  const int oc = tid >> 2, rc = (tid & 3) * 16;
  bf16x8 o0, o1;
  #pragma unroll
  for (int i = 0; i < 8; i++) { o0[i] = (short)t[rc + i][oc]; o1[i] = (short)t[rc + 8 + i][oc]; }
  *(bf16x8*)(vt + (size_t)(c0 + oc) * N + r0 + rc) = o0;
  *(bf16x8*)(vt + (size_t)(c0 + oc) * N + r0 + rc + 8) = o1;
}

// Flash attention: q,k interleaved in qkv [N][384] bf16 (q=+0, k=+128), v^T in vt[128][N].
// Block = 64 q-rows (4 waves x 16), KV tile = 64. Online softmax per row in f32.
__global__ __launch_bounds__(256) void flash_kernel(
    const u16* __restrict__ qkvA, const u16* __restrict__ vtA, u16* __restrict__ oA,
    const u16* __restrict__ qkvB, const u16* __restrict__ vtB, u16* __restrict__ oB,
    int N)
{
  __shared__ __align__(16) u16 Kt[64 * 136];
  __shared__ __align__(16) u16 Vtt[128 * 72];
  __shared__ __align__(16) u16 Pl[4 * 16 * 72];
  const u16* qkv = blockIdx.y ? qkvB : qkvA;
  const u16* vt  = blockIdx.y ? vtB  : vtA;
  u16* o = blockIdx.y ? oB : oA;
  const float scale = 0.088388347648318447f; // 1/sqrt(128)
  const int lane = threadIdx.x & 63, wid = threadIdx.x >> 6;
  const int g = lane >> 4, l15 = lane & 15;
  const int row0 = blockIdx.x * 64 + wid * 16;
  const u16* kg = qkv + 128;

  bf16x8 aQ[4];
  const u16* qr = qkv + (size_t)(row0 + l15) * 384;
  #pragma unroll
  for (int kk = 0; kk < 4; kk++) aQ[kk] = *(const bf16x8*)(qr + kk * 32 + g * 8);

  const f32x4 fz = {0.f, 0.f, 0.f, 0.f};
  f32x4 accO[8];
  #pragma unroll
  for (int n = 0; n < 8; n++) accO[n] = fz;
  float m_[4], l_[4];
  #pragma unroll
  for (int r = 0; r < 4; r++) { m_[r] = -INFINITY; l_[r] = 0.f; }

  u16* pw = &Pl[wid * 16 * 72];

  for (int kv0 = 0; kv0 < N; kv0 += 64) {
    #pragma unroll
    for (int i = 0; i < 4; i++) {
      int ch = (int)threadIdx.x + i * 256; int r = ch >> 4, c = (ch & 15) * 8;
      *(bf16x8*)&Kt[r * 136 + c] = *(const bf16x8*)(kg + (size_t)(kv0 + r) * 384 + c);
    }
    #pragma unroll
    for (int i = 0; i < 4; i++) {
      int ch = (int)threadIdx.x + i * 256; int r = ch >> 3, c = (ch & 7) * 8;
      *(bf16x8*)&Vtt[r * 72 + c] = *(const bf16x8*)(vt + (size_t)r * N + kv0 + c);
    }
    __syncthreads();

    f32x4 s[4];
    #pragma unroll
    for (int sb = 0; sb < 4; sb++) {
      s[sb] = fz;
      #pragma unroll
      for (int kk = 0; kk < 4; kk++) {
        bf16x8 bK = *(bf16x8*)&Kt[(sb * 16 + l15) * 136 + (kk * 4 + g) * 8];
        s[sb] = MFMA(aQ[kk], bK, s[sb]);
      }
    }

    float corr[4];
    #pragma unroll
    for (int r = 0; r < 4; r++) {
      float v = fmaxf(fmaxf(s[0][r], s[1][r]), fmaxf(s[2][r], s[3][r]));
      #pragma unroll
      for (int off = 1; off < 16; off <<= 1) v = fmaxf(v, __shfl_xor(v, off));
      float nm = fmaxf(m_[r], v);
      corr[r] = __expf(scale * (m_[r] - nm));
      m_[r] = nm;
      float sum = 0.f;
      #pragma unroll
      for (int sb = 0; sb < 4; sb++) {
        float p = __expf(scale * (s[sb][r] - nm));
        s[sb][r] = p; sum += p;
      }
      #pragma unroll
      for (int off = 1; off < 16; off <<= 1) sum += __shfl_xor(sum, off);
      l_[r] = l_[r] * corr[r] + sum;
    }
    #pragma unroll
    for (int n = 0; n < 8; n++) {
      #pragma unroll
      for (int r = 0; r < 4; r++) accO[n][r] *= corr[r];
    }

    #pragma unroll
    for (int sb = 0; sb < 4; sb++)
      #pragma unroll
      for (int r = 0; r < 4; r++)
        pw[(g * 4 + r) * 72 + sb * 16 + l15] = f2bf(s[sb][r]);
    __syncthreads();

    bf16x8 pA[2];
    #pragma unroll
    for (int kk2 = 0; kk2 < 2; kk2++) pA[kk2] = *(bf16x8*)&pw[l15 * 72 + kk2 * 32 + g * 8];
    #pragma unroll
    for (int n = 0; n < 8; n++) {
      #pragma unroll
      for (int kk2 = 0; kk2 < 2; kk2++) {
        bf16x8 bV = *(bf16x8*)&Vtt[(n * 16 + l15) * 72 + kk2 * 32 + g * 8];
        accO[n] = MFMA(pA[kk2], bV, accO[n]);
      }
    }
    __syncthreads();
  }

  #pragma unroll
  for (int n = 0; n < 8; n++)
    #pragma unroll
    for (int r = 0; r < 4; r++)
      o[(size_t)(row0 + g * 4 + r) * 128 + n * 16 + l15] = f2bf(accO[n][r] / l_[r]);
}

// agg[dst] += h[src] (h bf16) over E edges; 16 threads/edge, 8 f32 atomics each.
__global__ __launch_bounds__(256) void scatter_kernel(
    const u16* __restrict__ h0, const int* __restrict__ e0, float* __restrict__ a0,
    const u16* __restrict__ h1, const int* __restrict__ e1, float* __restrict__ a1,
    const u16* __restrict__ h2, const int* __restrict__ e2, float* __restrict__ a2,
    int E)
{
  const u16* h; const int* ei; float* agg;
  if (blockIdx.y == 0)      { h = h0; ei = e0; agg = a0; }
  else if (blockIdx.y == 1) { h = h1; ei = e1; agg = a1; }
  else                      { h = h2; ei = e2; agg = a2; }
  int tid = blockIdx.x * 256 + threadIdx.x;
  int e = tid >> 4;
  if (e >= E) return;
  int part = (tid & 15) * 8;
  int s = ei[e], d = ei[E + e];
  const u16* hp = h + (size_t)s * 128 + part;
  float* ap = agg + (size_t)d * 128 + part;
  bf16x8 hv = *(const bf16x8*)hp;
  #pragma unroll
  for (int i = 0; i < 8; i++)
    unsafeAtomicAdd(ap + i, bf2f((u16)hv[i]));
}

// out[:,0,:] (f32, row stride 768) = agg1@wl1^T + bl1 + h1@wr1^T (+ agg2@wl2^T + bl2 + h2@wr2^T)
__global__ __launch_bounds__(256) void sage_out_kernel(
    const float* __restrict__ agg1, const float* __restrict__ wl1, const float* __restrict__ bl1,
    const u16* __restrict__ h1, const float* __restrict__ wr1,
    const float* __restrict__ agg2, const float* __restrict__ wl2, const float* __restrict__ bl2,
    const u16* __restrict__ h2, const float* __restrict__ wr2,
    float* __restrict__ out)
{
  const int lane = threadIdx.x & 63, wid = threadIdx.x >> 6;
  const int g = lane >> 4, l15 = lane & 15;
  const int row0 = blockIdx.x * 64 + wid * 16;
  const bool two = (agg2 != nullptr);

  bf16x8 a1[4], aH1[4], a2[4], aH2[4];
  const float* ar1 = agg1 + (size_t)(row0 + l15) * 128;
  const u16* hr1 = h1 + (size_t)(row0 + l15) * 128;
  #pragma unroll
  for (int kk = 0; kk < 4; kk++) {
    a1[kk] = ld8f(ar1 + kk * 32 + g * 8);
    aH1[kk] = *(const bf16x8*)(hr1 + kk * 32 + g * 8);
  }
  if (two) {
    const float* ar2 = agg2 + (size_t)(row0 + l15) * 128;
    const u16* hr2 = h2 + (size_t)(row0 + l15) * 128;
    #pragma unroll
    for (int kk = 0; kk < 4; kk++) {
      a2[kk] = ld8f(ar2 + kk * 32 + g * 8);
      aH2[kk] = *(const bf16x8*)(hr2 + kk * 32 + g * 8);
    }
  }

  const f32x4 fz = {0.f, 0.f, 0.f, 0.f};
  for (int j0 = 0; j0 < 128; j0 += 16) {
    f32x4 acc = fz;
    const float* w1 = wl1 + (size_t)(j0 + l15) * 128;
    const float* w2 = wr1 + (size_t)(j0 + l15) * 128;
    #pragma unroll
    for (int kk = 0; kk < 4; kk++) {
      acc = MFMA(a1[kk], ld8f(w1 + kk * 32 + g * 8), acc);
      acc = MFMA(aH1[kk], ld8f(w2 + kk * 32 + g * 8), acc);
    }
    float bias = bl1[j0 + l15];
    if (two) {
      const float* w3 = wl2 + (size_t)(j0 + l15) * 128;
      const float* w4 = wr2 + (size_t)(j0 + l15) * 128;
      #pragma unroll
      for (int kk = 0; kk < 4; kk++) {
        acc = MFMA(a2[kk], ld8f(w3 + kk * 32 + g * 8), acc);
        acc = MFMA(aH2[kk], ld8f(w4 + kk * 32 + g * 8), acc);
      }
      bias += bl2[j0 + l15];
    }
    #pragma unroll
    for (int r = 0; r < 4; r++)
      out[(size_t)(row0 + g * 4 + r) * 768 + j0 + l15] = acc[r] + bias;
  }
}

// copy x[:,1:6,:] (f32) into out[:,1:6,:]
__global__ __launch_bounds__(256) void tail_kernel(
    const float* __restrict__ xA, float* __restrict__ oA,
    const float* __restrict__ xB, float* __restrict__ oB, int total)
{
  const float* x = blockIdx.y ? xB : xA;
  float* o = blockIdx.y ? oB : oA;
  int tid = blockIdx.x * 256 + threadIdx.x;
  if (tid >= total) return;
  int n = tid / 160, r = tid % 160;          // 5*128/4 = 160 float4 chunks per row
  size_t off = (size_t)n * 768 + 128 + (size_t)r * 4;
  *(f32x4*)(o + off) = *(const f32x4*)(x + off);
}

extern "C" void kernel_launch(void* const* d_in, const int* in_sizes, int n_in,
                              void* d_out, int out_size, void* d_ws, size_t ws_size,
                              hipStream_t stream)
{
  const int D = 128, C = 6;
  const int N = in_sizes[0] / (C * D);   // 8192
  const int E = in_sizes[2] / 2;         // 262144

  const float* xA = (const float*)d_in[0];
  const float* xB = (const float*)d_in[1];
  const int* eiAB = (const int*)d_in[2];
  const int* eiBA = (const int*)d_in[3];
  const int* eiAA = (const int*)d_in[4];
  const float* inW_A  = (const float*)d_in[5];
  const float* inB_A  = (const float*)d_in[6];
  const float* outW_A = (const float*)d_in[7];
  const float* outB_A = (const float*)d_in[8];
  const float* inW_B  = (const float*)d_in[9];
  const float* inB_B  = (const float*)d_in[10];
  const float* outW_B = (const float*)d_in[11];
  const float* outB_B = (const float*)d_in[12];
  const float* wlAB = (const float*)d_in[13];
  const float* blAB = (const float*)d_in[14];
  const float* wrAB = (const float*)d_in[15];
  const float* wlBA = (const float*)d_in[16];
  const float* blBA = (const float*)d_in[17];
  const float* wrBA = (const float*)d_in[18];
  const float* wlAA = (const float*)d_in[19];
  const float* blAA = (const float*)d_in[20];
  const float* wrAA = (const float*)d_in[21];

  // workspace carve (~38 MB), bf16 intermediates + f32 agg
  u16* qkvA = (u16*)d_ws;
  u16* qkvB = qkvA + (size_t)N * 384;
  u16* vtA  = qkvB + (size_t)N * 384;
  u16* vtB  = vtA + (size_t)D * N;
  u16* oA_  = vtB + (size_t)D * N;
  u16* oB_  = oA_ + (size_t)N * D;
  u16* hA   = oB_ + (size_t)N * D;
  u16* hB   = hA + (size_t)N * D;
  float* aggAB = (float*)(hB + (size_t)N * D);
  float* aggBA = aggAB + (size_t)N * D;
  float* aggAA = aggBA + (size_t)N * D;

  float* outA = (float*)d_out;
  float* outB = outA + (size_t)N * C * D;

  dim3 blk(256);
  // 1. qkv = x0 @ inW^T + inB  (x0 f32, row stride C*D)
  linear_kernel<0><<<dim3(N / 64, 2), blk, 0, stream>>>(xA, inW_A, inB_A, qkvA,
                                                        xB, inW_B, inB_B, qkvB, C * D, 384, 384);
  // 2. v -> v^T (bf16)
  transpose_kernel<<<dim3(N / 64, 2, 2), blk, 0, stream>>>(qkvA + 256, qkvB + 256, vtA, vtB, 384, N);
  // 3. flash attention -> o (bf16)
  flash_kernel<<<dim3(N / 64, 2), blk, 0, stream>>>(qkvA, vtA, oA_, qkvB, vtB, oB_, N);
  // 4. h = o @ outW^T + outB (o bf16)
  linear_kernel<1><<<dim3(N / 64, 2), blk, 0, stream>>>(oA_, outW_A, outB_A, hA,
                                                        oB_, outW_B, outB_B, hB, 128, 128, 128);
  // 5. segment sums (atomic f32)
  (void)hipMemsetAsync(aggAB, 0, (size_t)3 * N * D * sizeof(float), stream);
  scatter_kernel<<<dim3((E * 16 + 255) / 256, 3), blk, 0, stream>>>(hA, eiAB, aggAB,
                                                                    hB, eiBA, aggBA,
                                                                    hA, eiAA, aggAA, E);
  // 6. sage outputs into column 0 (f32)
  sage_out_kernel<<<dim3(N / 64), blk, 0, stream>>>(aggAB, wlAB, blAB, hB, wrAB,
                                                    nullptr, nullptr, nullptr, nullptr, nullptr, outB);
  sage_out_kernel<<<dim3(N / 64), blk, 0, stream>>>(aggBA, wlBA, blBA, hA, wrBA,
                                                    aggAA, wlAA, blAA, hA, wrAA, outA);
  // 7. tail columns 1..5 (f32 copy)
  int total = N * 160;
  tail_kernel<<<dim3((total + 255) / 256, 2), blk, 0, stream>>>(xA, outA, xB, outB, total);
}

// Round 3
// 489.652 us; speedup vs baseline: 6.4323x; 6.4323x over previous
//
#include <hip/hip_runtime.h>
#include <hip/hip_bf16.h>

typedef unsigned short u16;
typedef unsigned int u32;
typedef __attribute__((ext_vector_type(8))) short bf16x8;
typedef __attribute__((ext_vector_type(4))) float f32x4;

#define MFMA(a,b,c) __builtin_amdgcn_mfma_f32_16x16x32_bf16((a),(b),(c),0,0,0)

__device__ __forceinline__ float bf2f(u16 u){
  union { float f; u32 i; } c; c.i = ((u32)u) << 16; return c.f;
}
__device__ __forceinline__ u16 f2bf(float f){
  __hip_bfloat16 h = __float2bfloat16(f);
  u16 u; __builtin_memcpy(&u, &h, 2); return u;
}
// 8 consecutive f32 -> bf16x8 fragment
__device__ __forceinline__ bf16x8 ld8f(const float* p){
  bf16x8 r;
  #pragma unroll
  for (int i = 0; i < 8; i++) r[i] = (short)f2bf(p[i]);
  return r;
}

// y[N][ystride(=M)] (bf16) = x[N][K=128 (stride xstride)] @ w[M][128]^T + b[M]
// x dtype: XBF ? bf16 : f32. w,b are f32. One block = 64 rows (4 waves x 16).
template<int XBF>
__global__ __launch_bounds__(256) void linear_kernel(
    const void* __restrict__ xA_, const float* __restrict__ wA, const float* __restrict__ bA, u16* __restrict__ yA,
    const void* __restrict__ xB_, const float* __restrict__ wB, const float* __restrict__ bB, u16* __restrict__ yB,
    int xstride, int ystride, int M)
{
  const void* x_ = blockIdx.y ? xB_ : xA_;
  const float* w = blockIdx.y ? wB : wA;
  const float* b = blockIdx.y ? bB : bA;
  u16* y = blockIdx.y ? yB : yA;
  const int lane = threadIdx.x & 63, wid = threadIdx.x >> 6;
  const int g = lane >> 4, l15 = lane & 15;
  const int row0 = blockIdx.x * 64 + wid * 16;

  bf16x8 a[4];
  if (XBF) {
    const u16* xr = (const u16*)x_ + (size_t)(row0 + l15) * xstride;
    #pragma unroll
    for (int kk = 0; kk < 4; kk++) a[kk] = *(const bf16x8*)(xr + kk * 32 + g * 8);
  } else {
    const float* xr = (const float*)x_ + (size_t)(row0 + l15) * xstride;
    #pragma unroll
    for (int kk = 0; kk < 4; kk++) a[kk] = ld8f(xr + kk * 32 + g * 8);
  }

  const f32x4 fz = {0.f, 0.f, 0.f, 0.f};
  for (int j0 = 0; j0 < M; j0 += 16) {
    f32x4 acc = fz;
    const float* wr_ = w + (size_t)(j0 + l15) * 128;
    #pragma unroll
    for (int kk = 0; kk < 4; kk++)
      acc = MFMA(a[kk], ld8f(wr_ + kk * 32 + g * 8), acc);
    float bv = b[j0 + l15];
    #pragma unroll
    for (int r = 0; r < 4; r++)
      y[(size_t)(row0 + g * 4 + r) * ystride + j0 + l15] = f2bf(acc[r] + bv);
  }
}

// vt[128][N] = v[N][128 (row stride vstride)]^T ; bf16; 64x64 tiles via LDS
__global__ __launch_bounds__(256) void transpose_kernel(
    const u16* __restrict__ vA, const u16* __restrict__ vB,
    u16* __restrict__ vtA, u16* __restrict__ vtB, int vstride, int N)
{
  __shared__ __align__(16) u16 t[64][72];
  const u16* v = blockIdx.z ? vB : vA;
  u16* vt = blockIdx.z ? vtB : vtA;
  const int r0 = blockIdx.x * 64, c0 = blockIdx.y * 64;
  const int tid = threadIdx.x;
  #pragma unroll
  for (int i = 0; i < 2; i++) {
    int ch = tid + i * 256; int r = ch >> 3, c = (ch & 7) * 8;
    *(bf16x8*)&t[r][c] = *(const bf16x8*)(v + (size_t)(r0 + r) * vstride + c0 + c);
  }
  __syncthreads();
  const int oc = tid >> 2, rc = (tid & 3) * 16;
  bf16x8 o0, o1;
  #pragma unroll
  for (int i = 0; i < 8; i++) { o0[i] = (short)t[rc + i][oc]; o1[i] = (short)t[rc + 8 + i][oc]; }
  *(bf16x8*)(vt + (size_t)(c0 + oc) * N + r0 + rc) = o0;
  *(bf16x8*)(vt + (size_t)(c0 + oc) * N + r0 + rc + 8) = o1;
}

// Flash attention: q,k interleaved in qkv [N][384] bf16 (q=+0, k=+128), v^T in vt[128][N].
__global__ __launch_bounds__(256) void flash_kernel(
    const u16* __restrict__ qkvA, const u16* __restrict__ vtA, u16* __restrict__ oA,
    const u16* __restrict__ qkvB, const u16* __restrict__ vtB, u16* __restrict__ oB,
    int N)
{
  __shared__ __align__(16) u16 Kt[64 * 136];
  __shared__ __align__(16) u16 Vtt[128 * 72];
  __shared__ __align__(16) u16 Pl[4 * 16 * 72];
  const u16* qkv = blockIdx.y ? qkvB : qkvA;
  const u16* vt  = blockIdx.y ? vtB  : vtA;
  u16* o = blockIdx.y ? oB : oA;
  const float scale = 0.088388347648318447f; // 1/sqrt(128)
  const int lane = threadIdx.x & 63, wid = threadIdx.x >> 6;
  const int g = lane >> 4, l15 = lane & 15;
  const int row0 = blockIdx.x * 64 + wid * 16;
  const u16* kg = qkv + 128;

  bf16x8 aQ[4];
  const u16* qr = qkv + (size_t)(row0 + l15) * 384;
  #pragma unroll
  for (int kk = 0; kk < 4; kk++) aQ[kk] = *(const bf16x8*)(qr + kk * 32 + g * 8);

  const f32x4 fz = {0.f, 0.f, 0.f, 0.f};
  f32x4 accO[8];
  #pragma unroll
  for (int n = 0; n < 8; n++) accO[n] = fz;
  float m_[4], l_[4];
  #pragma unroll
  for (int r = 0; r < 4; r++) { m_[r] = -INFINITY; l_[r] = 0.f; }

  u16* pw = &Pl[wid * 16 * 72];

  for (int kv0 = 0; kv0 < N; kv0 += 64) {
    #pragma unroll
    for (int i = 0; i < 4; i++) {
      int ch = (int)threadIdx.x + i * 256; int r = ch >> 4, c = (ch & 15) * 8;
      *(bf16x8*)&Kt[r * 136 + c] = *(const bf16x8*)(kg + (size_t)(kv0 + r) * 384 + c);
    }
    #pragma unroll
    for (int i = 0; i < 4; i++) {
      int ch = (int)threadIdx.x + i * 256; int r = ch >> 3, c = (ch & 7) * 8;
      *(bf16x8*)&Vtt[r * 72 + c] = *(const bf16x8*)(vt + (size_t)r * N + kv0 + c);
    }
    __syncthreads();

    f32x4 s[4];
    #pragma unroll
    for (int sb = 0; sb < 4; sb++) {
      s[sb] = fz;
      #pragma unroll
      for (int kk = 0; kk < 4; kk++) {
        bf16x8 bK = *(bf16x8*)&Kt[(sb * 16 + l15) * 136 + (kk * 4 + g) * 8];
        s[sb] = MFMA(aQ[kk], bK, s[sb]);
      }
    }

    float corr[4];
    #pragma unroll
    for (int r = 0; r < 4; r++) {
      float v = fmaxf(fmaxf(s[0][r], s[1][r]), fmaxf(s[2][r], s[3][r]));
      #pragma unroll
      for (int off = 1; off < 16; off <<= 1) v = fmaxf(v, __shfl_xor(v, off));
      float nm = fmaxf(m_[r], v);
      corr[r] = __expf(scale * (m_[r] - nm));
      m_[r] = nm;
      float sum = 0.f;
      #pragma unroll
      for (int sb = 0; sb < 4; sb++) {
        float p = __expf(scale * (s[sb][r] - nm));
        s[sb][r] = p; sum += p;
      }
      #pragma unroll
      for (int off = 1; off < 16; off <<= 1) sum += __shfl_xor(sum, off);
      l_[r] = l_[r] * corr[r] + sum;
    }
    #pragma unroll
    for (int n = 0; n < 8; n++) {
      #pragma unroll
      for (int r = 0; r < 4; r++) accO[n][r] *= corr[r];
    }

    #pragma unroll
    for (int sb = 0; sb < 4; sb++)
      #pragma unroll
      for (int r = 0; r < 4; r++)
        pw[(g * 4 + r) * 72 + sb * 16 + l15] = f2bf(s[sb][r]);
    __syncthreads();

    bf16x8 pA[2];
    #pragma unroll
    for (int kk2 = 0; kk2 < 2; kk2++) pA[kk2] = *(bf16x8*)&pw[l15 * 72 + kk2 * 32 + g * 8];
    #pragma unroll
    for (int n = 0; n < 8; n++) {
      #pragma unroll
      for (int kk2 = 0; kk2 < 2; kk2++) {
        bf16x8 bV = *(bf16x8*)&Vtt[(n * 16 + l15) * 72 + kk2 * 32 + g * 8];
        accO[n] = MFMA(pA[kk2], bV, accO[n]);
      }
    }
    __syncthreads();
  }

  #pragma unroll
  for (int n = 0; n < 8; n++)
    #pragma unroll
    for (int r = 0; r < 4; r++)
      o[(size_t)(row0 + g * 4 + r) * 128 + n * 16 + l15] = f2bf(accO[n][r] / l_[r]);
}

// ---- segment-sum via counting sort (no f32 atomics) ----

// histogram of destinations per edge type
__global__ __launch_bounds__(256) void hist_kernel(
    const int* __restrict__ e0, const int* __restrict__ e1, const int* __restrict__ e2,
    int* __restrict__ cnt, int Nn, int E)
{
  const int t = blockIdx.y;
  const int* ei = t == 0 ? e0 : (t == 1 ? e1 : e2);
  int e = blockIdx.x * 256 + threadIdx.x;
  if (e >= E) return;
  atomicAdd(&cnt[t * Nn + ei[E + e]], 1);
}

// exclusive scan of cnt -> off (Nn+1 entries) and work cursors; one block per type
__global__ __launch_bounds__(1024) void scan_kernel(
    const int* __restrict__ cnt, int* __restrict__ off, int* __restrict__ work, int Nn)
{
  const int t = blockIdx.x;
  const int* c = cnt + t * Nn;
  int* o = off + t * (Nn + 1);
  int* w = work + t * Nn;
  __shared__ int part[1024];
  const int tid = threadIdx.x;
  const int base = tid * 8;          // Nn = 8192 = 1024*8
  int loc[8], s = 0;
  #pragma unroll
  for (int i = 0; i < 8; i++) { loc[i] = s; s += c[base + i]; }
  part[tid] = s;
  __syncthreads();
  #pragma unroll
  for (int st = 1; st < 1024; st <<= 1) {
    int v = (tid >= st) ? part[tid - st] : 0;
    __syncthreads();
    part[tid] += v;
    __syncthreads();
  }
  int pre = (tid == 0) ? 0 : part[tid - 1];
  #pragma unroll
  for (int i = 0; i < 8; i++) { int p = pre + loc[i]; o[base + i] = p; w[base + i] = p; }
  if (tid == 1023) o[Nn] = part[1023];
}

// scatter srcs into dst-sorted order
__global__ __launch_bounds__(256) void sortedges_kernel(
    const int* __restrict__ e0, const int* __restrict__ e1, const int* __restrict__ e2,
    int* __restrict__ work, int* __restrict__ ssrc, int Nn, int E)
{
  const int t = blockIdx.y;
  const int* ei = t == 0 ? e0 : (t == 1 ? e1 : e2);
  int e = blockIdx.x * 256 + threadIdx.x;
  if (e >= E) return;
  int s = ei[e], d = ei[E + e];
  int pos = atomicAdd(&work[t * Nn + d], 1);
  ssrc[(size_t)t * E + pos] = s;
}

// one wave per destination: sum h[src] rows (bf16) -> agg row (f32), single write
__global__ __launch_bounds__(256) void aggregate_kernel(
    const u16* __restrict__ h0, const u16* __restrict__ h1, const u16* __restrict__ h2,
    const int* __restrict__ off, const int* __restrict__ ssrc,
    float* __restrict__ agg, int Nn, int E)
{
  const int t = blockIdx.y;
  const u16* h = t == 0 ? h0 : (t == 1 ? h1 : h2);
  const int* o = off + t * (Nn + 1);
  const int* ss = ssrc + (size_t)t * E;
  float* a = agg + (size_t)t * Nn * 128;
  const int wid = threadIdx.x >> 6, lane = threadIdx.x & 63;
  const int d = blockIdx.x * 4 + wid;
  const int s0 = o[d], s1 = o[d + 1];
  float a0 = 0.f, a1 = 0.f;
  int e = s0;
  for (; e + 3 < s1; e += 4) {
    int r0 = ss[e], r1 = ss[e + 1], r2 = ss[e + 2], r3 = ss[e + 3];
    u32 v0 = *(const u32*)(h + (size_t)r0 * 128 + lane * 2);
    u32 v1 = *(const u32*)(h + (size_t)r1 * 128 + lane * 2);
    u32 v2 = *(const u32*)(h + (size_t)r2 * 128 + lane * 2);
    u32 v3 = *(const u32*)(h + (size_t)r3 * 128 + lane * 2);
    a0 += bf2f((u16)(v0 & 0xffff)) + bf2f((u16)(v1 & 0xffff)) + bf2f((u16)(v2 & 0xffff)) + bf2f((u16)(v3 & 0xffff));
    a1 += bf2f((u16)(v0 >> 16)) + bf2f((u16)(v1 >> 16)) + bf2f((u16)(v2 >> 16)) + bf2f((u16)(v3 >> 16));
  }
  for (; e < s1; e++) {
    u32 v = *(const u32*)(h + (size_t)ss[e] * 128 + lane * 2);
    a0 += bf2f((u16)(v & 0xffff));
    a1 += bf2f((u16)(v >> 16));
  }
  a[(size_t)d * 128 + lane * 2] = a0;
  a[(size_t)d * 128 + lane * 2 + 1] = a1;
}

// out[:,0,:] (f32, row stride 768) = agg1@wl1^T + bl1 + h1@wr1^T (+ agg2@wl2^T + bl2 + h2@wr2^T)
__global__ __launch_bounds__(256) void sage_out_kernel(
    const float* __restrict__ agg1, const float* __restrict__ wl1, const float* __restrict__ bl1,
    const u16* __restrict__ h1, const float* __restrict__ wr1,
    const float* __restrict__ agg2, const float* __restrict__ wl2, const float* __restrict__ bl2,
    const u16* __restrict__ h2, const float* __restrict__ wr2,
    float* __restrict__ out)
{
  const int lane = threadIdx.x & 63, wid = threadIdx.x >> 6;
  const int g = lane >> 4, l15 = lane & 15;
  const int row0 = blockIdx.x * 64 + wid * 16;
  const bool two = (agg2 != nullptr);

  bf16x8 a1[4], aH1[4], a2[4], aH2[4];
  const float* ar1 = agg1 + (size_t)(row0 + l15) * 128;
  const u16* hr1 = h1 + (size_t)(row0 + l15) * 128;
  #pragma unroll
  for (int kk = 0; kk < 4; kk++) {
    a1[kk] = ld8f(ar1 + kk * 32 + g * 8);
    aH1[kk] = *(const bf16x8*)(hr1 + kk * 32 + g * 8);
  }
  if (two) {
    const float* ar2 = agg2 + (size_t)(row0 + l15) * 128;
    const u16* hr2 = h2 + (size_t)(row0 + l15) * 128;
    #pragma unroll
    for (int kk = 0; kk < 4; kk++) {
      a2[kk] = ld8f(ar2 + kk * 32 + g * 8);
      aH2[kk] = *(const bf16x8*)(hr2 + kk * 32 + g * 8);
    }
  }

  const f32x4 fz = {0.f, 0.f, 0.f, 0.f};
  for (int j0 = 0; j0 < 128; j0 += 16) {
    f32x4 acc = fz;
    const float* w1 = wl1 + (size_t)(j0 + l15) * 128;
    const float* w2 = wr1 + (size_t)(j0 + l15) * 128;
    #pragma unroll
    for (int kk = 0; kk < 4; kk++) {
      acc = MFMA(a1[kk], ld8f(w1 + kk * 32 + g * 8), acc);
      acc = MFMA(aH1[kk], ld8f(w2 + kk * 32 + g * 8), acc);
    }
    float bias = bl1[j0 + l15];
    if (two) {
      const float* w3 = wl2 + (size_t)(j0 + l15) * 128;
      const float* w4 = wr2 + (size_t)(j0 + l15) * 128;
      #pragma unroll
      for (int kk = 0; kk < 4; kk++) {
        acc = MFMA(a2[kk], ld8f(w3 + kk * 32 + g * 8), acc);
        acc = MFMA(aH2[kk], ld8f(w4 + kk * 32 + g * 8), acc);
      }
      bias += bl2[j0 + l15];
    }
    #pragma unroll
    for (int r = 0; r < 4; r++)
      out[(size_t)(row0 + g * 4 + r) * 768 + j0 + l15] = acc[r] + bias;
  }
}

// copy x[:,1:6,:] (f32) into out[:,1:6,:]
__global__ __launch_bounds__(256) void tail_kernel(
    const float* __restrict__ xA, float* __restrict__ oA,
    const float* __restrict__ xB, float* __restrict__ oB, int total)
{
  const float* x = blockIdx.y ? xB : xA;
  float* o = blockIdx.y ? oB : oA;
  int tid = blockIdx.x * 256 + threadIdx.x;
  if (tid >= total) return;
  int n = tid / 160, r = tid % 160;
  size_t off = (size_t)n * 768 + 128 + (size_t)r * 4;
  *(f32x4*)(o + off) = *(const f32x4*)(x + off);
}

extern "C" void kernel_launch(void* const* d_in, const int* in_sizes, int n_in,
                              void* d_out, int out_size, void* d_ws, size_t ws_size,
                              hipStream_t stream)
{
  const int D = 128, C = 6;
  const int N = in_sizes[0] / (C * D);   // 8192
  const int E = in_sizes[2] / 2;         // 262144

  const float* xA = (const float*)d_in[0];
  const float* xB = (const float*)d_in[1];
  const int* eiAB = (const int*)d_in[2];
  const int* eiBA = (const int*)d_in[3];
  const int* eiAA = (const int*)d_in[4];
  const float* inW_A  = (const float*)d_in[5];
  const float* inB_A  = (const float*)d_in[6];
  const float* outW_A = (const float*)d_in[7];
  const float* outB_A = (const float*)d_in[8];
  const float* inW_B  = (const float*)d_in[9];
  const float* inB_B  = (const float*)d_in[10];
  const float* outW_B = (const float*)d_in[11];
  const float* outB_B = (const float*)d_in[12];
  const float* wlAB = (const float*)d_in[13];
  const float* blAB = (const float*)d_in[14];
  const float* wrAB = (const float*)d_in[15];
  const float* wlBA = (const float*)d_in[16];
  const float* blBA = (const float*)d_in[17];
  const float* wrBA = (const float*)d_in[18];
  const float* wlAA = (const float*)d_in[19];
  const float* blAA = (const float*)d_in[20];
  const float* wrAA = (const float*)d_in[21];

  // workspace carve: bf16 intermediates + f32 agg + sort scratch (~41 MB)
  u16* qkvA = (u16*)d_ws;
  u16* qkvB = qkvA + (size_t)N * 384;
  u16* vtA  = qkvB + (size_t)N * 384;
  u16* vtB  = vtA + (size_t)D * N;
  u16* oA_  = vtB + (size_t)D * N;
  u16* oB_  = oA_ + (size_t)N * D;
  u16* hA   = oB_ + (size_t)N * D;
  u16* hB   = hA + (size_t)N * D;
  float* aggAB = (float*)(hB + (size_t)N * D);
  float* aggBA = aggAB + (size_t)N * D;
  float* aggAA = aggBA + (size_t)N * D;
  int* cnt  = (int*)(aggAA + (size_t)N * D);   // 3*N
  int* off  = cnt + 3 * N;                     // 3*(N+1)
  int* work = off + 3 * (N + 1);               // 3*N
  int* ssrc = work + 3 * N;                    // 3*E

  float* outA = (float*)d_out;
  float* outB = outA + (size_t)N * C * D;

  dim3 blk(256);
  // 1. qkv = x0 @ inW^T + inB
  linear_kernel<0><<<dim3(N / 64, 2), blk, 0, stream>>>(xA, inW_A, inB_A, qkvA,
                                                        xB, inW_B, inB_B, qkvB, C * D, 384, 384);
  // 2. v -> v^T (bf16)
  transpose_kernel<<<dim3(N / 64, 2, 2), blk, 0, stream>>>(qkvA + 256, qkvB + 256, vtA, vtB, 384, N);
  // 3. flash attention -> o (bf16)
  flash_kernel<<<dim3(N / 64, 2), blk, 0, stream>>>(qkvA, vtA, oA_, qkvB, vtB, oB_, N);
  // 4. h = o @ outW^T + outB
  linear_kernel<1><<<dim3(N / 64, 2), blk, 0, stream>>>(oA_, outW_A, outB_A, hA,
                                                        oB_, outW_B, outB_B, hB, 128, 128, 128);
  // 5. segment sums via counting sort (types: 0=AB(h=A), 1=BA(h=B), 2=AA(h=A))
  (void)hipMemsetAsync(cnt, 0, (size_t)3 * N * sizeof(int), stream);
  hist_kernel<<<dim3((E + 255) / 256, 3), blk, 0, stream>>>(eiAB, eiBA, eiAA, cnt, N, E);
  scan_kernel<<<dim3(3), dim3(1024), 0, stream>>>(cnt, off, work, N);
  sortedges_kernel<<<dim3((E + 255) / 256, 3), blk, 0, stream>>>(eiAB, eiBA, eiAA, work, ssrc, N, E);
  aggregate_kernel<<<dim3(N / 4, 3), blk, 0, stream>>>(hA, hB, hA, off, ssrc, aggAB, N, E);
  // 6. sage outputs into column 0 (f32)
  sage_out_kernel<<<dim3(N / 64), blk, 0, stream>>>(aggAB, wlAB, blAB, hB, wrAB,
                                                    nullptr, nullptr, nullptr, nullptr, nullptr, outB);
  sage_out_kernel<<<dim3(N / 64), blk, 0, stream>>>(aggBA, wlBA, blBA, hA, wrBA,
                                                    aggAA, wlAA, blAA, hA, wrAA, outA);
  // 7. tail columns 1..5 (f32 copy)
  int total = N * 160;
  tail_kernel<<<dim3((total + 255) / 256, 2), blk, 0, stream>>>(xA, outA, xB, outB, total);
}

// Round 4
// 379.186 us; speedup vs baseline: 8.3063x; 1.2913x over previous
//
#include <hip/hip_runtime.h>
#include <hip/hip_bf16.h>

typedef unsigned short u16;
typedef unsigned int u32;
typedef __attribute__((ext_vector_type(8))) short bf16x8;
typedef __attribute__((ext_vector_type(4))) short bf16x4;
typedef __attribute__((ext_vector_type(2))) unsigned int u32x2;
typedef __attribute__((ext_vector_type(4))) float f32x4;

#define MFMA(a,b,c) __builtin_amdgcn_mfma_f32_16x16x32_bf16((a),(b),(c),0,0,0)

__device__ __forceinline__ float bf2f(u16 u){
  union { float f; u32 i; } c; c.i = ((u32)u) << 16; return c.f;
}
__device__ __forceinline__ u16 f2bf(float f){
  __hip_bfloat16 h = __float2bfloat16(f);
  u16 u; __builtin_memcpy(&u, &h, 2); return u;
}
__device__ __forceinline__ bf16x8 ld8f(const float* p){
  bf16x8 r;
  #pragma unroll
  for (int i = 0; i < 8; i++) r[i] = (short)f2bf(p[i]);
  return r;
}
__device__ __forceinline__ u32 pk2(float a, float b){
  return (u32)f2bf(a) | ((u32)f2bf(b) << 16);
}

// y[N][ystride(=M)] (bf16) = x[N][K=128 (stride xstride)] @ w[M][128]^T + b[M]
template<int XBF>
__global__ __launch_bounds__(256) void linear_kernel(
    const void* __restrict__ xA_, const float* __restrict__ wA, const float* __restrict__ bA, u16* __restrict__ yA,
    const void* __restrict__ xB_, const float* __restrict__ wB, const float* __restrict__ bB, u16* __restrict__ yB,
    int xstride, int ystride, int M)
{
  const void* x_ = blockIdx.y ? xB_ : xA_;
  const float* w = blockIdx.y ? wB : wA;
  const float* b = blockIdx.y ? bB : bA;
  u16* y = blockIdx.y ? yB : yA;
  const int lane = threadIdx.x & 63, wid = threadIdx.x >> 6;
  const int g = lane >> 4, l15 = lane & 15;
  const int row0 = blockIdx.x * 64 + wid * 16;

  bf16x8 a[4];
  if (XBF) {
    const u16* xr = (const u16*)x_ + (size_t)(row0 + l15) * xstride;
    #pragma unroll
    for (int kk = 0; kk < 4; kk++) a[kk] = *(const bf16x8*)(xr + kk * 32 + g * 8);
  } else {
    const float* xr = (const float*)x_ + (size_t)(row0 + l15) * xstride;
    #pragma unroll
    for (int kk = 0; kk < 4; kk++) a[kk] = ld8f(xr + kk * 32 + g * 8);
  }

  const f32x4 fz = {0.f, 0.f, 0.f, 0.f};
  for (int j0 = 0; j0 < M; j0 += 16) {
    f32x4 acc = fz;
    const float* wr_ = w + (size_t)(j0 + l15) * 128;
    #pragma unroll
    for (int kk = 0; kk < 4; kk++)
      acc = MFMA(a[kk], ld8f(wr_ + kk * 32 + g * 8), acc);
    float bv = b[j0 + l15];
    #pragma unroll
    for (int r = 0; r < 4; r++)
      y[(size_t)(row0 + g * 4 + r) * ystride + j0 + l15] = f2bf(acc[r] + bv);
  }
}

// vt[128][N] = v[N][128 (row stride vstride)]^T ; bf16; 64x64 tiles via LDS
__global__ __launch_bounds__(256) void transpose_kernel(
    const u16* __restrict__ vA, const u16* __restrict__ vB,
    u16* __restrict__ vtA, u16* __restrict__ vtB, int vstride, int N)
{
  __shared__ __align__(16) u16 t[64][72];
  const u16* v = blockIdx.z ? vB : vA;
  u16* vt = blockIdx.z ? vtB : vtA;
  const int r0 = blockIdx.x * 64, c0 = blockIdx.y * 64;
  const int tid = threadIdx.x;
  #pragma unroll
  for (int i = 0; i < 2; i++) {
    int ch = tid + i * 256; int r = ch >> 3, c = (ch & 7) * 8;
    *(bf16x8*)&t[r][c] = *(const bf16x8*)(v + (size_t)(r0 + r) * vstride + c0 + c);
  }
  __syncthreads();
  const int oc = tid >> 2, rc = (tid & 3) * 16;
  bf16x8 o0, o1;
  #pragma unroll
  for (int i = 0; i < 8; i++) { o0[i] = (short)t[rc + i][oc]; o1[i] = (short)t[rc + 8 + i][oc]; }
  *(bf16x8*)(vt + (size_t)(c0 + oc) * N + r0 + rc) = o0;
  *(bf16x8*)(vt + (size_t)(c0 + oc) * N + r0 + rc + 8) = o1;
}

// Flash attention, KV-split, swapped-QK^T (lane-local softmax).
// grid = (N/64, SEG, 2 types), block = 256 (4 waves x 16 q-rows).
// Writes unnormalized partial O (bf16) + per-row (m,l) f32.
__global__ __launch_bounds__(256, 4) void flash_kernel(
    const u16* __restrict__ qkvA, const u16* __restrict__ vtA,
    const u16* __restrict__ qkvB, const u16* __restrict__ vtB,
    u16* __restrict__ part_acc, float* __restrict__ part_ml,
    int N, int segsz, int SEG)
{
  __shared__ __align__(16) u16 Kt[64 * 128];    // swizzled: idx = r*128 + (c ^ ((r&7)<<3))
  __shared__ __align__(16) u16 Vtt[128 * 64];   // swizzled: idx = r*64  + (c ^ ((r&7)<<3))
  __shared__ __align__(16) u32 Pscr[4 * 16 * 32]; // per-wave P^T scratch
  const int t = blockIdx.z;
  const u16* qkv = t ? qkvB : qkvA;
  const u16* vt  = t ? vtB  : vtA;
  const int lane = threadIdx.x & 63, wid = threadIdx.x >> 6;
  const int g = lane >> 4, l15 = lane & 15;
  const int q = blockIdx.x * 64 + wid * 16 + l15;
  const int seg = blockIdx.y;
  const int kvbase = seg * segsz;
  const float C = 0.088388347648318447f * 1.4426950408889634f; // scale*log2(e)

  bf16x8 aQ[4];
  const u16* qr = qkv + (size_t)q * 384;
  #pragma unroll
  for (int kk = 0; kk < 4; kk++) aQ[kk] = *(const bf16x8*)(qr + kk * 32 + g * 8);

  const f32x4 fz = {0.f, 0.f, 0.f, 0.f};
  f32x4 accOT[8];
  #pragma unroll
  for (int n = 0; n < 8; n++) accOT[n] = fz;
  float m_ = -INFINITY, l_ = 0.f;

  u32* pw = Pscr + wid * 512 + l15 * 32;
  const int swz8 = (l15 & 7) << 3;   // u16-granule XOR for Kt/Vtt reads
  const int swz4 = (l15 & 7) << 2;   // u32-granule XOR for Pscr

  for (int kt = 0; kt < segsz; kt += 64) {
    const int kv0 = kvbase + kt;
    // stage K [64][128] and V^T [128][64] tiles, XOR-swizzled
    #pragma unroll
    for (int i = 0; i < 4; i++) {
      int ch = (int)threadIdx.x + i * 256;
      { int r = ch >> 4, c = (ch & 15) * 8;
        *(bf16x8*)&Kt[r * 128 + (c ^ ((r & 7) << 3))] =
            *(const bf16x8*)(qkv + 128 + (size_t)(kv0 + r) * 384 + c); }
      { int r = ch >> 3, c = (ch & 7) * 8;
        *(bf16x8*)&Vtt[r * 64 + (c ^ ((r & 7) << 3))] =
            *(const bf16x8*)(vt + (size_t)r * N + kv0 + c); }
    }
    __syncthreads();

    // S^T = K @ Q^T : lane holds S[kv = sb*16+g*4+r][q = l15]
    f32x4 s[4];
    #pragma unroll
    for (int sb = 0; sb < 4; sb++) {
      s[sb] = fz;
      #pragma unroll
      for (int kk = 0; kk < 4; kk++) {
        bf16x8 aK = *(bf16x8*)&Kt[(sb * 16 + l15) * 128 + (((kk * 4 + g) * 8) ^ swz8)];
        s[sb] = MFMA(aK, aQ[kk], s[sb]);
      }
    }

    // lane-local online softmax (q = l15 fixed per lane)
    float v = s[0][0];
    #pragma unroll
    for (int sb = 0; sb < 4; sb++)
      #pragma unroll
      for (int r = 0; r < 4; r++) v = fmaxf(v, s[sb][r]);
    v = fmaxf(v, __shfl_xor(v, 16));
    v = fmaxf(v, __shfl_xor(v, 32));
    const float nm = fmaxf(m_, v);
    const float corr = __builtin_exp2f((m_ - nm) * C);
    m_ = nm;
    float p[16];
    float sum = 0.f;
    #pragma unroll
    for (int sb = 0; sb < 4; sb++)
      #pragma unroll
      for (int r = 0; r < 4; r++) {
        float e = __builtin_exp2f((s[sb][r] - nm) * C);
        p[sb * 4 + r] = e; sum += e;
      }
    sum += __shfl_xor(sum, 16);
    sum += __shfl_xor(sum, 32);
    l_ = l_ * corr + sum;
    #pragma unroll
    for (int n = 0; n < 8; n++) {
      #pragma unroll
      for (int r = 0; r < 4; r++) accOT[n][r] *= corr;
    }

    // P^T -> per-wave LDS scratch (no barrier; wave-local)
    #pragma unroll
    for (int sb = 0; sb < 4; sb++) {
      u32x2 w2; w2[0] = pk2(p[sb * 4 + 0], p[sb * 4 + 1]); w2[1] = pk2(p[sb * 4 + 2], p[sb * 4 + 3]);
      *(u32x2*)(pw + ((sb * 8 + g * 2) ^ swz4)) = w2;
    }
    bf16x8 pB[2];
    #pragma unroll
    for (int c = 0; c < 2; c++) pB[c] = *(bf16x8*)(pw + ((c * 16 + g * 4) ^ swz4));

    // O^T += V^T @ P^T
    #pragma unroll
    for (int n = 0; n < 8; n++) {
      #pragma unroll
      for (int c = 0; c < 2; c++) {
        bf16x8 aV = *(bf16x8*)&Vtt[(n * 16 + l15) * 64 + (((c * 4 + g) * 8) ^ swz8)];
        accOT[n] = MFMA(aV, pB[c], accOT[n]);
      }
    }
    __syncthreads();
  }

  // partial store: acc (bf16, unnormalized) + (m,l)
  const size_t pbase = ((size_t)(t * SEG + seg) * N + q) * 128;
  #pragma unroll
  for (int n = 0; n < 8; n++) {
    bf16x4 o4;
    #pragma unroll
    for (int r = 0; r < 4; r++) o4[r] = (short)f2bf(accOT[n][r]);
    *(bf16x4*)(part_acc + pbase + n * 16 + g * 4) = o4;
  }
  if (g == 0) {
    float* ml = part_ml + ((size_t)(t * SEG + seg) * N + q) * 2;
    ml[0] = m_; ml[1] = l_;
  }
}

// combine SEG partials -> o (bf16 [N][128]); grid (N/64, 2), block 256 (4 thr/row)
__global__ __launch_bounds__(256) void combine_kernel(
    const u16* __restrict__ part_acc, const float* __restrict__ part_ml,
    u16* __restrict__ oA_, u16* __restrict__ oB_, int N, int SEG)
{
  const int t = blockIdx.y;
  u16* o = t ? oB_ : oA_;
  const int row = blockIdx.x * 64 + ((int)threadIdx.x >> 2);
  const int qt = threadIdx.x & 3;
  const float C = 0.088388347648318447f * 1.4426950408889634f;

  float m = -INFINITY;
  for (int s = 0; s < SEG; s++)
    m = fmaxf(m, part_ml[((size_t)(t * SEG + s) * N + row) * 2]);
  float l = 0.f;
  float acc[32];
  #pragma unroll
  for (int i = 0; i < 32; i++) acc[i] = 0.f;
  for (int s = 0; s < SEG; s++) {
    const float* ml = part_ml + ((size_t)(t * SEG + s) * N + row) * 2;
    float w = __builtin_exp2f((ml[0] - m) * C);
    l += w * ml[1];
    const u16* pa = part_acc + ((size_t)(t * SEG + s) * N + row) * 128 + qt * 32;
    #pragma unroll
    for (int j = 0; j < 4; j++) {
      bf16x8 vch = *(const bf16x8*)(pa + j * 8);
      #pragma unroll
      for (int i = 0; i < 8; i++) acc[j * 8 + i] += w * bf2f((u16)vch[i]);
    }
  }
  const float inv = 1.f / l;
  #pragma unroll
  for (int j = 0; j < 4; j++) {
    bf16x8 oc;
    #pragma unroll
    for (int i = 0; i < 8; i++) oc[i] = (short)f2bf(acc[j * 8 + i] * inv);
    *(bf16x8*)(o + (size_t)row * 128 + qt * 32 + j * 8) = oc;
  }
}

// ---- segment-sum via counting sort (no f32 atomics) ----
__global__ __launch_bounds__(256) void hist_kernel(
    const int* __restrict__ e0, const int* __restrict__ e1, const int* __restrict__ e2,
    int* __restrict__ cnt, int Nn, int E)
{
  const int t = blockIdx.y;
  const int* ei = t == 0 ? e0 : (t == 1 ? e1 : e2);
  int e = blockIdx.x * 256 + threadIdx.x;
  if (e >= E) return;
  atomicAdd(&cnt[t * Nn + ei[E + e]], 1);
}

__global__ __launch_bounds__(1024) void scan_kernel(
    const int* __restrict__ cnt, int* __restrict__ off, int* __restrict__ work, int Nn)
{
  const int t = blockIdx.x;
  const int* c = cnt + t * Nn;
  int* o = off + t * (Nn + 1);
  int* w = work + t * Nn;
  __shared__ int part[1024];
  const int tid = threadIdx.x;
  const int base = tid * 8;
  int loc[8], s = 0;
  #pragma unroll
  for (int i = 0; i < 8; i++) { loc[i] = s; s += c[base + i]; }
  part[tid] = s;
  __syncthreads();
  #pragma unroll
  for (int st = 1; st < 1024; st <<= 1) {
    int v = (tid >= st) ? part[tid - st] : 0;
    __syncthreads();
    part[tid] += v;
    __syncthreads();
  }
  int pre = (tid == 0) ? 0 : part[tid - 1];
  #pragma unroll
  for (int i = 0; i < 8; i++) { int p = pre + loc[i]; o[base + i] = p; w[base + i] = p; }
  if (tid == 1023) o[Nn] = part[1023];
}

__global__ __launch_bounds__(256) void sortedges_kernel(
    const int* __restrict__ e0, const int* __restrict__ e1, const int* __restrict__ e2,
    int* __restrict__ work, int* __restrict__ ssrc, int Nn, int E)
{
  const int t = blockIdx.y;
  const int* ei = t == 0 ? e0 : (t == 1 ? e1 : e2);
  int e = blockIdx.x * 256 + threadIdx.x;
  if (e >= E) return;
  int s = ei[e], d = ei[E + e];
  int pos = atomicAdd(&work[t * Nn + d], 1);
  ssrc[(size_t)t * E + pos] = s;
}

__global__ __launch_bounds__(256) void aggregate_kernel(
    const u16* __restrict__ h0, const u16* __restrict__ h1, const u16* __restrict__ h2,
    const int* __restrict__ off, const int* __restrict__ ssrc,
    float* __restrict__ agg, int Nn, int E)
{
  const int t = blockIdx.y;
  const u16* h = t == 0 ? h0 : (t == 1 ? h1 : h2);
  const int* o = off + t * (Nn + 1);
  const int* ss = ssrc + (size_t)t * E;
  float* a = agg + (size_t)t * Nn * 128;
  const int wid = threadIdx.x >> 6, lane = threadIdx.x & 63;
  const int d = blockIdx.x * 4 + wid;
  const int s0 = o[d], s1 = o[d + 1];
  float a0 = 0.f, a1 = 0.f;
  int e = s0;
  for (; e + 3 < s1; e += 4) {
    int r0 = ss[e], r1 = ss[e + 1], r2 = ss[e + 2], r3 = ss[e + 3];
    u32 v0 = *(const u32*)(h + (size_t)r0 * 128 + lane * 2);
    u32 v1 = *(const u32*)(h + (size_t)r1 * 128 + lane * 2);
    u32 v2 = *(const u32*)(h + (size_t)r2 * 128 + lane * 2);
    u32 v3 = *(const u32*)(h + (size_t)r3 * 128 + lane * 2);
    a0 += bf2f((u16)(v0 & 0xffff)) + bf2f((u16)(v1 & 0xffff)) + bf2f((u16)(v2 & 0xffff)) + bf2f((u16)(v3 & 0xffff));
    a1 += bf2f((u16)(v0 >> 16)) + bf2f((u16)(v1 >> 16)) + bf2f((u16)(v2 >> 16)) + bf2f((u16)(v3 >> 16));
  }
  for (; e < s1; e++) {
    u32 v = *(const u32*)(h + (size_t)ss[e] * 128 + lane * 2);
    a0 += bf2f((u16)(v & 0xffff));
    a1 += bf2f((u16)(v >> 16));
  }
  a[(size_t)d * 128 + lane * 2] = a0;
  a[(size_t)d * 128 + lane * 2 + 1] = a1;
}

__global__ __launch_bounds__(256) void sage_out_kernel(
    const float* __restrict__ agg1, const float* __restrict__ wl1, const float* __restrict__ bl1,
    const u16* __restrict__ h1, const float* __restrict__ wr1,
    const float* __restrict__ agg2, const float* __restrict__ wl2, const float* __restrict__ bl2,
    const u16* __restrict__ h2, const float* __restrict__ wr2,
    float* __restrict__ out)
{
  const int lane = threadIdx.x & 63, wid = threadIdx.x >> 6;
  const int g = lane >> 4, l15 = lane & 15;
  const int row0 = blockIdx.x * 64 + wid * 16;
  const bool two = (agg2 != nullptr);

  bf16x8 a1[4], aH1[4], a2[4], aH2[4];
  const float* ar1 = agg1 + (size_t)(row0 + l15) * 128;
  const u16* hr1 = h1 + (size_t)(row0 + l15) * 128;
  #pragma unroll
  for (int kk = 0; kk < 4; kk++) {
    a1[kk] = ld8f(ar1 + kk * 32 + g * 8);
    aH1[kk] = *(const bf16x8*)(hr1 + kk * 32 + g * 8);
  }
  if (two) {
    const float* ar2 = agg2 + (size_t)(row0 + l15) * 128;
    const u16* hr2 = h2 + (size_t)(row0 + l15) * 128;
    #pragma unroll
    for (int kk = 0; kk < 4; kk++) {
      a2[kk] = ld8f(ar2 + kk * 32 + g * 8);
      aH2[kk] = *(const bf16x8*)(hr2 + kk * 32 + g * 8);
    }
  }

  const f32x4 fz = {0.f, 0.f, 0.f, 0.f};
  for (int j0 = 0; j0 < 128; j0 += 16) {
    f32x4 acc = fz;
    const float* w1 = wl1 + (size_t)(j0 + l15) * 128;
    const float* w2 = wr1 + (size_t)(j0 + l15) * 128;
    #pragma unroll
    for (int kk = 0; kk < 4; kk++) {
      acc = MFMA(a1[kk], ld8f(w1 + kk * 32 + g * 8), acc);
      acc = MFMA(aH1[kk], ld8f(w2 + kk * 32 + g * 8), acc);
    }
    float bias = bl1[j0 + l15];
    if (two) {
      const float* w3 = wl2 + (size_t)(j0 + l15) * 128;
      const float* w4 = wr2 + (size_t)(j0 + l15) * 128;
      #pragma unroll
      for (int kk = 0; kk < 4; kk++) {
        acc = MFMA(a2[kk], ld8f(w3 + kk * 32 + g * 8), acc);
        acc = MFMA(aH2[kk], ld8f(w4 + kk * 32 + g * 8), acc);
      }
      bias += bl2[j0 + l15];
    }
    #pragma unroll
    for (int r = 0; r < 4; r++)
      out[(size_t)(row0 + g * 4 + r) * 768 + j0 + l15] = acc[r] + bias;
  }
}

__global__ __launch_bounds__(256) void tail_kernel(
    const float* __restrict__ xA, float* __restrict__ oA,
    const float* __restrict__ xB, float* __restrict__ oB, int total)
{
  const float* x = blockIdx.y ? xB : xA;
  float* o = blockIdx.y ? oB : oA;
  int tid = blockIdx.x * 256 + threadIdx.x;
  if (tid >= total) return;
  int n = tid / 160, r = tid % 160;
  size_t off = (size_t)n * 768 + 128 + (size_t)r * 4;
  *(f32x4*)(o + off) = *(const f32x4*)(x + off);
}

extern "C" void kernel_launch(void* const* d_in, const int* in_sizes, int n_in,
                              void* d_out, int out_size, void* d_ws, size_t ws_size,
                              hipStream_t stream)
{
  const int D = 128, C = 6;
  const int N = in_sizes[0] / (C * D);   // 8192
  const int E = in_sizes[2] / 2;         // 262144

  const float* xA = (const float*)d_in[0];
  const float* xB = (const float*)d_in[1];
  const int* eiAB = (const int*)d_in[2];
  const int* eiBA = (const int*)d_in[3];
  const int* eiAA = (const int*)d_in[4];
  const float* inW_A  = (const float*)d_in[5];
  const float* inB_A  = (const float*)d_in[6];
  const float* outW_A = (const float*)d_in[7];
  const float* outB_A = (const float*)d_in[8];
  const float* inW_B  = (const float*)d_in[9];
  const float* inB_B  = (const float*)d_in[10];
  const float* outW_B = (const float*)d_in[11];
  const float* outB_B = (const float*)d_in[12];
  const float* wlAB = (const float*)d_in[13];
  const float* blAB = (const float*)d_in[14];
  const float* wrAB = (const float*)d_in[15];
  const float* wlBA = (const float*)d_in[16];
  const float* blBA = (const float*)d_in[17];
  const float* wrBA = (const float*)d_in[18];
  const float* wlAA = (const float*)d_in[19];
  const float* blAA = (const float*)d_in[20];
  const float* wrAA = (const float*)d_in[21];

  // ---- workspace carve ----
  // persistent region: qkv, vt, o, h
  u16* qkvA = (u16*)d_ws;
  u16* qkvB = qkvA + (size_t)N * 384;
  u16* vtA  = qkvB + (size_t)N * 384;
  u16* vtB  = vtA + (size_t)D * N;
  u16* oA_  = vtB + (size_t)D * N;
  u16* oB_  = oA_ + (size_t)N * D;
  u16* hA   = oB_ + (size_t)N * D;
  u16* hB   = hA + (size_t)N * D;
  // union region: flash partials (phase 1) OR agg+sort scratch (phase 2)
  char* uni = (char*)(hB + (size_t)N * D);
  size_t base_b = (size_t)((char*)uni - (char*)d_ws);
  size_t aggsort_b = (size_t)3 * N * 128 * 4 + (size_t)(3 * N + 3 * (N + 1) + 3 * N) * 4 + (size_t)3 * E * 4;
  auto part_b = [&](int S){ return (size_t)2 * S * N * 128 * 2 + (size_t)2 * S * N * 2 * 4; };
  int SEG = 4;
  {
    size_t need4 = base_b + (part_b(4) > aggsort_b ? part_b(4) : aggsort_b);
    size_t need2 = base_b + (part_b(2) > aggsort_b ? part_b(2) : aggsort_b);
    if (ws_size < need4) SEG = (ws_size < need2) ? 1 : 2;
  }
  const int segsz = N / SEG;
  // view 1: partials
  u16* part_acc = (u16*)uni;
  float* part_ml = (float*)(part_acc + (size_t)2 * SEG * N * 128);
  // view 2: agg + sort
  float* aggAB = (float*)uni;
  float* aggBA = aggAB + (size_t)N * D;
  float* aggAA = aggBA + (size_t)N * D;
  int* cnt  = (int*)(aggAA + (size_t)N * D);
  int* off  = cnt + 3 * N;
  int* work = off + 3 * (N + 1);
  int* ssrc = work + 3 * N;

  float* outA = (float*)d_out;
  float* outB = outA + (size_t)N * C * D;

  dim3 blk(256);
  // 1. qkv = x0 @ inW^T + inB
  linear_kernel<0><<<dim3(N / 64, 2), blk, 0, stream>>>(xA, inW_A, inB_A, qkvA,
                                                        xB, inW_B, inB_B, qkvB, C * D, 384, 384);
  // 2. v -> v^T (bf16)
  transpose_kernel<<<dim3(N / 64, 2, 2), blk, 0, stream>>>(qkvA + 256, qkvB + 256, vtA, vtB, 384, N);
  // 3. flash attention partials (KV-split)
  flash_kernel<<<dim3(N / 64, SEG, 2), blk, 0, stream>>>(qkvA, vtA, qkvB, vtB,
                                                         part_acc, part_ml, N, segsz, SEG);
  // 3b. combine partials -> o (bf16)
  combine_kernel<<<dim3(N / 64, 2), blk, 0, stream>>>(part_acc, part_ml, oA_, oB_, N, SEG);
  // 4. h = o @ outW^T + outB
  linear_kernel<1><<<dim3(N / 64, 2), blk, 0, stream>>>(oA_, outW_A, outB_A, hA,
                                                        oB_, outW_B, outB_B, hB, 128, 128, 128);
  // 5. segment sums via counting sort (partials region is dead now; reuse as agg/sort)
  (void)hipMemsetAsync(cnt, 0, (size_t)3 * N * sizeof(int), stream);
  hist_kernel<<<dim3((E + 255) / 256, 3), blk, 0, stream>>>(eiAB, eiBA, eiAA, cnt, N, E);
  scan_kernel<<<dim3(3), dim3(1024), 0, stream>>>(cnt, off, work, N);
  sortedges_kernel<<<dim3((E + 255) / 256, 3), blk, 0, stream>>>(eiAB, eiBA, eiAA, work, ssrc, N, E);
  aggregate_kernel<<<dim3(N / 4, 3), blk, 0, stream>>>(hA, hB, hA, off, ssrc, aggAB, N, E);
  // 6. sage outputs into column 0 (f32)
  sage_out_kernel<<<dim3(N / 64), blk, 0, stream>>>(aggAB, wlAB, blAB, hB, wrAB,
                                                    nullptr, nullptr, nullptr, nullptr, nullptr, outB);
  sage_out_kernel<<<dim3(N / 64), blk, 0, stream>>>(aggBA, wlBA, blBA, hA, wrBA,
                                                    aggAA, wlAA, blAA, hA, wrAA, outA);
  // 7. tail columns 1..5 (f32 copy)
  int total = N * 160;
  tail_kernel<<<dim3((total + 255) / 256, 2), blk, 0, stream>>>(xA, outA, xB, outB, total);
}

// Round 5
// 330.921 us; speedup vs baseline: 9.5177x; 1.1459x over previous
//
#include <hip/hip_runtime.h>
#include <hip/hip_bf16.h>

typedef unsigned short u16;
typedef unsigned int u32;
typedef __attribute__((ext_vector_type(8))) short bf16x8;
typedef __attribute__((ext_vector_type(4))) short bf16x4;
typedef __attribute__((ext_vector_type(4))) float f32x4;
typedef __attribute__((ext_vector_type(16))) float f32x16;

#define MFMA(a,b,c)   __builtin_amdgcn_mfma_f32_16x16x32_bf16((a),(b),(c),0,0,0)
#define MFMA32(a,b,c) __builtin_amdgcn_mfma_f32_32x32x16_bf16((a),(b),(c),0,0,0)

__device__ __forceinline__ float bf2f(u16 u){
  union { float f; u32 i; } c; c.i = ((u32)u) << 16; return c.f;
}
__device__ __forceinline__ u16 f2bf(float f){
  __hip_bfloat16 h = __float2bfloat16(f);
  u16 u; __builtin_memcpy(&u, &h, 2); return u;
}
__device__ __forceinline__ bf16x8 ld8f(const float* p){
  bf16x8 r;
  #pragma unroll
  for (int i = 0; i < 8; i++) r[i] = (short)f2bf(p[i]);
  return r;
}
// pack two f32 -> one u32 of 2 bf16 (lo = a, hi = b)
__device__ __forceinline__ u32 cvtpk(float a, float b){
  u32 r; asm volatile("v_cvt_pk_bf16_f32 %0, %1, %2" : "=v"(r) : "v"(a), "v"(b)); return r;
}
// after: a = (a.lo | b.lo-in-hi-lanes), b = (a.hi-in-lo-lanes | b.hi)
__device__ __forceinline__ void pl32swap(u32 &a, u32 &b){
  asm volatile("v_permlane32_swap_b32 %0, %1" : "+v"(a), "+v"(b));
}

// y[N][ystride] (bf16) = x[N][128 (stride xstride)] @ w[M][128]^T + b[M]
// For j0 >= 256 (the V block of the QKV projection), write TRANSPOSED into vt[128][N].
template<int XBF>
__global__ __launch_bounds__(256) void linear_kernel(
    const void* __restrict__ xA_, const float* __restrict__ wA, const float* __restrict__ bA, u16* __restrict__ yA,
    const void* __restrict__ xB_, const float* __restrict__ wB, const float* __restrict__ bB, u16* __restrict__ yB,
    u16* __restrict__ vtA_, u16* __restrict__ vtB_,
    int xstride, int ystride, int M, int N)
{
  const void* x_ = blockIdx.y ? xB_ : xA_;
  const float* w = blockIdx.y ? wB : wA;
  const float* b = blockIdx.y ? bB : bA;
  u16* y = blockIdx.y ? yB : yA;
  u16* vt = blockIdx.y ? vtB_ : vtA_;
  const int lane = threadIdx.x & 63, wid = threadIdx.x >> 6;
  const int g = lane >> 4, l15 = lane & 15;
  const int row0 = blockIdx.x * 64 + wid * 16;

  bf16x8 a[4];
  if (XBF) {
    const u16* xr = (const u16*)x_ + (size_t)(row0 + l15) * xstride;
    #pragma unroll
    for (int kk = 0; kk < 4; kk++) a[kk] = *(const bf16x8*)(xr + kk * 32 + g * 8);
  } else {
    const float* xr = (const float*)x_ + (size_t)(row0 + l15) * xstride;
    #pragma unroll
    for (int kk = 0; kk < 4; kk++) a[kk] = ld8f(xr + kk * 32 + g * 8);
  }

  const f32x4 fz = {0.f, 0.f, 0.f, 0.f};
  for (int j0 = 0; j0 < M; j0 += 16) {
    f32x4 acc = fz;
    const float* wr_ = w + (size_t)(j0 + l15) * 128;
    #pragma unroll
    for (int kk = 0; kk < 4; kk++)
      acc = MFMA(a[kk], ld8f(wr_ + kk * 32 + g * 8), acc);
    float bv = b[j0 + l15];
    if (j0 < 256 || vt == nullptr) {
      #pragma unroll
      for (int r = 0; r < 4; r++)
        y[(size_t)(row0 + g * 4 + r) * ystride + j0 + l15] = f2bf(acc[r] + bv);
    } else {
      bf16x4 o4;
      #pragma unroll
      for (int r = 0; r < 4; r++) o4[r] = (short)f2bf(acc[r] + bv);
      *(bf16x4*)(vt + (size_t)(j0 - 256 + l15) * N + row0 + g * 4) = o4;
    }
  }
}

// Flash attention, KV-split, swapped-QK^T, 32x32x16 MFMA, 32 q-rows/wave,
// P in registers via cvt_pk + permlane32_swap, defer-max rescale.
// grid = (N/128, SEG, 2 types), block = 256 (4 waves x 32 q-rows).
__global__ __launch_bounds__(256, 2) void flash_kernel(
    const u16* __restrict__ qkvA, const u16* __restrict__ vtA,
    const u16* __restrict__ qkvB, const u16* __restrict__ vtB,
    u16* __restrict__ part_acc, float* __restrict__ part_ml,
    int N, int segsz, int SEG)
{
  __shared__ __align__(16) u16 Kt[64 * 128];   // swizzled: idx = r*128 + (c ^ ((r&7)<<3))
  __shared__ __align__(16) u16 Vtt[128 * 64];  // swizzled: idx = r*64  + (c ^ ((r&7)<<3))
  const int ty = blockIdx.z;
  const u16* qkv = ty ? qkvB : qkvA;
  const u16* vt  = ty ? vtB  : vtA;
  const int lane = threadIdx.x & 63, wid = threadIdx.x >> 6;
  const int l31 = lane & 31, h = lane >> 5, l7 = lane & 7;
  const int q = blockIdx.x * 128 + wid * 32 + l31;
  const int seg = blockIdx.y;
  const int kvbase = seg * segsz;
  const float C = 0.088388347648318447f * 1.4426950408889634f; // scale*log2(e)
  const float THR = 8.0f / C;

  // Q^T B-fragments: lane holds Q[q][kk*16 + h*8 .. +7]
  bf16x8 aQ[8];
  const u16* qr = qkv + (size_t)q * 256;
  #pragma unroll
  for (int kk = 0; kk < 8; kk++) aQ[kk] = *(const bf16x8*)(qr + kk * 16 + h * 8);

  f32x16 accO[4];
  #pragma unroll
  for (int d = 0; d < 4; d++) accO[d] = (f32x16)0.f;
  float m_ = -INFINITY, l_ = 0.f;

  for (int kt = 0; kt < segsz; kt += 64) {
    const int kv0 = kvbase + kt;
    // stage K [64][128] and V^T [128][64], XOR-swizzled
    #pragma unroll
    for (int i = 0; i < 4; i++) {
      int ch = (int)threadIdx.x + i * 256;
      { int r = ch >> 4, c = (ch & 15) * 8;
        *(bf16x8*)&Kt[r * 128 + (c ^ ((r & 7) << 3))] =
            *(const bf16x8*)(qkv + 128 + (size_t)(kv0 + r) * 256 + c); }
      { int r = ch >> 3, c = (ch & 7) * 8;
        *(bf16x8*)&Vtt[r * 64 + (c ^ ((r & 7) << 3))] =
            *(const bf16x8*)(vt + (size_t)r * N + kv0 + c); }
    }
    __syncthreads();

    // S^T = K @ Q^T : C[kv][q], col q = lane&31, row kv = u*32 + 4h + (reg&3) + 8*(reg>>2)
    f32x16 sc[2];
    #pragma unroll
    for (int u = 0; u < 2; u++) sc[u] = (f32x16)0.f;
    #pragma unroll
    for (int kk = 0; kk < 8; kk++) {
      #pragma unroll
      for (int u = 0; u < 2; u++) {
        bf16x8 aK = *(bf16x8*)&Kt[(u * 32 + l31) * 128 + (((kk * 2 + h) * 8) ^ (l7 << 3))];
        sc[u] = MFMA32(aK, aQ[kk], sc[u]);
      }
    }

    // lane-local online softmax (q fixed per lane; lanes l and l+32 share q)
    float pmax = sc[0][0];
    #pragma unroll
    for (int u = 0; u < 2; u++)
      #pragma unroll
      for (int i = 0; i < 16; i++) pmax = fmaxf(pmax, sc[u][i]);
    pmax = fmaxf(pmax, __shfl_xor(pmax, 32));
    if (!__all(pmax - m_ <= THR)) {
      float nm = fmaxf(m_, pmax);
      float corr = __builtin_exp2f((m_ - nm) * C);
      m_ = nm; l_ *= corr;
      #pragma unroll
      for (int d = 0; d < 4; d++)
        #pragma unroll
        for (int i = 0; i < 16; i++) accO[d][i] *= corr;
    }
    float sum = 0.f;
    #pragma unroll
    for (int u = 0; u < 2; u++)
      #pragma unroll
      for (int i = 0; i < 16; i++) {
        float e = __builtin_exp2f((sc[u][i] - m_) * C);
        sc[u][i] = e; sum += e;
      }
    sum += __shfl_xor(sum, 32);
    l_ += sum;

    // O^T += V^T @ P^T ; P^T B-frags built in-register
    #pragma unroll
    for (int t = 0; t < 4; t++) {
      const int u = t >> 1, jA = (t & 1) * 2, jB = jA + 1;
      u32 a0 = cvtpk(sc[u][jA * 4 + 0], sc[u][jA * 4 + 1]);
      u32 b0 = cvtpk(sc[u][jB * 4 + 0], sc[u][jB * 4 + 1]);
      u32 a1 = cvtpk(sc[u][jA * 4 + 2], sc[u][jA * 4 + 3]);
      u32 b1 = cvtpk(sc[u][jB * 4 + 2], sc[u][jB * 4 + 3]);
      pl32swap(a0, b0);
      pl32swap(a1, b1);
      union { u32 w[4]; bf16x8 v; } pf;
      pf.w[0] = a0; pf.w[1] = a1; pf.w[2] = b0; pf.w[3] = b1;
      #pragma unroll
      for (int d = 0; d < 4; d++) {
        bf16x8 aV = *(bf16x8*)&Vtt[(d * 32 + l31) * 64 + (((t * 2 + h) * 8) ^ (l7 << 3))];
        accO[d] = MFMA32(aV, pf.v, accO[d]);
      }
    }
    __syncthreads();
  }

  // partial store [q][128] bf16 (unnormalized) + (m,l)
  const size_t pbase = ((size_t)(ty * SEG + seg) * N + q) * 128;
  #pragma unroll
  for (int d = 0; d < 4; d++)
    #pragma unroll
    for (int j = 0; j < 4; j++) {
      bf16x4 o4;
      #pragma unroll
      for (int r = 0; r < 4; r++) o4[r] = (short)f2bf(accO[d][j * 4 + r]);
      *(bf16x4*)(part_acc + pbase + d * 32 + j * 8 + h * 4) = o4;
    }
  if (h == 0) {
    float2 ml; ml.x = m_; ml.y = l_;
    *(float2*)(part_ml + ((size_t)(ty * SEG + seg) * N + q) * 2) = ml;
  }
}

// combine SEG partials -> o (bf16 [N][128]); grid (N/64, 2), block 256 (4 thr/row)
__global__ __launch_bounds__(256) void combine_kernel(
    const u16* __restrict__ part_acc, const float* __restrict__ part_ml,
    u16* __restrict__ oA_, u16* __restrict__ oB_, int N, int SEG)
{
  const int t = blockIdx.y;
  u16* o = t ? oB_ : oA_;
  const int row = blockIdx.x * 64 + ((int)threadIdx.x >> 2);
  const int qt = threadIdx.x & 3;
  const float C = 0.088388347648318447f * 1.4426950408889634f;

  float m = -INFINITY;
  for (int s = 0; s < SEG; s++)
    m = fmaxf(m, part_ml[((size_t)(t * SEG + s) * N + row) * 2]);
  float l = 0.f;
  float acc[32];
  #pragma unroll
  for (int i = 0; i < 32; i++) acc[i] = 0.f;
  for (int s = 0; s < SEG; s++) {
    const float* ml = part_ml + ((size_t)(t * SEG + s) * N + row) * 2;
    float w = __builtin_exp2f((ml[0] - m) * C);
    l += w * ml[1];
    const u16* pa = part_acc + ((size_t)(t * SEG + s) * N + row) * 128 + qt * 32;
    #pragma unroll
    for (int j = 0; j < 4; j++) {
      bf16x8 vch = *(const bf16x8*)(pa + j * 8);
      #pragma unroll
      for (int i = 0; i < 8; i++) acc[j * 8 + i] += w * bf2f((u16)vch[i]);
    }
  }
  const float inv = 1.f / l;
  #pragma unroll
  for (int j = 0; j < 4; j++) {
    bf16x8 oc;
    #pragma unroll
    for (int i = 0; i < 8; i++) oc[i] = (short)f2bf(acc[j * 8 + i] * inv);
    *(bf16x8*)(o + (size_t)row * 128 + qt * 32 + j * 8) = oc;
  }
}

// ---- segment-sum via counting sort (no f32 atomics) ----
__global__ __launch_bounds__(256) void hist_kernel(
    const int* __restrict__ e0, const int* __restrict__ e1, const int* __restrict__ e2,
    int* __restrict__ cnt, int Nn, int E)
{
  const int t = blockIdx.y;
  const int* ei = t == 0 ? e0 : (t == 1 ? e1 : e2);
  int e = blockIdx.x * 256 + threadIdx.x;
  if (e >= E) return;
  atomicAdd(&cnt[t * Nn + ei[E + e]], 1);
}

__global__ __launch_bounds__(1024) void scan_kernel(
    const int* __restrict__ cnt, int* __restrict__ off, int* __restrict__ work, int Nn)
{
  const int t = blockIdx.x;
  const int* c = cnt + t * Nn;
  int* o = off + t * (Nn + 1);
  int* w = work + t * Nn;
  __shared__ int part[1024];
  const int tid = threadIdx.x;
  const int base = tid * 8;
  int loc[8], s = 0;
  #pragma unroll
  for (int i = 0; i < 8; i++) { loc[i] = s; s += c[base + i]; }
  part[tid] = s;
  __syncthreads();
  #pragma unroll
  for (int st = 1; st < 1024; st <<= 1) {
    int v = (tid >= st) ? part[tid - st] : 0;
    __syncthreads();
    part[tid] += v;
    __syncthreads();
  }
  int pre = (tid == 0) ? 0 : part[tid - 1];
  #pragma unroll
  for (int i = 0; i < 8; i++) { int p = pre + loc[i]; o[base + i] = p; w[base + i] = p; }
  if (tid == 1023) o[Nn] = part[1023];
}

__global__ __launch_bounds__(256) void sortedges_kernel(
    const int* __restrict__ e0, const int* __restrict__ e1, const int* __restrict__ e2,
    int* __restrict__ work, int* __restrict__ ssrc, int Nn, int E)
{
  const int t = blockIdx.y;
  const int* ei = t == 0 ? e0 : (t == 1 ? e1 : e2);
  int e = blockIdx.x * 256 + threadIdx.x;
  if (e >= E) return;
  int s = ei[e], d = ei[E + e];
  int pos = atomicAdd(&work[t * Nn + d], 1);
  ssrc[(size_t)t * E + pos] = s;
}

__global__ __launch_bounds__(256) void aggregate_kernel(
    const u16* __restrict__ h0, const u16* __restrict__ h1, const u16* __restrict__ h2,
    const int* __restrict__ off, const int* __restrict__ ssrc,
    float* __restrict__ agg, int Nn, int E)
{
  const int t = blockIdx.y;
  const u16* h = t == 0 ? h0 : (t == 1 ? h1 : h2);
  const int* o = off + t * (Nn + 1);
  const int* ss = ssrc + (size_t)t * E;
  float* a = agg + (size_t)t * Nn * 128;
  const int wid = threadIdx.x >> 6, lane = threadIdx.x & 63;
  const int d = blockIdx.x * 4 + wid;
  const int s0 = o[d], s1 = o[d + 1];
  float a0 = 0.f, a1 = 0.f;
  int e = s0;
  for (; e + 3 < s1; e += 4) {
    int r0 = ss[e], r1 = ss[e + 1], r2 = ss[e + 2], r3 = ss[e + 3];
    u32 v0 = *(const u32*)(h + (size_t)r0 * 128 + lane * 2);
    u32 v1 = *(const u32*)(h + (size_t)r1 * 128 + lane * 2);
    u32 v2 = *(const u32*)(h + (size_t)r2 * 128 + lane * 2);
    u32 v3 = *(const u32*)(h + (size_t)r3 * 128 + lane * 2);
    a0 += bf2f((u16)(v0 & 0xffff)) + bf2f((u16)(v1 & 0xffff)) + bf2f((u16)(v2 & 0xffff)) + bf2f((u16)(v3 & 0xffff));
    a1 += bf2f((u16)(v0 >> 16)) + bf2f((u16)(v1 >> 16)) + bf2f((u16)(v2 >> 16)) + bf2f((u16)(v3 >> 16));
  }
  for (; e < s1; e++) {
    u32 v = *(const u32*)(h + (size_t)ss[e] * 128 + lane * 2);
    a0 += bf2f((u16)(v & 0xffff));
    a1 += bf2f((u16)(v >> 16));
  }
  a[(size_t)d * 128 + lane * 2] = a0;
  a[(size_t)d * 128 + lane * 2 + 1] = a1;
}

__global__ __launch_bounds__(256) void sage_out_kernel(
    const float* __restrict__ agg1, const float* __restrict__ wl1, const float* __restrict__ bl1,
    const u16* __restrict__ h1, const float* __restrict__ wr1,
    const float* __restrict__ agg2, const float* __restrict__ wl2, const float* __restrict__ bl2,
    const u16* __restrict__ h2, const float* __restrict__ wr2,
    float* __restrict__ out)
{
  const int lane = threadIdx.x & 63, wid = threadIdx.x >> 6;
  const int g = lane >> 4, l15 = lane & 15;
  const int row0 = blockIdx.x * 64 + wid * 16;
  const bool two = (agg2 != nullptr);

  bf16x8 a1[4], aH1[4], a2[4], aH2[4];
  const float* ar1 = agg1 + (size_t)(row0 + l15) * 128;
  const u16* hr1 = h1 + (size_t)(row0 + l15) * 128;
  #pragma unroll
  for (int kk = 0; kk < 4; kk++) {
    a1[kk] = ld8f(ar1 + kk * 32 + g * 8);
    aH1[kk] = *(const bf16x8*)(hr1 + kk * 32 + g * 8);
  }
  if (two) {
    const float* ar2 = agg2 + (size_t)(row0 + l15) * 128;
    const u16* hr2 = h2 + (size_t)(row0 + l15) * 128;
    #pragma unroll
    for (int kk = 0; kk < 4; kk++) {
      a2[kk] = ld8f(ar2 + kk * 32 + g * 8);
      aH2[kk] = *(const bf16x8*)(hr2 + kk * 32 + g * 8);
    }
  }

  const f32x4 fz = {0.f, 0.f, 0.f, 0.f};
  for (int j0 = 0; j0 < 128; j0 += 16) {
    f32x4 acc = fz;
    const float* w1 = wl1 + (size_t)(j0 + l15) * 128;
    const float* w2 = wr1 + (size_t)(j0 + l15) * 128;
    #pragma unroll
    for (int kk = 0; kk < 4; kk++) {
      acc = MFMA(a1[kk], ld8f(w1 + kk * 32 + g * 8), acc);
      acc = MFMA(aH1[kk], ld8f(w2 + kk * 32 + g * 8), acc);
    }
    float bias = bl1[j0 + l15];
    if (two) {
      const float* w3 = wl2 + (size_t)(j0 + l15) * 128;
      const float* w4 = wr2 + (size_t)(j0 + l15) * 128;
      #pragma unroll
      for (int kk = 0; kk < 4; kk++) {
        acc = MFMA(a2[kk], ld8f(w3 + kk * 32 + g * 8), acc);
        acc = MFMA(aH2[kk], ld8f(w4 + kk * 32 + g * 8), acc);
      }
      bias += bl2[j0 + l15];
    }
    #pragma unroll
    for (int r = 0; r < 4; r++)
      out[(size_t)(row0 + g * 4 + r) * 768 + j0 + l15] = acc[r] + bias;
  }
}

__global__ __launch_bounds__(256) void tail_kernel(
    const float* __restrict__ xA, float* __restrict__ oA,
    const float* __restrict__ xB, float* __restrict__ oB, int total)
{
  const float* x = blockIdx.y ? xB : xA;
  float* o = blockIdx.y ? oB : oA;
  int tid = blockIdx.x * 256 + threadIdx.x;
  if (tid >= total) return;
  int n = tid / 160, r = tid % 160;
  size_t off = (size_t)n * 768 + 128 + (size_t)r * 4;
  *(f32x4*)(o + off) = *(const f32x4*)(x + off);
}

extern "C" void kernel_launch(void* const* d_in, const int* in_sizes, int n_in,
                              void* d_out, int out_size, void* d_ws, size_t ws_size,
                              hipStream_t stream)
{
  const int D = 128, C = 6;
  const int N = in_sizes[0] / (C * D);   // 8192
  const int E = in_sizes[2] / 2;         // 262144

  const float* xA = (const float*)d_in[0];
  const float* xB = (const float*)d_in[1];
  const int* eiAB = (const int*)d_in[2];
  const int* eiBA = (const int*)d_in[3];
  const int* eiAA = (const int*)d_in[4];
  const float* inW_A  = (const float*)d_in[5];
  const float* inB_A  = (const float*)d_in[6];
  const float* outW_A = (const float*)d_in[7];
  const float* outB_A = (const float*)d_in[8];
  const float* inW_B  = (const float*)d_in[9];
  const float* inB_B  = (const float*)d_in[10];
  const float* outW_B = (const float*)d_in[11];
  const float* outB_B = (const float*)d_in[12];
  const float* wlAB = (const float*)d_in[13];
  const float* blAB = (const float*)d_in[14];
  const float* wrAB = (const float*)d_in[15];
  const float* wlBA = (const float*)d_in[16];
  const float* blBA = (const float*)d_in[17];
  const float* wrBA = (const float*)d_in[18];
  const float* wlAA = (const float*)d_in[19];
  const float* blAA = (const float*)d_in[20];
  const float* wrAA = (const float*)d_in[21];

  // ---- workspace carve ----
  // persistent: qkv (q,k only, stride 256), vt, o, h
  u16* qkvA = (u16*)d_ws;
  u16* qkvB = qkvA + (size_t)N * 256;
  u16* vtA  = qkvB + (size_t)N * 256;
  u16* vtB  = vtA + (size_t)D * N;
  u16* oA_  = vtB + (size_t)D * N;
  u16* oB_  = oA_ + (size_t)N * D;
  u16* hA   = oB_ + (size_t)N * D;
  u16* hB   = hA + (size_t)N * D;
  // union region: flash partials (phase 1) OR agg+sort scratch (phase 2)
  char* uni = (char*)(hB + (size_t)N * D);
  size_t base_b = (size_t)((char*)uni - (char*)d_ws);
  size_t aggsort_b = (size_t)3 * N * 128 * 4 + (size_t)(3 * N + 3 * (N + 1) + 3 * N) * 4 + (size_t)3 * E * 4;
  auto part_b = [&](int S){ return (size_t)2 * S * N * 128 * 2 + (size_t)2 * S * N * 2 * 4; };
  int SEG = 8;
  while (SEG > 1 && ws_size < base_b + (part_b(SEG) > aggsort_b ? part_b(SEG) : aggsort_b)) SEG >>= 1;
  const int segsz = N / SEG;
  // view 1: partials
  u16* part_acc = (u16*)uni;
  float* part_ml = (float*)(part_acc + (size_t)2 * SEG * N * 128);
  // view 2: agg + sort
  float* aggAB = (float*)uni;
  float* aggBA = aggAB + (size_t)N * D;
  float* aggAA = aggBA + (size_t)N * D;
  int* cnt  = (int*)(aggAA + (size_t)N * D);
  int* off  = cnt + 3 * N;
  int* work = off + 3 * (N + 1);
  int* ssrc = work + 3 * N;

  float* outA = (float*)d_out;
  float* outB = outA + (size_t)N * C * D;

  dim3 blk(256);
  // 1. qkv = x0 @ inW^T + inB ; V written transposed into vt
  linear_kernel<0><<<dim3(N / 64, 2), blk, 0, stream>>>(xA, inW_A, inB_A, qkvA,
                                                        xB, inW_B, inB_B, qkvB,
                                                        vtA, vtB, C * D, 256, 384, N);
  // 2. flash attention partials (KV-split)
  flash_kernel<<<dim3(N / 128, SEG, 2), blk, 0, stream>>>(qkvA, vtA, qkvB, vtB,
                                                          part_acc, part_ml, N, segsz, SEG);
  // 2b. combine partials -> o (bf16)
  combine_kernel<<<dim3(N / 64, 2), blk, 0, stream>>>(part_acc, part_ml, oA_, oB_, N, SEG);
  // 3. h = o @ outW^T + outB
  linear_kernel<1><<<dim3(N / 64, 2), blk, 0, stream>>>(oA_, outW_A, outB_A, hA,
                                                        oB_, outW_B, outB_B, hB,
                                                        nullptr, nullptr, 128, 128, 128, N);
  // 4. segment sums via counting sort (types: 0=AB(h=A), 1=BA(h=B), 2=AA(h=A))
  (void)hipMemsetAsync(cnt, 0, (size_t)3 * N * sizeof(int), stream);
  hist_kernel<<<dim3((E + 255) / 256, 3), blk, 0, stream>>>(eiAB, eiBA, eiAA, cnt, N, E);
  scan_kernel<<<dim3(3), dim3(1024), 0, stream>>>(cnt, off, work, N);
  sortedges_kernel<<<dim3((E + 255) / 256, 3), blk, 0, stream>>>(eiAB, eiBA, eiAA, work, ssrc, N, E);
  aggregate_kernel<<<dim3(N / 4, 3), blk, 0, stream>>>(hA, hB, hA, off, ssrc, aggAB, N, E);
  // 5. sage outputs into column 0 (f32)
  sage_out_kernel<<<dim3(N / 64), blk, 0, stream>>>(aggAB, wlAB, blAB, hB, wrAB,
                                                    nullptr, nullptr, nullptr, nullptr, nullptr, outB);
  sage_out_kernel<<<dim3(N / 64), blk, 0, stream>>>(aggBA, wlBA, blBA, hA, wrBA,
                                                    aggAA, wlAA, blAA, hA, wrAA, outA);
  // 6. tail columns 1..5 (f32 copy)
  int total = N * 160;
  tail_kernel<<<dim3((total + 255) / 256, 2), blk, 0, stream>>>(xA, outA, xB, outB, total);
}

// Round 6
// 317.071 us; speedup vs baseline: 9.9335x; 1.0437x over previous
//
#include <hip/hip_runtime.h>
#include <hip/hip_bf16.h>

typedef unsigned short u16;
typedef unsigned int u32;
typedef __attribute__((ext_vector_type(8))) short bf16x8;
typedef __attribute__((ext_vector_type(4))) short bf16x4;
typedef __attribute__((ext_vector_type(4))) float f32x4;
typedef __attribute__((ext_vector_type(16))) float f32x16;

#define MFMA(a,b,c)   __builtin_amdgcn_mfma_f32_16x16x32_bf16((a),(b),(c),0,0,0)
#define MFMA32(a,b,c) __builtin_amdgcn_mfma_f32_32x32x16_bf16((a),(b),(c),0,0,0)

__device__ __forceinline__ float bf2f(u16 u){
  union { float f; u32 i; } c; c.i = ((u32)u) << 16; return c.f;
}
__device__ __forceinline__ u16 f2bf(float f){
  __hip_bfloat16 h = __float2bfloat16(f);
  u16 u; __builtin_memcpy(&u, &h, 2); return u;
}
__device__ __forceinline__ bf16x8 ld8f(const float* p){
  bf16x8 r;
  #pragma unroll
  for (int i = 0; i < 8; i++) r[i] = (short)f2bf(p[i]);
  return r;
}
__device__ __forceinline__ u32 cvtpk(float a, float b){
  u32 r; asm volatile("v_cvt_pk_bf16_f32 %0, %1, %2" : "=v"(r) : "v"(a), "v"(b)); return r;
}
__device__ __forceinline__ void pl32swap(u32 &a, u32 &b){
  asm volatile("v_permlane32_swap_b32 %0, %1" : "+v"(a), "+v"(b));
}

// ---- weight pre-conversion f32 -> bf16 (10 matrices, one kernel) ----
struct WPrepArgs { const float* src[10]; int off[10]; int total4; };
__global__ __launch_bounds__(256) void wprep_kernel(WPrepArgs a, u16* __restrict__ dst)
{
  int i = blockIdx.x * 256 + threadIdx.x;
  if (i >= a.total4) return;
  int e = i * 4;
  int j = 0;
  #pragma unroll
  for (int k = 1; k < 10; k++) if (e >= a.off[k]) j = k;
  const float* s = a.src[j] + (e - a.off[j]);
  f32x4 v = *(const f32x4*)s;
  bf16x4 o;
  #pragma unroll
  for (int r = 0; r < 4; r++) o[r] = (short)f2bf(v[r]);
  *(bf16x4*)(dst + e) = o;
}

// y[N][ystride] (bf16) = x[N][128 (stride xstride)] @ w[M][128]^T + b[M]  (w bf16)
// For j0 >= 256 (V block of QKV), write TRANSPOSED into vt[128][N].
template<int XBF>
__global__ __launch_bounds__(256) void linear_kernel(
    const void* __restrict__ xA_, const u16* __restrict__ wA, const float* __restrict__ bA, u16* __restrict__ yA,
    const void* __restrict__ xB_, const u16* __restrict__ wB, const float* __restrict__ bB, u16* __restrict__ yB,
    u16* __restrict__ vtA_, u16* __restrict__ vtB_,
    int xstride, int ystride, int M, int N)
{
  const void* x_ = blockIdx.y ? xB_ : xA_;
  const u16* w = blockIdx.y ? wB : wA;
  const float* b = blockIdx.y ? bB : bA;
  u16* y = blockIdx.y ? yB : yA;
  u16* vt = blockIdx.y ? vtB_ : vtA_;
  const int lane = threadIdx.x & 63, wid = threadIdx.x >> 6;
  const int g = lane >> 4, l15 = lane & 15;
  const int row0 = blockIdx.x * 64 + wid * 16;

  bf16x8 a[4];
  if (XBF) {
    const u16* xr = (const u16*)x_ + (size_t)(row0 + l15) * xstride;
    #pragma unroll
    for (int kk = 0; kk < 4; kk++) a[kk] = *(const bf16x8*)(xr + kk * 32 + g * 8);
  } else {
    const float* xr = (const float*)x_ + (size_t)(row0 + l15) * xstride;
    #pragma unroll
    for (int kk = 0; kk < 4; kk++) a[kk] = ld8f(xr + kk * 32 + g * 8);
  }

  const f32x4 fz = {0.f, 0.f, 0.f, 0.f};
  for (int j0 = 0; j0 < M; j0 += 16) {
    f32x4 acc = fz;
    const u16* wr_ = w + (size_t)(j0 + l15) * 128;
    #pragma unroll
    for (int kk = 0; kk < 4; kk++)
      acc = MFMA(a[kk], *(const bf16x8*)(wr_ + kk * 32 + g * 8), acc);
    float bv = b[j0 + l15];
    if (j0 < 256 || vt == nullptr) {
      #pragma unroll
      for (int r = 0; r < 4; r++)
        y[(size_t)(row0 + g * 4 + r) * ystride + j0 + l15] = f2bf(acc[r] + bv);
    } else {
      bf16x4 o4;
      #pragma unroll
      for (int r = 0; r < 4; r++) o4[r] = (short)f2bf(acc[r] + bv);
      *(bf16x4*)(vt + (size_t)(j0 - 256 + l15) * N + row0 + g * 4) = o4;
    }
  }
}

// Flash attention, KV-split, swapped-QK^T, 32x32x16 MFMA, 64 q-rows/wave (2 q-groups),
// P in registers via cvt_pk + permlane32_swap, defer-max, 32-kv softmax substeps.
// grid = (N/256, SEG, 2 types), block = 256 (4 waves x 64 q-rows).
__global__ __launch_bounds__(256, 2) void flash_kernel(
    const u16* __restrict__ qkvA, const u16* __restrict__ vtA,
    const u16* __restrict__ qkvB, const u16* __restrict__ vtB,
    u16* __restrict__ part_acc, float* __restrict__ part_ml,
    int N, int segsz, int SEG)
{
  __shared__ __align__(16) u16 Kt[64 * 128];   // idx = r*128 + (c ^ ((r&7)<<3))
  __shared__ __align__(16) u16 Vtt[128 * 64];  // idx = r*64  + (c ^ ((r&7)<<3))
  const int ty = blockIdx.z;
  const u16* qkv = ty ? qkvB : qkvA;
  const u16* vt  = ty ? vtB  : vtA;
  const int lane = threadIdx.x & 63, wid = threadIdx.x >> 6;
  const int l31 = lane & 31, h = lane >> 5, l7 = lane & 7;
  const int qbase = blockIdx.x * 256 + wid * 64;
  const int seg = blockIdx.y;
  const int kvbase = seg * segsz;
  const float C = 0.088388347648318447f * 1.4426950408889634f; // scale*log2(e)
  const float THR = 8.0f / C;

  bf16x8 aQ[2][8];
  #pragma unroll
  for (int qg = 0; qg < 2; qg++) {
    const u16* qr = qkv + (size_t)(qbase + qg * 32 + l31) * 256;
    #pragma unroll
    for (int kk = 0; kk < 8; kk++) aQ[qg][kk] = *(const bf16x8*)(qr + kk * 16 + h * 8);
  }

  f32x16 accO[2][4];
  #pragma unroll
  for (int qg = 0; qg < 2; qg++)
    #pragma unroll
    for (int db = 0; db < 4; db++) accO[qg][db] = (f32x16)0.f;
  float m_[2] = {-INFINITY, -INFINITY}, l_[2] = {0.f, 0.f};

  for (int kt = 0; kt < segsz; kt += 64) {
    const int kv0 = kvbase + kt;
    #pragma unroll
    for (int i = 0; i < 4; i++) {
      int ch = (int)threadIdx.x + i * 256;
      { int r = ch >> 4, c = (ch & 15) * 8;
        *(bf16x8*)&Kt[r * 128 + (c ^ ((r & 7) << 3))] =
            *(const bf16x8*)(qkv + 128 + (size_t)(kv0 + r) * 256 + c); }
      { int r = ch >> 3, c = (ch & 7) * 8;
        *(bf16x8*)&Vtt[r * 64 + (c ^ ((r & 7) << 3))] =
            *(const bf16x8*)(vt + (size_t)r * N + kv0 + c); }
    }
    __syncthreads();

    #pragma unroll
    for (int u = 0; u < 2; u++) {
      // S^T for kv-half u: C[kv][q], col q = l31, row kv = u*32 + 4h + (reg&3) + 8*(reg>>2)
      f32x16 sc[2];
      sc[0] = (f32x16)0.f; sc[1] = (f32x16)0.f;
      #pragma unroll
      for (int kk = 0; kk < 8; kk++) {
        bf16x8 aK = *(bf16x8*)&Kt[(u * 32 + l31) * 128 + (((kk * 2 + h) * 8) ^ (l7 << 3))];
        sc[0] = MFMA32(aK, aQ[0][kk], sc[0]);
        sc[1] = MFMA32(aK, aQ[1][kk], sc[1]);
      }
      // lane-local online softmax per q-group
      #pragma unroll
      for (int qg = 0; qg < 2; qg++) {
        float pmax = sc[qg][0];
        #pragma unroll
        for (int i = 1; i < 16; i++) pmax = fmaxf(pmax, sc[qg][i]);
        pmax = fmaxf(pmax, __shfl_xor(pmax, 32));
        if (!__all(pmax - m_[qg] <= THR)) {
          float nm = fmaxf(m_[qg], pmax);
          float corr = __builtin_exp2f((m_[qg] - nm) * C);
          m_[qg] = nm; l_[qg] *= corr;
          #pragma unroll
          for (int db = 0; db < 4; db++)
            #pragma unroll
            for (int i = 0; i < 16; i++) accO[qg][db][i] *= corr;
        }
        float sum = 0.f;
        #pragma unroll
        for (int i = 0; i < 16; i++) {
          float e = __builtin_exp2f((sc[qg][i] - m_[qg]) * C);
          sc[qg][i] = e; sum += e;
        }
        sum += __shfl_xor(sum, 32);
        l_[qg] += sum;
      }
      // PV: O^T += V^T @ P^T ; aV shared across both q-groups
      #pragma unroll
      for (int tt = 0; tt < 2; tt++) {
        bf16x8 pf[2];
        #pragma unroll
        for (int qg = 0; qg < 2; qg++) {
          u32 a0 = cvtpk(sc[qg][(tt * 2) * 4 + 0], sc[qg][(tt * 2) * 4 + 1]);
          u32 b0 = cvtpk(sc[qg][(tt * 2 + 1) * 4 + 0], sc[qg][(tt * 2 + 1) * 4 + 1]);
          u32 a1 = cvtpk(sc[qg][(tt * 2) * 4 + 2], sc[qg][(tt * 2) * 4 + 3]);
          u32 b1 = cvtpk(sc[qg][(tt * 2 + 1) * 4 + 2], sc[qg][(tt * 2 + 1) * 4 + 3]);
          pl32swap(a0, b0); pl32swap(a1, b1);
          union { u32 w[4]; bf16x8 v; } u_;
          u_.w[0] = a0; u_.w[1] = a1; u_.w[2] = b0; u_.w[3] = b1;
          pf[qg] = u_.v;
        }
        const int tg = u * 2 + tt;
        #pragma unroll
        for (int db = 0; db < 4; db++) {
          bf16x8 aV = *(bf16x8*)&Vtt[(db * 32 + l31) * 64 + (((tg * 2 + h) * 8) ^ (l7 << 3))];
          accO[0][db] = MFMA32(aV, pf[0], accO[0][db]);
          accO[1][db] = MFMA32(aV, pf[1], accO[1][db]);
        }
      }
    }
    __syncthreads();
  }

  #pragma unroll
  for (int qg = 0; qg < 2; qg++) {
    const int q = qbase + qg * 32 + l31;
    const size_t pbase = ((size_t)(ty * SEG + seg) * N + q) * 128;
    #pragma unroll
    for (int d = 0; d < 4; d++)
      #pragma unroll
      for (int j = 0; j < 4; j++) {
        bf16x4 o4;
        #pragma unroll
        for (int r = 0; r < 4; r++) o4[r] = (short)f2bf(accO[qg][d][j * 4 + r]);
        *(bf16x4*)(part_acc + pbase + d * 32 + j * 8 + h * 4) = o4;
      }
    if (h == 0) {
      float2 ml; ml.x = m_[qg]; ml.y = l_[qg];
      *(float2*)(part_ml + ((size_t)(ty * SEG + seg) * N + q) * 2) = ml;
    }
  }
}

// combine SEG partials -> o-tile in LDS, then h = o @ outW^T + outB (fused).
// grid (N/64, 2), block 256.
__global__ __launch_bounds__(256) void combine_hproj_kernel(
    const u16* __restrict__ part_acc, const float* __restrict__ part_ml,
    const u16* __restrict__ woutA, const float* __restrict__ boutA, u16* __restrict__ hA,
    const u16* __restrict__ woutB, const float* __restrict__ boutB, u16* __restrict__ hB,
    int N, int SEG)
{
  __shared__ __align__(16) u16 ot[64 * 136];
  const int t = blockIdx.y;
  const u16* w = t ? woutB : woutA;
  const float* bb = t ? boutB : boutA;
  u16* hOut = t ? hB : hA;
  const int tid = threadIdx.x;
  const int row = tid >> 2, qt = tid & 3;
  const int grow = blockIdx.x * 64 + row;
  const float C = 0.088388347648318447f * 1.4426950408889634f;

  float m = -INFINITY;
  for (int s = 0; s < SEG; s++)
    m = fmaxf(m, part_ml[((size_t)(t * SEG + s) * N + grow) * 2]);
  float l = 0.f;
  float acc[32];
  #pragma unroll
  for (int i = 0; i < 32; i++) acc[i] = 0.f;
  for (int s = 0; s < SEG; s++) {
    const float* ml = part_ml + ((size_t)(t * SEG + s) * N + grow) * 2;
    float w8 = __builtin_exp2f((ml[0] - m) * C);
    l += w8 * ml[1];
    const u16* pa = part_acc + ((size_t)(t * SEG + s) * N + grow) * 128 + qt * 32;
    #pragma unroll
    for (int j = 0; j < 4; j++) {
      bf16x8 vch = *(const bf16x8*)(pa + j * 8);
      #pragma unroll
      for (int i = 0; i < 8; i++) acc[j * 8 + i] += w8 * bf2f((u16)vch[i]);
    }
  }
  const float inv = 1.f / l;
  #pragma unroll
  for (int j = 0; j < 4; j++) {
    bf16x8 oc;
    #pragma unroll
    for (int i = 0; i < 8; i++) oc[i] = (short)f2bf(acc[j * 8 + i] * inv);
    *(bf16x8*)&ot[row * 136 + qt * 32 + j * 8] = oc;
  }
  __syncthreads();

  const int lane = tid & 63, wid = tid >> 6;
  const int g = lane >> 4, l15 = lane & 15;
  const int row0 = wid * 16;
  bf16x8 a[4];
  #pragma unroll
  for (int kk = 0; kk < 4; kk++) a[kk] = *(bf16x8*)&ot[(row0 + l15) * 136 + kk * 32 + g * 8];
  const f32x4 fz = {0.f, 0.f, 0.f, 0.f};
  for (int j0 = 0; j0 < 128; j0 += 16) {
    f32x4 acc2 = fz;
    const u16* wr_ = w + (size_t)(j0 + l15) * 128;
    #pragma unroll
    for (int kk = 0; kk < 4; kk++)
      acc2 = MFMA(a[kk], *(const bf16x8*)(wr_ + kk * 32 + g * 8), acc2);
    float bv = bb[j0 + l15];
    #pragma unroll
    for (int r = 0; r < 4; r++)
      hOut[(size_t)(blockIdx.x * 64 + row0 + g * 4 + r) * 128 + j0 + l15] = f2bf(acc2[r] + bv);
  }
}

// ---- segment-sum via counting sort (no f32 atomics) ----
__global__ __launch_bounds__(256) void hist_kernel(
    const int* __restrict__ e0, const int* __restrict__ e1, const int* __restrict__ e2,
    int* __restrict__ cnt, int Nn, int E)
{
  const int t = blockIdx.y;
  const int* ei = t == 0 ? e0 : (t == 1 ? e1 : e2);
  int e = blockIdx.x * 256 + threadIdx.x;
  if (e >= E) return;
  atomicAdd(&cnt[t * Nn + ei[E + e]], 1);
}

__global__ __launch_bounds__(1024) void scan_kernel(
    const int* __restrict__ cnt, int* __restrict__ off, int* __restrict__ work, int Nn)
{
  const int t = blockIdx.x;
  const int* c = cnt + t * Nn;
  int* o = off + t * (Nn + 1);
  int* w = work + t * Nn;
  __shared__ int part[1024];
  const int tid = threadIdx.x;
  const int base = tid * 8;
  int loc[8], s = 0;
  #pragma unroll
  for (int i = 0; i < 8; i++) { loc[i] = s; s += c[base + i]; }
  part[tid] = s;
  __syncthreads();
  #pragma unroll
  for (int st = 1; st < 1024; st <<= 1) {
    int v = (tid >= st) ? part[tid - st] : 0;
    __syncthreads();
    part[tid] += v;
    __syncthreads();
  }
  int pre = (tid == 0) ? 0 : part[tid - 1];
  #pragma unroll
  for (int i = 0; i < 8; i++) { int p = pre + loc[i]; o[base + i] = p; w[base + i] = p; }
  if (tid == 1023) o[Nn] = part[1023];
}

__global__ __launch_bounds__(256) void sortedges_kernel(
    const int* __restrict__ e0, const int* __restrict__ e1, const int* __restrict__ e2,
    int* __restrict__ work, int* __restrict__ ssrc, int Nn, int E)
{
  const int t = blockIdx.y;
  const int* ei = t == 0 ? e0 : (t == 1 ? e1 : e2);
  int e = blockIdx.x * 256 + threadIdx.x;
  if (e >= E) return;
  int s = ei[e], d = ei[E + e];
  int pos = atomicAdd(&work[t * Nn + d], 1);
  ssrc[(size_t)t * E + pos] = s;
}

__global__ __launch_bounds__(256) void aggregate_kernel(
    const u16* __restrict__ h0, const u16* __restrict__ h1, const u16* __restrict__ h2,
    const int* __restrict__ off, const int* __restrict__ ssrc,
    float* __restrict__ agg, int Nn, int E)
{
  const int t = blockIdx.y;
  const u16* h = t == 0 ? h0 : (t == 1 ? h1 : h2);
  const int* o = off + t * (Nn + 1);
  const int* ss = ssrc + (size_t)t * E;
  float* a = agg + (size_t)t * Nn * 128;
  const int wid = threadIdx.x >> 6, lane = threadIdx.x & 63;
  const int d = blockIdx.x * 4 + wid;
  const int s0 = o[d], s1 = o[d + 1];
  float a0 = 0.f, a1 = 0.f;
  int e = s0;
  for (; e + 3 < s1; e += 4) {
    int r0 = ss[e], r1 = ss[e + 1], r2 = ss[e + 2], r3 = ss[e + 3];
    u32 v0 = *(const u32*)(h + (size_t)r0 * 128 + lane * 2);
    u32 v1 = *(const u32*)(h + (size_t)r1 * 128 + lane * 2);
    u32 v2 = *(const u32*)(h + (size_t)r2 * 128 + lane * 2);
    u32 v3 = *(const u32*)(h + (size_t)r3 * 128 + lane * 2);
    a0 += bf2f((u16)(v0 & 0xffff)) + bf2f((u16)(v1 & 0xffff)) + bf2f((u16)(v2 & 0xffff)) + bf2f((u16)(v3 & 0xffff));
    a1 += bf2f((u16)(v0 >> 16)) + bf2f((u16)(v1 >> 16)) + bf2f((u16)(v2 >> 16)) + bf2f((u16)(v3 >> 16));
  }
  for (; e < s1; e++) {
    u32 v = *(const u32*)(h + (size_t)ss[e] * 128 + lane * 2);
    a0 += bf2f((u16)(v & 0xffff));
    a1 += bf2f((u16)(v >> 16));
  }
  a[(size_t)d * 128 + lane * 2] = a0;
  a[(size_t)d * 128 + lane * 2 + 1] = a1;
}

__global__ __launch_bounds__(256) void sage_out_kernel(
    const float* __restrict__ agg1, const u16* __restrict__ wl1, const float* __restrict__ bl1,
    const u16* __restrict__ h1, const u16* __restrict__ wr1,
    const float* __restrict__ agg2, const u16* __restrict__ wl2, const float* __restrict__ bl2,
    const u16* __restrict__ h2, const u16* __restrict__ wr2,
    float* __restrict__ out)
{
  const int lane = threadIdx.x & 63, wid = threadIdx.x >> 6;
  const int g = lane >> 4, l15 = lane & 15;
  const int row0 = blockIdx.x * 64 + wid * 16;
  const bool two = (agg2 != nullptr);

  bf16x8 a1[4], aH1[4], a2[4], aH2[4];
  const float* ar1 = agg1 + (size_t)(row0 + l15) * 128;
  const u16* hr1 = h1 + (size_t)(row0 + l15) * 128;
  #pragma unroll
  for (int kk = 0; kk < 4; kk++) {
    a1[kk] = ld8f(ar1 + kk * 32 + g * 8);
    aH1[kk] = *(const bf16x8*)(hr1 + kk * 32 + g * 8);
  }
  if (two) {
    const float* ar2 = agg2 + (size_t)(row0 + l15) * 128;
    const u16* hr2 = h2 + (size_t)(row0 + l15) * 128;
    #pragma unroll
    for (int kk = 0; kk < 4; kk++) {
      a2[kk] = ld8f(ar2 + kk * 32 + g * 8);
      aH2[kk] = *(const bf16x8*)(hr2 + kk * 32 + g * 8);
    }
  }

  const f32x4 fz = {0.f, 0.f, 0.f, 0.f};
  for (int j0 = 0; j0 < 128; j0 += 16) {
    f32x4 acc = fz;
    const u16* w1 = wl1 + (size_t)(j0 + l15) * 128;
    const u16* w2 = wr1 + (size_t)(j0 + l15) * 128;
    #pragma unroll
    for (int kk = 0; kk < 4; kk++) {
      acc = MFMA(a1[kk], *(const bf16x8*)(w1 + kk * 32 + g * 8), acc);
      acc = MFMA(aH1[kk], *(const bf16x8*)(w2 + kk * 32 + g * 8), acc);
    }
    float bias = bl1[j0 + l15];
    if (two) {
      const u16* w3 = wl2 + (size_t)(j0 + l15) * 128;
      const u16* w4 = wr2 + (size_t)(j0 + l15) * 128;
      #pragma unroll
      for (int kk = 0; kk < 4; kk++) {
        acc = MFMA(a2[kk], *(const bf16x8*)(w3 + kk * 32 + g * 8), acc);
        acc = MFMA(aH2[kk], *(const bf16x8*)(w4 + kk * 32 + g * 8), acc);
      }
      bias += bl2[j0 + l15];
    }
    #pragma unroll
    for (int r = 0; r < 4; r++)
      out[(size_t)(row0 + g * 4 + r) * 768 + j0 + l15] = acc[r] + bias;
  }
}

__global__ __launch_bounds__(256) void tail_kernel(
    const float* __restrict__ xA, float* __restrict__ oA,
    const float* __restrict__ xB, float* __restrict__ oB, int total)
{
  const float* x = blockIdx.y ? xB : xA;
  float* o = blockIdx.y ? oB : oA;
  int tid = blockIdx.x * 256 + threadIdx.x;
  if (tid >= total) return;
  int n = tid / 160, r = tid % 160;
  size_t off = (size_t)n * 768 + 128 + (size_t)r * 4;
  *(f32x4*)(o + off) = *(const f32x4*)(x + off);
}

extern "C" void kernel_launch(void* const* d_in, const int* in_sizes, int n_in,
                              void* d_out, int out_size, void* d_ws, size_t ws_size,
                              hipStream_t stream)
{
  const int D = 128, C = 6;
  const int N = in_sizes[0] / (C * D);   // 8192
  const int E = in_sizes[2] / 2;         // 262144

  const float* xA = (const float*)d_in[0];
  const float* xB = (const float*)d_in[1];
  const int* eiAB = (const int*)d_in[2];
  const int* eiBA = (const int*)d_in[3];
  const int* eiAA = (const int*)d_in[4];
  const float* inW_A  = (const float*)d_in[5];
  const float* inB_A  = (const float*)d_in[6];
  const float* outW_A = (const float*)d_in[7];
  const float* outB_A = (const float*)d_in[8];
  const float* inW_B  = (const float*)d_in[9];
  const float* inB_B  = (const float*)d_in[10];
  const float* outW_B = (const float*)d_in[11];
  const float* outB_B = (const float*)d_in[12];
  const float* wlAB = (const float*)d_in[13];
  const float* blAB = (const float*)d_in[14];
  const float* wrAB = (const float*)d_in[15];
  const float* wlBA = (const float*)d_in[16];
  const float* blBA = (const float*)d_in[17];
  const float* wrBA = (const float*)d_in[18];
  const float* wlAA = (const float*)d_in[19];
  const float* blAA = (const float*)d_in[20];
  const float* wrAA = (const float*)d_in[21];

  // ---- workspace carve ----
  u16* qkvA = (u16*)d_ws;
  u16* qkvB = qkvA + (size_t)N * 256;
  u16* vtA  = qkvB + (size_t)N * 256;
  u16* vtB  = vtA + (size_t)D * N;
  u16* hA   = vtB + (size_t)D * N;
  u16* hB   = hA + (size_t)N * D;
  u16* wbf  = hB + (size_t)N * D;        // bf16 weights, 229376 elems
  const int wsz[10] = {3*D*D, 3*D*D, D*D, D*D, D*D, D*D, D*D, D*D, D*D, D*D};
  const float* wsrc[10] = {inW_A, inW_B, outW_A, outW_B, wlAB, wrAB, wlBA, wrBA, wlAA, wrAA};
  WPrepArgs wp; int wtot = 0;
  for (int k = 0; k < 10; k++) { wp.src[k] = wsrc[k]; wp.off[k] = wtot; wtot += wsz[k]; }
  wp.total4 = wtot / 4;
  u16* w_inA  = wbf + wp.off[0];
  u16* w_inB  = wbf + wp.off[1];
  u16* w_outA = wbf + wp.off[2];
  u16* w_outB = wbf + wp.off[3];
  u16* w_wlAB = wbf + wp.off[4];
  u16* w_wrAB = wbf + wp.off[5];
  u16* w_wlBA = wbf + wp.off[6];
  u16* w_wrBA = wbf + wp.off[7];
  u16* w_wlAA = wbf + wp.off[8];
  u16* w_wrAA = wbf + wp.off[9];

  // union region: flash partials (phase 1) OR agg+sort scratch (phase 2)
  char* uni = (char*)(wbf + wtot);
  size_t base_b = (size_t)((char*)uni - (char*)d_ws);
  size_t aggsort_b = (size_t)3 * N * 128 * 4 + (size_t)(3 * N + 3 * (N + 1) + 3 * N) * 4 + (size_t)3 * E * 4;
  auto part_b = [&](int S){ return (size_t)2 * S * N * 128 * 2 + (size_t)2 * S * N * 2 * 4; };
  int SEG = 8;
  while (SEG > 1 && ws_size < base_b + (part_b(SEG) > aggsort_b ? part_b(SEG) : aggsort_b)) SEG >>= 1;
  const int segsz = N / SEG;
  u16* part_acc = (u16*)uni;
  float* part_ml = (float*)(part_acc + (size_t)2 * SEG * N * 128);
  float* aggAB = (float*)uni;
  float* aggBA = aggAB + (size_t)N * D;
  float* aggAA = aggBA + (size_t)N * D;
  int* cnt  = (int*)(aggAA + (size_t)N * D);
  int* off  = cnt + 3 * N;
  int* work = off + 3 * (N + 1);
  int* ssrc = work + 3 * N;

  float* outA = (float*)d_out;
  float* outB = outA + (size_t)N * C * D;

  dim3 blk(256);
  // 0. weights f32 -> bf16
  wprep_kernel<<<dim3((wp.total4 + 255) / 256), blk, 0, stream>>>(wp, wbf);
  // 1. qkv = x0 @ inW^T + inB ; V written transposed into vt
  linear_kernel<0><<<dim3(N / 64, 2), blk, 0, stream>>>(xA, w_inA, inB_A, qkvA,
                                                        xB, w_inB, inB_B, qkvB,
                                                        vtA, vtB, C * D, 256, 384, N);
  // 2. flash attention partials (KV-split, 64 q/wave)
  flash_kernel<<<dim3(N / 256, SEG, 2), blk, 0, stream>>>(qkvA, vtA, qkvB, vtB,
                                                          part_acc, part_ml, N, segsz, SEG);
  // 3. combine partials + h = o @ outW^T + outB (fused)
  combine_hproj_kernel<<<dim3(N / 64, 2), blk, 0, stream>>>(part_acc, part_ml,
                                                            w_outA, outB_A, hA,
                                                            w_outB, outB_B, hB, N, SEG);
  // 4. segment sums via counting sort (types: 0=AB(h=A), 1=BA(h=B), 2=AA(h=A))
  (void)hipMemsetAsync(cnt, 0, (size_t)3 * N * sizeof(int), stream);
  hist_kernel<<<dim3((E + 255) / 256, 3), blk, 0, stream>>>(eiAB, eiBA, eiAA, cnt, N, E);
  scan_kernel<<<dim3(3), dim3(1024), 0, stream>>>(cnt, off, work, N);
  sortedges_kernel<<<dim3((E + 255) / 256, 3), blk, 0, stream>>>(eiAB, eiBA, eiAA, work, ssrc, N, E);
  aggregate_kernel<<<dim3(N / 4, 3), blk, 0, stream>>>(hA, hB, hA, off, ssrc, aggAB, N, E);
  // 5. sage outputs into column 0 (f32)
  sage_out_kernel<<<dim3(N / 64), blk, 0, stream>>>(aggAB, w_wlAB, blAB, hB, w_wrAB,
                                                    nullptr, nullptr, nullptr, nullptr, nullptr, outB);
  sage_out_kernel<<<dim3(N / 64), blk, 0, stream>>>(aggBA, w_wlBA, blBA, hA, w_wrBA,
                                                    aggAA, w_wlAA, blAA, hA, w_wrAA, outA);
  // 6. tail columns 1..5 (f32 copy)
  int total = N * 160;
  tail_kernel<<<dim3((total + 255) / 256, 2), blk, 0, stream>>>(xA, outA, xB, outB, total);
}

// Round 7
// 275.574 us; speedup vs baseline: 11.4293x; 1.1506x over previous
//
#include <hip/hip_runtime.h>
#include <hip/hip_bf16.h>

typedef unsigned short u16;
typedef unsigned int u32;
typedef __attribute__((ext_vector_type(8))) short bf16x8;
typedef __attribute__((ext_vector_type(4))) short bf16x4;
typedef __attribute__((ext_vector_type(4))) float f32x4;
typedef __attribute__((ext_vector_type(16))) float f32x16;

#define MFMA(a,b,c)   __builtin_amdgcn_mfma_f32_16x16x32_bf16((a),(b),(c),0,0,0)
#define MFMA32(a,b,c) __builtin_amdgcn_mfma_f32_32x32x16_bf16((a),(b),(c),0,0,0)

__device__ __forceinline__ float bf2f(u16 u){
  union { float f; u32 i; } c; c.i = ((u32)u) << 16; return c.f;
}
__device__ __forceinline__ u16 f2bf(float f){
  __hip_bfloat16 h = __float2bfloat16(f);
  u16 u; __builtin_memcpy(&u, &h, 2); return u;
}
__device__ __forceinline__ bf16x8 ld8f(const float* p){
  bf16x8 r;
  #pragma unroll
  for (int i = 0; i < 8; i++) r[i] = (short)f2bf(p[i]);
  return r;
}
__device__ __forceinline__ u32 cvtpk(float a, float b){
  u32 r; asm volatile("v_cvt_pk_bf16_f32 %0, %1, %2" : "=v"(r) : "v"(a), "v"(b)); return r;
}
__device__ __forceinline__ void pl32swap(u32 &a, u32 &b){
  asm volatile("v_permlane32_swap_b32 %0, %1" : "+v"(a), "+v"(b));
}

// ---- weight pre-conversion f32 -> bf16 (10 matrices, one kernel) ----
struct WPrepArgs { const float* src[10]; int off[10]; int total4; };
__global__ __launch_bounds__(256) void wprep_kernel(WPrepArgs a, u16* __restrict__ dst)
{
  int i = blockIdx.x * 256 + threadIdx.x;
  if (i >= a.total4) return;
  int e = i * 4;
  int j = 0;
  #pragma unroll
  for (int k = 1; k < 10; k++) if (e >= a.off[k]) j = k;
  const float* s = a.src[j] + (e - a.off[j]);
  f32x4 v = *(const f32x4*)s;
  bf16x4 o;
  #pragma unroll
  for (int r = 0; r < 4; r++) o[r] = (short)f2bf(v[r]);
  *(bf16x4*)(dst + e) = o;
}

// y[N][ystride] (bf16) = x[N][128 (stride xstride)] @ w[M][128]^T + b[M]  (w bf16)
// For j0 >= 256 (V block of QKV), write TRANSPOSED into vt[128][N].
template<int XBF>
__global__ __launch_bounds__(256) void linear_kernel(
    const void* __restrict__ xA_, const u16* __restrict__ wA, const float* __restrict__ bA, u16* __restrict__ yA,
    const void* __restrict__ xB_, const u16* __restrict__ wB, const float* __restrict__ bB, u16* __restrict__ yB,
    u16* __restrict__ vtA_, u16* __restrict__ vtB_,
    int xstride, int ystride, int M, int N)
{
  const void* x_ = blockIdx.y ? xB_ : xA_;
  const u16* w = blockIdx.y ? wB : wA;
  const float* b = blockIdx.y ? bB : bA;
  u16* y = blockIdx.y ? yB : yA;
  u16* vt = blockIdx.y ? vtB_ : vtA_;
  const int lane = threadIdx.x & 63, wid = threadIdx.x >> 6;
  const int g = lane >> 4, l15 = lane & 15;
  const int row0 = blockIdx.x * 64 + wid * 16;

  bf16x8 a[4];
  if (XBF) {
    const u16* xr = (const u16*)x_ + (size_t)(row0 + l15) * xstride;
    #pragma unroll
    for (int kk = 0; kk < 4; kk++) a[kk] = *(const bf16x8*)(xr + kk * 32 + g * 8);
  } else {
    const float* xr = (const float*)x_ + (size_t)(row0 + l15) * xstride;
    #pragma unroll
    for (int kk = 0; kk < 4; kk++) a[kk] = ld8f(xr + kk * 32 + g * 8);
  }

  const f32x4 fz = {0.f, 0.f, 0.f, 0.f};
  for (int j0 = 0; j0 < M; j0 += 16) {
    f32x4 acc = fz;
    const u16* wr_ = w + (size_t)(j0 + l15) * 128;
    #pragma unroll
    for (int kk = 0; kk < 4; kk++)
      acc = MFMA(a[kk], *(const bf16x8*)(wr_ + kk * 32 + g * 8), acc);
    float bv = b[j0 + l15];
    if (j0 < 256 || vt == nullptr) {
      #pragma unroll
      for (int r = 0; r < 4; r++)
        y[(size_t)(row0 + g * 4 + r) * ystride + j0 + l15] = f2bf(acc[r] + bv);
    } else {
      bf16x4 o4;
      #pragma unroll
      for (int r = 0; r < 4; r++) o4[r] = (short)f2bf(acc[r] + bv);
      *(bf16x4*)(vt + (size_t)(j0 - 256 + l15) * N + row0 + g * 4) = o4;
    }
  }
}

// Flash attention, KV-split, swapped-QK^T, 32x32x16 MFMA, 32 q-rows/wave,
// P in registers via cvt_pk + permlane32_swap, defer-max,
// DOUBLE-BUFFERED K/V LDS with async-STAGE split (issue-early / write-late).
// grid = (N/128, SEG, 2 types), block = 256 (4 waves x 32 q-rows).
__global__ __launch_bounds__(256, 2) void flash_kernel(
    const u16* __restrict__ qkvA, const u16* __restrict__ vtA,
    const u16* __restrict__ qkvB, const u16* __restrict__ vtB,
    u16* __restrict__ part_acc, float* __restrict__ part_ml,
    int N, int segsz, int SEG)
{
  __shared__ __align__(16) u16 Kt[2][64 * 128];   // idx = r*128 + (c ^ ((r&7)<<3))
  __shared__ __align__(16) u16 Vtt[2][128 * 64];  // idx = r*64  + (c ^ ((r&7)<<3))
  const int ty = blockIdx.z;
  const u16* qkv = ty ? qkvB : qkvA;
  const u16* vt  = ty ? vtB  : vtA;
  const int tid = threadIdx.x;
  const int lane = tid & 63, wid = tid >> 6;
  const int l31 = lane & 31, h = lane >> 5, l7 = lane & 7;
  const int q = blockIdx.x * 128 + wid * 32 + l31;
  const int seg = blockIdx.y;
  const int kvbase = seg * segsz;
  const float C = 0.088388347648318447f * 1.4426950408889634f; // scale*log2(e)
  const float THR = 8.0f / C;

  // per-lane staging geometry (fixed; only kv0 varies)
  int rk[4], ck[4], cks[4], rv[4], cv[4], cvs[4];
  #pragma unroll
  for (int i = 0; i < 4; i++) {
    int ch = tid + i * 256;
    rk[i] = ch >> 4; ck[i] = (ch & 15) * 8; cks[i] = ck[i] ^ ((rk[i] & 7) << 3);
    rv[i] = ch >> 3; cv[i] = (ch & 7) * 8;  cvs[i] = cv[i] ^ ((rv[i] & 7) << 3);
  }

  bf16x8 aQ[8];
  const u16* qr = qkv + (size_t)q * 256;
  #pragma unroll
  for (int kk = 0; kk < 8; kk++) aQ[kk] = *(const bf16x8*)(qr + kk * 16 + h * 8);

  f32x16 accO[4];
  #pragma unroll
  for (int d = 0; d < 4; d++) accO[d] = (f32x16)0.f;
  float m_ = -INFINITY, l_ = 0.f;

  // prologue: stage tile 0 into buffer 0
  {
    #pragma unroll
    for (int i = 0; i < 4; i++) {
      bf16x8 kv8 = *(const bf16x8*)(qkv + 128 + (size_t)(kvbase + rk[i]) * 256 + ck[i]);
      bf16x8 vv8 = *(const bf16x8*)(vt + (size_t)rv[i] * N + kvbase + cv[i]);
      *(bf16x8*)&Kt[0][rk[i] * 128 + cks[i]] = kv8;
      *(bf16x8*)&Vtt[0][rv[i] * 64 + cvs[i]] = vv8;
    }
  }
  __syncthreads();

  int cur = 0;
  for (int kt = 0; kt < segsz; kt += 64) {
    const bool pfch = (kt + 64 < segsz);
    bf16x8 kreg[4], vreg[4];
    if (pfch) {
      const int kv0n = kvbase + kt + 64;
      #pragma unroll
      for (int i = 0; i < 4; i++) {
        kreg[i] = *(const bf16x8*)(qkv + 128 + (size_t)(kv0n + rk[i]) * 256 + ck[i]);
        vreg[i] = *(const bf16x8*)(vt + (size_t)rv[i] * N + kv0n + cv[i]);
      }
    }

    const u16* KtC = Kt[cur];
    const u16* VtC = Vtt[cur];

    // S^T = K @ Q^T : C[kv][q], col q = l31, row kv = u*32 + 4h + (reg&3) + 8*(reg>>2)
    f32x16 sc0 = (f32x16)0.f, sc1 = (f32x16)0.f;
    #pragma unroll
    for (int kk = 0; kk < 8; kk++) {
      const int co = ((kk * 2 + h) * 8) ^ (l7 << 3);
      bf16x8 aK0 = *(bf16x8*)&KtC[l31 * 128 + co];
      bf16x8 aK1 = *(bf16x8*)&KtC[(32 + l31) * 128 + co];
      sc0 = MFMA32(aK0, aQ[kk], sc0);
      sc1 = MFMA32(aK1, aQ[kk], sc1);
    }

    // lane-local online softmax (q fixed per lane; lanes l and l+32 share q)
    float pmax = sc0[0];
    #pragma unroll
    for (int i = 1; i < 16; i++) pmax = fmaxf(pmax, sc0[i]);
    #pragma unroll
    for (int i = 0; i < 16; i++) pmax = fmaxf(pmax, sc1[i]);
    pmax = fmaxf(pmax, __shfl_xor(pmax, 32));
    if (!__all(pmax - m_ <= THR)) {
      float nm = fmaxf(m_, pmax);
      float corr = __builtin_exp2f((m_ - nm) * C);
      m_ = nm; l_ *= corr;
      #pragma unroll
      for (int d = 0; d < 4; d++)
        #pragma unroll
        for (int i = 0; i < 16; i++) accO[d][i] *= corr;
    }
    float sum = 0.f;
    #pragma unroll
    for (int i = 0; i < 16; i++) {
      float e0 = __builtin_exp2f((sc0[i] - m_) * C);
      float e1 = __builtin_exp2f((sc1[i] - m_) * C);
      sc0[i] = e0; sc1[i] = e1; sum += e0 + e1;
    }
    sum += __shfl_xor(sum, 32);
    l_ += sum;

    // O^T += V^T @ P^T ; P^T B-frags built in-register
    #pragma unroll
    for (int t = 0; t < 4; t++) {
      const int jA = (t & 1) * 2, jB = jA + 1;
      u32 a0, b0, a1, b1;
      if (t < 2) {
        a0 = cvtpk(sc0[jA * 4 + 0], sc0[jA * 4 + 1]);
        b0 = cvtpk(sc0[jB * 4 + 0], sc0[jB * 4 + 1]);
        a1 = cvtpk(sc0[jA * 4 + 2], sc0[jA * 4 + 3]);
        b1 = cvtpk(sc0[jB * 4 + 2], sc0[jB * 4 + 3]);
      } else {
        a0 = cvtpk(sc1[jA * 4 + 0], sc1[jA * 4 + 1]);
        b0 = cvtpk(sc1[jB * 4 + 0], sc1[jB * 4 + 1]);
        a1 = cvtpk(sc1[jA * 4 + 2], sc1[jA * 4 + 3]);
        b1 = cvtpk(sc1[jB * 4 + 2], sc1[jB * 4 + 3]);
      }
      pl32swap(a0, b0); pl32swap(a1, b1);
      union { u32 w[4]; bf16x8 v; } pf;
      pf.w[0] = a0; pf.w[1] = a1; pf.w[2] = b0; pf.w[3] = b1;
      #pragma unroll
      for (int db = 0; db < 4; db++) {
        bf16x8 aV = *(bf16x8*)&VtC[(db * 32 + l31) * 64 + (((t * 2 + h) * 8) ^ (l7 << 3))];
        accO[db] = MFMA32(aV, pf.v, accO[db]);
      }
    }

    // write-late: deposit prefetched tile into the idle buffer
    if (pfch) {
      const int nb = cur ^ 1;
      #pragma unroll
      for (int i = 0; i < 4; i++) {
        *(bf16x8*)&Kt[nb][rk[i] * 128 + cks[i]] = kreg[i];
        *(bf16x8*)&Vtt[nb][rv[i] * 64 + cvs[i]] = vreg[i];
      }
    }
    __syncthreads();
    cur ^= 1;
  }

  // partial store [q][128] bf16 (unnormalized) + (m,l)
  const size_t pbase = ((size_t)(ty * SEG + seg) * N + q) * 128;
  #pragma unroll
  for (int d = 0; d < 4; d++)
    #pragma unroll
    for (int j = 0; j < 4; j++) {
      bf16x4 o4;
      #pragma unroll
      for (int r = 0; r < 4; r++) o4[r] = (short)f2bf(accO[d][j * 4 + r]);
      *(bf16x4*)(part_acc + pbase + d * 32 + j * 8 + h * 4) = o4;
    }
  if (h == 0) {
    float2 ml; ml.x = m_; ml.y = l_;
    *(float2*)(part_ml + ((size_t)(ty * SEG + seg) * N + q) * 2) = ml;
  }
}

// combine SEG partials -> o-tile in LDS, then h = o @ outW^T + outB (fused).
// grid (N/64, 2), block 256.
__global__ __launch_bounds__(256) void combine_hproj_kernel(
    const u16* __restrict__ part_acc, const float* __restrict__ part_ml,
    const u16* __restrict__ woutA, const float* __restrict__ boutA, u16* __restrict__ hA,
    const u16* __restrict__ woutB, const float* __restrict__ boutB, u16* __restrict__ hB,
    int N, int SEG)
{
  __shared__ __align__(16) u16 ot[64 * 136];
  const int t = blockIdx.y;
  const u16* w = t ? woutB : woutA;
  const float* bb = t ? boutB : boutA;
  u16* hOut = t ? hB : hA;
  const int tid = threadIdx.x;
  const int row = tid >> 2, qt = tid & 3;
  const int grow = blockIdx.x * 64 + row;
  const float C = 0.088388347648318447f * 1.4426950408889634f;

  float m = -INFINITY;
  for (int s = 0; s < SEG; s++)
    m = fmaxf(m, part_ml[((size_t)(t * SEG + s) * N + grow) * 2]);
  float l = 0.f;
  float acc[32];
  #pragma unroll
  for (int i = 0; i < 32; i++) acc[i] = 0.f;
  for (int s = 0; s < SEG; s++) {
    const float* ml = part_ml + ((size_t)(t * SEG + s) * N + grow) * 2;
    float w8 = __builtin_exp2f((ml[0] - m) * C);
    l += w8 * ml[1];
    const u16* pa = part_acc + ((size_t)(t * SEG + s) * N + grow) * 128 + qt * 32;
    #pragma unroll
    for (int j = 0; j < 4; j++) {
      bf16x8 vch = *(const bf16x8*)(pa + j * 8);
      #pragma unroll
      for (int i = 0; i < 8; i++) acc[j * 8 + i] += w8 * bf2f((u16)vch[i]);
    }
  }
  const float inv = 1.f / l;
  #pragma unroll
  for (int j = 0; j < 4; j++) {
    bf16x8 oc;
    #pragma unroll
    for (int i = 0; i < 8; i++) oc[i] = (short)f2bf(acc[j * 8 + i] * inv);
    *(bf16x8*)&ot[row * 136 + qt * 32 + j * 8] = oc;
  }
  __syncthreads();

  const int lane = tid & 63, wid = tid >> 6;
  const int g = lane >> 4, l15 = lane & 15;
  const int row0 = wid * 16;
  bf16x8 a[4];
  #pragma unroll
  for (int kk = 0; kk < 4; kk++) a[kk] = *(bf16x8*)&ot[(row0 + l15) * 136 + kk * 32 + g * 8];
  const f32x4 fz = {0.f, 0.f, 0.f, 0.f};
  for (int j0 = 0; j0 < 128; j0 += 16) {
    f32x4 acc2 = fz;
    const u16* wr_ = w + (size_t)(j0 + l15) * 128;
    #pragma unroll
    for (int kk = 0; kk < 4; kk++)
      acc2 = MFMA(a[kk], *(const bf16x8*)(wr_ + kk * 32 + g * 8), acc2);
    float bv = bb[j0 + l15];
    #pragma unroll
    for (int r = 0; r < 4; r++)
      hOut[(size_t)(blockIdx.x * 64 + row0 + g * 4 + r) * 128 + j0 + l15] = f2bf(acc2[r] + bv);
  }
}

// ---- segment-sum via counting sort (no f32 atomics) ----
__global__ __launch_bounds__(256) void hist_kernel(
    const int* __restrict__ e0, const int* __restrict__ e1, const int* __restrict__ e2,
    int* __restrict__ cnt, int Nn, int E)
{
  const int t = blockIdx.y;
  const int* ei = t == 0 ? e0 : (t == 1 ? e1 : e2);
  int e = blockIdx.x * 256 + threadIdx.x;
  if (e >= E) return;
  atomicAdd(&cnt[t * Nn + ei[E + e]], 1);
}

__global__ __launch_bounds__(1024) void scan_kernel(
    const int* __restrict__ cnt, int* __restrict__ off, int* __restrict__ work, int Nn)
{
  const int t = blockIdx.x;
  const int* c = cnt + t * Nn;
  int* o = off + t * (Nn + 1);
  int* w = work + t * Nn;
  __shared__ int part[1024];
  const int tid = threadIdx.x;
  const int base = tid * 8;
  int loc[8], s = 0;
  #pragma unroll
  for (int i = 0; i < 8; i++) { loc[i] = s; s += c[base + i]; }
  part[tid] = s;
  __syncthreads();
  #pragma unroll
  for (int st = 1; st < 1024; st <<= 1) {
    int v = (tid >= st) ? part[tid - st] : 0;
    __syncthreads();
    part[tid] += v;
    __syncthreads();
  }
  int pre = (tid == 0) ? 0 : part[tid - 1];
  #pragma unroll
  for (int i = 0; i < 8; i++) { int p = pre + loc[i]; o[base + i] = p; w[base + i] = p; }
  if (tid == 1023) o[Nn] = part[1023];
}

__global__ __launch_bounds__(256) void sortedges_kernel(
    const int* __restrict__ e0, const int* __restrict__ e1, const int* __restrict__ e2,
    int* __restrict__ work, int* __restrict__ ssrc, int Nn, int E)
{
  const int t = blockIdx.y;
  const int* ei = t == 0 ? e0 : (t == 1 ? e1 : e2);
  int e = blockIdx.x * 256 + threadIdx.x;
  if (e >= E) return;
  int s = ei[e], d = ei[E + e];
  int pos = atomicAdd(&work[t * Nn + d], 1);
  ssrc[(size_t)t * E + pos] = s;
}

__global__ __launch_bounds__(256) void aggregate_kernel(
    const u16* __restrict__ h0, const u16* __restrict__ h1, const u16* __restrict__ h2,
    const int* __restrict__ off, const int* __restrict__ ssrc,
    float* __restrict__ agg, int Nn, int E)
{
  const int t = blockIdx.y;
  const u16* h = t == 0 ? h0 : (t == 1 ? h1 : h2);
  const int* o = off + t * (Nn + 1);
  const int* ss = ssrc + (size_t)t * E;
  float* a = agg + (size_t)t * Nn * 128;
  const int wid = threadIdx.x >> 6, lane = threadIdx.x & 63;
  const int d = blockIdx.x * 4 + wid;
  const int s0 = o[d], s1 = o[d + 1];
  float a0 = 0.f, a1 = 0.f;
  int e = s0;
  for (; e + 3 < s1; e += 4) {
    int r0 = ss[e], r1 = ss[e + 1], r2 = ss[e + 2], r3 = ss[e + 3];
    u32 v0 = *(const u32*)(h + (size_t)r0 * 128 + lane * 2);
    u32 v1 = *(const u32*)(h + (size_t)r1 * 128 + lane * 2);
    u32 v2 = *(const u32*)(h + (size_t)r2 * 128 + lane * 2);
    u32 v3 = *(const u32*)(h + (size_t)r3 * 128 + lane * 2);
    a0 += bf2f((u16)(v0 & 0xffff)) + bf2f((u16)(v1 & 0xffff)) + bf2f((u16)(v2 & 0xffff)) + bf2f((u16)(v3 & 0xffff));
    a1 += bf2f((u16)(v0 >> 16)) + bf2f((u16)(v1 >> 16)) + bf2f((u16)(v2 >> 16)) + bf2f((u16)(v3 >> 16));
  }
  for (; e < s1; e++) {
    u32 v = *(const u32*)(h + (size_t)ss[e] * 128 + lane * 2);
    a0 += bf2f((u16)(v & 0xffff));
    a1 += bf2f((u16)(v >> 16));
  }
  a[(size_t)d * 128 + lane * 2] = a0;
  a[(size_t)d * 128 + lane * 2 + 1] = a1;
}

__global__ __launch_bounds__(256) void sage_out_kernel(
    const float* __restrict__ agg1, const u16* __restrict__ wl1, const float* __restrict__ bl1,
    const u16* __restrict__ h1, const u16* __restrict__ wr1,
    const float* __restrict__ agg2, const u16* __restrict__ wl2, const float* __restrict__ bl2,
    const u16* __restrict__ h2, const u16* __restrict__ wr2,
    float* __restrict__ out)
{
  const int lane = threadIdx.x & 63, wid = threadIdx.x >> 6;
  const int g = lane >> 4, l15 = lane & 15;
  const int row0 = blockIdx.x * 64 + wid * 16;
  const bool two = (agg2 != nullptr);

  bf16x8 a1[4], aH1[4], a2[4], aH2[4];
  const float* ar1 = agg1 + (size_t)(row0 + l15) * 128;
  const u16* hr1 = h1 + (size_t)(row0 + l15) * 128;
  #pragma unroll
  for (int kk = 0; kk < 4; kk++) {
    a1[kk] = ld8f(ar1 + kk * 32 + g * 8);
    aH1[kk] = *(const bf16x8*)(hr1 + kk * 32 + g * 8);
  }
  if (two) {
    const float* ar2 = agg2 + (size_t)(row0 + l15) * 128;
    const u16* hr2 = h2 + (size_t)(row0 + l15) * 128;
    #pragma unroll
    for (int kk = 0; kk < 4; kk++) {
      a2[kk] = ld8f(ar2 + kk * 32 + g * 8);
      aH2[kk] = *(const bf16x8*)(hr2 + kk * 32 + g * 8);
    }
  }

  const f32x4 fz = {0.f, 0.f, 0.f, 0.f};
  for (int j0 = 0; j0 < 128; j0 += 16) {
    f32x4 acc = fz;
    const u16* w1 = wl1 + (size_t)(j0 + l15) * 128;
    const u16* w2 = wr1 + (size_t)(j0 + l15) * 128;
    #pragma unroll
    for (int kk = 0; kk < 4; kk++) {
      acc = MFMA(a1[kk], *(const bf16x8*)(w1 + kk * 32 + g * 8), acc);
      acc = MFMA(aH1[kk], *(const bf16x8*)(w2 + kk * 32 + g * 8), acc);
    }
    float bias = bl1[j0 + l15];
    if (two) {
      const u16* w3 = wl2 + (size_t)(j0 + l15) * 128;
      const u16* w4 = wr2 + (size_t)(j0 + l15) * 128;
      #pragma unroll
      for (int kk = 0; kk < 4; kk++) {
        acc = MFMA(a2[kk], *(const bf16x8*)(w3 + kk * 32 + g * 8), acc);
        acc = MFMA(aH2[kk], *(const bf16x8*)(w4 + kk * 32 + g * 8), acc);
      }
      bias += bl2[j0 + l15];
    }
    #pragma unroll
    for (int r = 0; r < 4; r++)
      out[(size_t)(row0 + g * 4 + r) * 768 + j0 + l15] = acc[r] + bias;
  }
}

__global__ __launch_bounds__(256) void tail_kernel(
    const float* __restrict__ xA, float* __restrict__ oA,
    const float* __restrict__ xB, float* __restrict__ oB, int total)
{
  const float* x = blockIdx.y ? xB : xA;
  float* o = blockIdx.y ? oB : oA;
  int tid = blockIdx.x * 256 + threadIdx.x;
  if (tid >= total) return;
  int n = tid / 160, r = tid % 160;
  size_t off = (size_t)n * 768 + 128 + (size_t)r * 4;
  *(f32x4*)(o + off) = *(const f32x4*)(x + off);
}

extern "C" void kernel_launch(void* const* d_in, const int* in_sizes, int n_in,
                              void* d_out, int out_size, void* d_ws, size_t ws_size,
                              hipStream_t stream)
{
  const int D = 128, C = 6;
  const int N = in_sizes[0] / (C * D);   // 8192
  const int E = in_sizes[2] / 2;         // 262144

  const float* xA = (const float*)d_in[0];
  const float* xB = (const float*)d_in[1];
  const int* eiAB = (const int*)d_in[2];
  const int* eiBA = (const int*)d_in[3];
  const int* eiAA = (const int*)d_in[4];
  const float* inW_A  = (const float*)d_in[5];
  const float* inB_A  = (const float*)d_in[6];
  const float* outW_A = (const float*)d_in[7];
  const float* outB_A = (const float*)d_in[8];
  const float* inW_B  = (const float*)d_in[9];
  const float* inB_B  = (const float*)d_in[10];
  const float* outW_B = (const float*)d_in[11];
  const float* outB_B = (const float*)d_in[12];
  const float* wlAB = (const float*)d_in[13];
  const float* blAB = (const float*)d_in[14];
  const float* wrAB = (const float*)d_in[15];
  const float* wlBA = (const float*)d_in[16];
  const float* blBA = (const float*)d_in[17];
  const float* wrBA = (const float*)d_in[18];
  const float* wlAA = (const float*)d_in[19];
  const float* blAA = (const float*)d_in[20];
  const float* wrAA = (const float*)d_in[21];

  // ---- workspace carve ----
  u16* qkvA = (u16*)d_ws;
  u16* qkvB = qkvA + (size_t)N * 256;
  u16* vtA  = qkvB + (size_t)N * 256;
  u16* vtB  = vtA + (size_t)D * N;
  u16* hA   = vtB + (size_t)D * N;
  u16* hB   = hA + (size_t)N * D;
  u16* wbf  = hB + (size_t)N * D;        // bf16 weights, 229376 elems
  const int wsz[10] = {3*D*D, 3*D*D, D*D, D*D, D*D, D*D, D*D, D*D, D*D, D*D};
  const float* wsrc[10] = {inW_A, inW_B, outW_A, outW_B, wlAB, wrAB, wlBA, wrBA, wlAA, wrAA};
  WPrepArgs wp; int wtot = 0;
  for (int k = 0; k < 10; k++) { wp.src[k] = wsrc[k]; wp.off[k] = wtot; wtot += wsz[k]; }
  wp.total4 = wtot / 4;
  u16* w_inA  = wbf + wp.off[0];
  u16* w_inB  = wbf + wp.off[1];
  u16* w_outA = wbf + wp.off[2];
  u16* w_outB = wbf + wp.off[3];
  u16* w_wlAB = wbf + wp.off[4];
  u16* w_wrAB = wbf + wp.off[5];
  u16* w_wlBA = wbf + wp.off[6];
  u16* w_wrBA = wbf + wp.off[7];
  u16* w_wlAA = wbf + wp.off[8];
  u16* w_wrAA = wbf + wp.off[9];

  // union region: flash partials (phase 1) OR agg+sort scratch (phase 2)
  char* uni = (char*)(wbf + wtot);
  size_t base_b = (size_t)((char*)uni - (char*)d_ws);
  size_t aggsort_b = (size_t)3 * N * 128 * 4 + (size_t)(3 * N + 3 * (N + 1) + 3 * N) * 4 + (size_t)3 * E * 4;
  auto part_b = [&](int S){ return (size_t)2 * S * N * 128 * 2 + (size_t)2 * S * N * 2 * 4; };
  int SEG = 4;
  while (SEG > 1 && ws_size < base_b + (part_b(SEG) > aggsort_b ? part_b(SEG) : aggsort_b)) SEG >>= 1;
  const int segsz = N / SEG;
  u16* part_acc = (u16*)uni;
  float* part_ml = (float*)(part_acc + (size_t)2 * SEG * N * 128);
  float* aggAB = (float*)uni;
  float* aggBA = aggAB + (size_t)N * D;
  float* aggAA = aggBA + (size_t)N * D;
  int* cnt  = (int*)(aggAA + (size_t)N * D);
  int* off  = cnt + 3 * N;
  int* work = off + 3 * (N + 1);
  int* ssrc = work + 3 * N;

  float* outA = (float*)d_out;
  float* outB = outA + (size_t)N * C * D;

  dim3 blk(256);
  // 0. weights f32 -> bf16
  wprep_kernel<<<dim3((wp.total4 + 255) / 256), blk, 0, stream>>>(wp, wbf);
  // 1. qkv = x0 @ inW^T + inB ; V written transposed into vt
  linear_kernel<0><<<dim3(N / 64, 2), blk, 0, stream>>>(xA, w_inA, inB_A, qkvA,
                                                        xB, w_inB, inB_B, qkvB,
                                                        vtA, vtB, C * D, 256, 384, N);
  // 2. flash attention partials (KV-split, double-buffered 2-phase pipeline)
  flash_kernel<<<dim3(N / 128, SEG, 2), blk, 0, stream>>>(qkvA, vtA, qkvB, vtB,
                                                          part_acc, part_ml, N, segsz, SEG);
  // 3. combine partials + h = o @ outW^T + outB (fused)
  combine_hproj_kernel<<<dim3(N / 64, 2), blk, 0, stream>>>(part_acc, part_ml,
                                                            w_outA, outB_A, hA,
                                                            w_outB, outB_B, hB, N, SEG);
  // 4. segment sums via counting sort (types: 0=AB(h=A), 1=BA(h=B), 2=AA(h=A))
  (void)hipMemsetAsync(cnt, 0, (size_t)3 * N * sizeof(int), stream);
  hist_kernel<<<dim3((E + 255) / 256, 3), blk, 0, stream>>>(eiAB, eiBA, eiAA, cnt, N, E);
  scan_kernel<<<dim3(3), dim3(1024), 0, stream>>>(cnt, off, work, N);
  sortedges_kernel<<<dim3((E + 255) / 256, 3), blk, 0, stream>>>(eiAB, eiBA, eiAA, work, ssrc, N, E);
  aggregate_kernel<<<dim3(N / 4, 3), blk, 0, stream>>>(hA, hB, hA, off, ssrc, aggAB, N, E);
  // 5. sage outputs into column 0 (f32)
  sage_out_kernel<<<dim3(N / 64), blk, 0, stream>>>(aggAB, w_wlAB, blAB, hB, w_wrAB,
                                                    nullptr, nullptr, nullptr, nullptr, nullptr, outB);
  sage_out_kernel<<<dim3(N / 64), blk, 0, stream>>>(aggBA, w_wlBA, blBA, hA, w_wrBA,
                                                    aggAA, w_wlAA, blAA, hA, w_wrAA, outA);
  // 6. tail columns 1..5 (f32 copy)
  int total = N * 160;
  tail_kernel<<<dim3((total + 255) / 256, 2), blk, 0, stream>>>(xA, outA, xB, outB, total);
}

// Round 8
// 270.278 us; speedup vs baseline: 11.6532x; 1.0196x over previous
//
#include <hip/hip_runtime.h>
#include <hip/hip_bf16.h>

typedef unsigned short u16;
typedef unsigned int u32;
typedef __attribute__((ext_vector_type(8))) short bf16x8;
typedef __attribute__((ext_vector_type(4))) short bf16x4;
typedef __attribute__((ext_vector_type(4))) float f32x4;
typedef __attribute__((ext_vector_type(16))) float f32x16;

#define MFMA(a,b,c)   __builtin_amdgcn_mfma_f32_16x16x32_bf16((a),(b),(c),0,0,0)
#define MFMA32(a,b,c) __builtin_amdgcn_mfma_f32_32x32x16_bf16((a),(b),(c),0,0,0)

__device__ __forceinline__ float bf2f(u16 u){
  union { float f; u32 i; } c; c.i = ((u32)u) << 16; return c.f;
}
__device__ __forceinline__ u16 f2bf(float f){
  __hip_bfloat16 h = __float2bfloat16(f);
  u16 u; __builtin_memcpy(&u, &h, 2); return u;
}
__device__ __forceinline__ bf16x8 ld8f(const float* p){
  bf16x8 r;
  #pragma unroll
  for (int i = 0; i < 8; i++) r[i] = (short)f2bf(p[i]);
  return r;
}
__device__ __forceinline__ u32 cvtpk(float a, float b){
  u32 r; asm volatile("v_cvt_pk_bf16_f32 %0, %1, %2" : "=v"(r) : "v"(a), "v"(b)); return r;
}
__device__ __forceinline__ void pl32swap(u32 &a, u32 &b){
  asm volatile("v_permlane32_swap_b32 %0, %1" : "+v"(a), "+v"(b));
}

// ---- prelude: wprep (f32->bf16 weights) + hist (3 types) + tail copy, one flat grid ----
struct WPrepArgs { const float* src[10]; int off[10]; int total4; };
__global__ __launch_bounds__(256) void prelude_kernel(
    WPrepArgs a, u16* __restrict__ wdst,
    const int* __restrict__ e0, const int* __restrict__ e1, const int* __restrict__ e2,
    int* __restrict__ cnt,
    const float* __restrict__ xA, float* __restrict__ outA,
    const float* __restrict__ xB, float* __restrict__ outB,
    int Nn, int E, int W, int HB, int TB)
{
  const int tid = threadIdx.x;
  int b = blockIdx.x;
  if (b < W) {                      // weight convert
    int i = b * 256 + tid;
    if (i >= a.total4) return;
    int e = i * 4;
    int j = 0;
    #pragma unroll
    for (int k = 1; k < 10; k++) if (e >= a.off[k]) j = k;
    f32x4 v = *(const f32x4*)(a.src[j] + (e - a.off[j]));
    bf16x4 o;
    #pragma unroll
    for (int r = 0; r < 4; r++) o[r] = (short)f2bf(v[r]);
    *(bf16x4*)(wdst + e) = o;
    return;
  }
  b -= W;
  if (b < 3 * HB) {                 // destination histogram
    int t = b / HB;
    int e = (b % HB) * 256 + tid;
    if (e >= E) return;
    const int* ei = t == 0 ? e0 : (t == 1 ? e1 : e2);
    atomicAdd(&cnt[t * Nn + ei[E + e]], 1);
    return;
  }
  b -= 3 * HB;
  {                                 // tail copy x[:,1:6,:] -> out[:,1:6,:]
    int t = b / TB;
    int idx = (b % TB) * 256 + tid;
    if (idx >= Nn * 160) return;
    const float* x = t ? xB : xA;
    float* o = t ? outB : outA;
    int n = idx / 160, r = idx % 160;
    size_t off = (size_t)n * 768 + 128 + (size_t)r * 4;
    *(f32x4*)(o + off) = *(const f32x4*)(x + off);
  }
}

// y[N][ystride] (bf16) = x[N][128 (stride xstride)] @ w[M][128]^T + b[M]  (w bf16)
// For j0 >= 256 (V block of QKV), write TRANSPOSED into vt[128][N].
template<int XBF>
__global__ __launch_bounds__(256) void linear_kernel(
    const void* __restrict__ xA_, const u16* __restrict__ wA, const float* __restrict__ bA, u16* __restrict__ yA,
    const void* __restrict__ xB_, const u16* __restrict__ wB, const float* __restrict__ bB, u16* __restrict__ yB,
    u16* __restrict__ vtA_, u16* __restrict__ vtB_,
    int xstride, int ystride, int M, int N)
{
  const void* x_ = blockIdx.y ? xB_ : xA_;
  const u16* w = blockIdx.y ? wB : wA;
  const float* b = blockIdx.y ? bB : bA;
  u16* y = blockIdx.y ? yB : yA;
  u16* vt = blockIdx.y ? vtB_ : vtA_;
  const int lane = threadIdx.x & 63, wid = threadIdx.x >> 6;
  const int g = lane >> 4, l15 = lane & 15;
  const int row0 = blockIdx.x * 64 + wid * 16;

  bf16x8 a[4];
  if (XBF) {
    const u16* xr = (const u16*)x_ + (size_t)(row0 + l15) * xstride;
    #pragma unroll
    for (int kk = 0; kk < 4; kk++) a[kk] = *(const bf16x8*)(xr + kk * 32 + g * 8);
  } else {
    const float* xr = (const float*)x_ + (size_t)(row0 + l15) * xstride;
    #pragma unroll
    for (int kk = 0; kk < 4; kk++) a[kk] = ld8f(xr + kk * 32 + g * 8);
  }

  const f32x4 fz = {0.f, 0.f, 0.f, 0.f};
  for (int j0 = 0; j0 < M; j0 += 16) {
    f32x4 acc = fz;
    const u16* wr_ = w + (size_t)(j0 + l15) * 128;
    #pragma unroll
    for (int kk = 0; kk < 4; kk++)
      acc = MFMA(a[kk], *(const bf16x8*)(wr_ + kk * 32 + g * 8), acc);
    float bv = b[j0 + l15];
    if (j0 < 256 || vt == nullptr) {
      #pragma unroll
      for (int r = 0; r < 4; r++)
        y[(size_t)(row0 + g * 4 + r) * ystride + j0 + l15] = f2bf(acc[r] + bv);
    } else {
      bf16x4 o4;
      #pragma unroll
      for (int r = 0; r < 4; r++) o4[r] = (short)f2bf(acc[r] + bv);
      *(bf16x4*)(vt + (size_t)(j0 - 256 + l15) * N + row0 + g * 4) = o4;
    }
  }
}

// Flash attention, KV-split, swapped-QK^T, 32x32x16 MFMA, 32 q-rows/wave,
// P in registers, defer-max, double-buffered LDS + async-STAGE, setprio on MFMA.
// grid = (N/128, SEG, 2 types), block = 256.
__global__ __launch_bounds__(256, 2) void flash_kernel(
    const u16* __restrict__ qkvA, const u16* __restrict__ vtA,
    const u16* __restrict__ qkvB, const u16* __restrict__ vtB,
    u16* __restrict__ part_acc, float* __restrict__ part_ml,
    int N, int segsz, int SEG)
{
  __shared__ __align__(16) u16 Kt[2][64 * 128];
  __shared__ __align__(16) u16 Vtt[2][128 * 64];
  const int ty = blockIdx.z;
  const u16* qkv = ty ? qkvB : qkvA;
  const u16* vt  = ty ? vtB  : vtA;
  const int tid = threadIdx.x;
  const int lane = tid & 63, wid = tid >> 6;
  const int l31 = lane & 31, h = lane >> 5, l7 = lane & 7;
  const int q = blockIdx.x * 128 + wid * 32 + l31;
  const int seg = blockIdx.y;
  const int kvbase = seg * segsz;
  const float C = 0.088388347648318447f * 1.4426950408889634f;
  const float THR = 8.0f / C;

  int rk[4], ck[4], cks[4], rv[4], cv[4], cvs[4];
  #pragma unroll
  for (int i = 0; i < 4; i++) {
    int ch = tid + i * 256;
    rk[i] = ch >> 4; ck[i] = (ch & 15) * 8; cks[i] = ck[i] ^ ((rk[i] & 7) << 3);
    rv[i] = ch >> 3; cv[i] = (ch & 7) * 8;  cvs[i] = cv[i] ^ ((rv[i] & 7) << 3);
  }

  bf16x8 aQ[8];
  const u16* qr = qkv + (size_t)q * 256;
  #pragma unroll
  for (int kk = 0; kk < 8; kk++) aQ[kk] = *(const bf16x8*)(qr + kk * 16 + h * 8);

  f32x16 accO[4];
  #pragma unroll
  for (int d = 0; d < 4; d++) accO[d] = (f32x16)0.f;
  float m_ = -INFINITY, l_ = 0.f;

  {
    #pragma unroll
    for (int i = 0; i < 4; i++) {
      bf16x8 kv8 = *(const bf16x8*)(qkv + 128 + (size_t)(kvbase + rk[i]) * 256 + ck[i]);
      bf16x8 vv8 = *(const bf16x8*)(vt + (size_t)rv[i] * N + kvbase + cv[i]);
      *(bf16x8*)&Kt[0][rk[i] * 128 + cks[i]] = kv8;
      *(bf16x8*)&Vtt[0][rv[i] * 64 + cvs[i]] = vv8;
    }
  }
  __syncthreads();

  int cur = 0;
  for (int kt = 0; kt < segsz; kt += 64) {
    const bool pfch = (kt + 64 < segsz);
    bf16x8 kreg[4], vreg[4];
    if (pfch) {
      const int kv0n = kvbase + kt + 64;
      #pragma unroll
      for (int i = 0; i < 4; i++) {
        kreg[i] = *(const bf16x8*)(qkv + 128 + (size_t)(kv0n + rk[i]) * 256 + ck[i]);
        vreg[i] = *(const bf16x8*)(vt + (size_t)rv[i] * N + kv0n + cv[i]);
      }
    }

    const u16* KtC = Kt[cur];
    const u16* VtC = Vtt[cur];

    f32x16 sc0 = (f32x16)0.f, sc1 = (f32x16)0.f;
    __builtin_amdgcn_s_setprio(1);
    #pragma unroll
    for (int kk = 0; kk < 8; kk++) {
      const int co = ((kk * 2 + h) * 8) ^ (l7 << 3);
      bf16x8 aK0 = *(bf16x8*)&KtC[l31 * 128 + co];
      bf16x8 aK1 = *(bf16x8*)&KtC[(32 + l31) * 128 + co];
      sc0 = MFMA32(aK0, aQ[kk], sc0);
      sc1 = MFMA32(aK1, aQ[kk], sc1);
    }
    __builtin_amdgcn_s_setprio(0);

    float pmax = sc0[0];
    #pragma unroll
    for (int i = 1; i < 16; i++) pmax = fmaxf(pmax, sc0[i]);
    #pragma unroll
    for (int i = 0; i < 16; i++) pmax = fmaxf(pmax, sc1[i]);
    pmax = fmaxf(pmax, __shfl_xor(pmax, 32));
    if (!__all(pmax - m_ <= THR)) {
      float nm = fmaxf(m_, pmax);
      float corr = __builtin_exp2f((m_ - nm) * C);
      m_ = nm; l_ *= corr;
      #pragma unroll
      for (int d = 0; d < 4; d++)
        #pragma unroll
        for (int i = 0; i < 16; i++) accO[d][i] *= corr;
    }
    float sum = 0.f;
    #pragma unroll
    for (int i = 0; i < 16; i++) {
      float e0 = __builtin_exp2f((sc0[i] - m_) * C);
      float e1 = __builtin_exp2f((sc1[i] - m_) * C);
      sc0[i] = e0; sc1[i] = e1; sum += e0 + e1;
    }
    sum += __shfl_xor(sum, 32);
    l_ += sum;

    #pragma unroll
    for (int t = 0; t < 4; t++) {
      const int jA = (t & 1) * 2, jB = jA + 1;
      u32 a0, b0, a1, b1;
      if (t < 2) {
        a0 = cvtpk(sc0[jA * 4 + 0], sc0[jA * 4 + 1]);
        b0 = cvtpk(sc0[jB * 4 + 0], sc0[jB * 4 + 1]);
        a1 = cvtpk(sc0[jA * 4 + 2], sc0[jA * 4 + 3]);
        b1 = cvtpk(sc0[jB * 4 + 2], sc0[jB * 4 + 3]);
      } else {
        a0 = cvtpk(sc1[jA * 4 + 0], sc1[jA * 4 + 1]);
        b0 = cvtpk(sc1[jB * 4 + 0], sc1[jB * 4 + 1]);
        a1 = cvtpk(sc1[jA * 4 + 2], sc1[jA * 4 + 3]);
        b1 = cvtpk(sc1[jB * 4 + 2], sc1[jB * 4 + 3]);
      }
      pl32swap(a0, b0); pl32swap(a1, b1);
      union { u32 w[4]; bf16x8 v; } pf;
      pf.w[0] = a0; pf.w[1] = a1; pf.w[2] = b0; pf.w[3] = b1;
      __builtin_amdgcn_s_setprio(1);
      #pragma unroll
      for (int db = 0; db < 4; db++) {
        bf16x8 aV = *(bf16x8*)&VtC[(db * 32 + l31) * 64 + (((t * 2 + h) * 8) ^ (l7 << 3))];
        accO[db] = MFMA32(aV, pf.v, accO[db]);
      }
      __builtin_amdgcn_s_setprio(0);
    }

    if (pfch) {
      const int nb = cur ^ 1;
      #pragma unroll
      for (int i = 0; i < 4; i++) {
        *(bf16x8*)&Kt[nb][rk[i] * 128 + cks[i]] = kreg[i];
        *(bf16x8*)&Vtt[nb][rv[i] * 64 + cvs[i]] = vreg[i];
      }
    }
    __syncthreads();
    cur ^= 1;
  }

  const size_t pbase = ((size_t)(ty * SEG + seg) * N + q) * 128;
  #pragma unroll
  for (int d = 0; d < 4; d++)
    #pragma unroll
    for (int j = 0; j < 4; j++) {
      bf16x4 o4;
      #pragma unroll
      for (int r = 0; r < 4; r++) o4[r] = (short)f2bf(accO[d][j * 4 + r]);
      *(bf16x4*)(part_acc + pbase + d * 32 + j * 8 + h * 4) = o4;
    }
  if (h == 0) {
    float2 ml; ml.x = m_; ml.y = l_;
    *(float2*)(part_ml + ((size_t)(ty * SEG + seg) * N + q) * 2) = ml;
  }
}

// combine SEG partials -> o-tile in LDS, then h = o @ outW^T + outB (fused).
__global__ __launch_bounds__(256) void combine_hproj_kernel(
    const u16* __restrict__ part_acc, const float* __restrict__ part_ml,
    const u16* __restrict__ woutA, const float* __restrict__ boutA, u16* __restrict__ hA,
    const u16* __restrict__ woutB, const float* __restrict__ boutB, u16* __restrict__ hB,
    int N, int SEG)
{
  __shared__ __align__(16) u16 ot[64 * 136];
  const int t = blockIdx.y;
  const u16* w = t ? woutB : woutA;
  const float* bb = t ? boutB : boutA;
  u16* hOut = t ? hB : hA;
  const int tid = threadIdx.x;
  const int row = tid >> 2, qt = tid & 3;
  const int grow = blockIdx.x * 64 + row;
  const float C = 0.088388347648318447f * 1.4426950408889634f;

  float m = -INFINITY;
  for (int s = 0; s < SEG; s++)
    m = fmaxf(m, part_ml[((size_t)(t * SEG + s) * N + grow) * 2]);
  float l = 0.f;
  float acc[32];
  #pragma unroll
  for (int i = 0; i < 32; i++) acc[i] = 0.f;
  for (int s = 0; s < SEG; s++) {
    const float* ml = part_ml + ((size_t)(t * SEG + s) * N + grow) * 2;
    float w8 = __builtin_exp2f((ml[0] - m) * C);
    l += w8 * ml[1];
    const u16* pa = part_acc + ((size_t)(t * SEG + s) * N + grow) * 128 + qt * 32;
    #pragma unroll
    for (int j = 0; j < 4; j++) {
      bf16x8 vch = *(const bf16x8*)(pa + j * 8);
      #pragma unroll
      for (int i = 0; i < 8; i++) acc[j * 8 + i] += w8 * bf2f((u16)vch[i]);
    }
  }
  const float inv = 1.f / l;
  #pragma unroll
  for (int j = 0; j < 4; j++) {
    bf16x8 oc;
    #pragma unroll
    for (int i = 0; i < 8; i++) oc[i] = (short)f2bf(acc[j * 8 + i] * inv);
    *(bf16x8*)&ot[row * 136 + qt * 32 + j * 8] = oc;
  }
  __syncthreads();

  const int lane = tid & 63, wid = tid >> 6;
  const int g = lane >> 4, l15 = lane & 15;
  const int row0 = wid * 16;
  bf16x8 a[4];
  #pragma unroll
  for (int kk = 0; kk < 4; kk++) a[kk] = *(bf16x8*)&ot[(row0 + l15) * 136 + kk * 32 + g * 8];
  const f32x4 fz = {0.f, 0.f, 0.f, 0.f};
  for (int j0 = 0; j0 < 128; j0 += 16) {
    f32x4 acc2 = fz;
    const u16* wr_ = w + (size_t)(j0 + l15) * 128;
    #pragma unroll
    for (int kk = 0; kk < 4; kk++)
      acc2 = MFMA(a[kk], *(const bf16x8*)(wr_ + kk * 32 + g * 8), acc2);
    float bv = bb[j0 + l15];
    #pragma unroll
    for (int r = 0; r < 4; r++)
      hOut[(size_t)(blockIdx.x * 64 + row0 + g * 4 + r) * 128 + j0 + l15] = f2bf(acc2[r] + bv);
  }
}

__global__ __launch_bounds__(1024) void scan_kernel(
    const int* __restrict__ cnt, int* __restrict__ off, int* __restrict__ work, int Nn)
{
  const int t = blockIdx.x;
  const int* c = cnt + t * Nn;
  int* o = off + t * (Nn + 1);
  int* w = work + t * Nn;
  __shared__ int part[1024];
  const int tid = threadIdx.x;
  const int base = tid * 8;
  int loc[8], s = 0;
  #pragma unroll
  for (int i = 0; i < 8; i++) { loc[i] = s; s += c[base + i]; }
  part[tid] = s;
  __syncthreads();
  #pragma unroll
  for (int st = 1; st < 1024; st <<= 1) {
    int v = (tid >= st) ? part[tid - st] : 0;
    __syncthreads();
    part[tid] += v;
    __syncthreads();
  }
  int pre = (tid == 0) ? 0 : part[tid - 1];
  #pragma unroll
  for (int i = 0; i < 8; i++) { int p = pre + loc[i]; o[base + i] = p; w[base + i] = p; }
  if (tid == 1023) o[Nn] = part[1023];
}

__global__ __launch_bounds__(256) void sortedges_kernel(
    const int* __restrict__ e0, const int* __restrict__ e1, const int* __restrict__ e2,
    int* __restrict__ work, int* __restrict__ ssrc, int Nn, int E)
{
  const int t = blockIdx.y;
  const int* ei = t == 0 ? e0 : (t == 1 ? e1 : e2);
  int e = blockIdx.x * 256 + threadIdx.x;
  if (e >= E) return;
  int s = ei[e], d = ei[E + e];
  int pos = atomicAdd(&work[t * Nn + d], 1);
  ssrc[(size_t)t * E + pos] = s;
}

// one wave per 1 of 4 destinations/block: sum h[src] rows -> agg row (bf16), single write
__global__ __launch_bounds__(256) void aggregate_kernel(
    const u16* __restrict__ h0, const u16* __restrict__ h1, const u16* __restrict__ h2,
    const int* __restrict__ off, const int* __restrict__ ssrc,
    u16* __restrict__ agg, int Nn, int E)
{
  const int t = blockIdx.y;
  const u16* h = t == 0 ? h0 : (t == 1 ? h1 : h2);
  const int* o = off + t * (Nn + 1);
  const int* ss = ssrc + (size_t)t * E;
  u16* a = agg + (size_t)t * Nn * 128;
  const int wid = threadIdx.x >> 6, lane = threadIdx.x & 63;
  const int d = blockIdx.x * 4 + wid;
  const int s0 = o[d], s1 = o[d + 1];
  float a0 = 0.f, a1 = 0.f;
  int e = s0;
  for (; e + 3 < s1; e += 4) {
    int r0 = ss[e], r1 = ss[e + 1], r2 = ss[e + 2], r3 = ss[e + 3];
    u32 v0 = *(const u32*)(h + (size_t)r0 * 128 + lane * 2);
    u32 v1 = *(const u32*)(h + (size_t)r1 * 128 + lane * 2);
    u32 v2 = *(const u32*)(h + (size_t)r2 * 128 + lane * 2);
    u32 v3 = *(const u32*)(h + (size_t)r3 * 128 + lane * 2);
    a0 += bf2f((u16)(v0 & 0xffff)) + bf2f((u16)(v1 & 0xffff)) + bf2f((u16)(v2 & 0xffff)) + bf2f((u16)(v3 & 0xffff));
    a1 += bf2f((u16)(v0 >> 16)) + bf2f((u16)(v1 >> 16)) + bf2f((u16)(v2 >> 16)) + bf2f((u16)(v3 >> 16));
  }
  for (; e < s1; e++) {
    u32 v = *(const u32*)(h + (size_t)ss[e] * 128 + lane * 2);
    a0 += bf2f((u16)(v & 0xffff));
    a1 += bf2f((u16)(v >> 16));
  }
  *(u32*)(a + (size_t)d * 128 + lane * 2) = cvtpk(a0, a1);
}

// out[:,0,:] (f32) = agg1@wl1^T + bl1 + h1@wr1^T (+ agg2@wl2^T + bl2 + h2@wr2^T); all operands bf16
__global__ __launch_bounds__(256) void sage_out_kernel(
    const u16* __restrict__ agg1, const u16* __restrict__ wl1, const float* __restrict__ bl1,
    const u16* __restrict__ h1, const u16* __restrict__ wr1,
    const u16* __restrict__ agg2, const u16* __restrict__ wl2, const float* __restrict__ bl2,
    const u16* __restrict__ h2, const u16* __restrict__ wr2,
    float* __restrict__ out)
{
  const int lane = threadIdx.x & 63, wid = threadIdx.x >> 6;
  const int g = lane >> 4, l15 = lane & 15;
  const int row0 = blockIdx.x * 64 + wid * 16;
  const bool two = (agg2 != nullptr);

  bf16x8 a1[4], aH1[4], a2[4], aH2[4];
  const u16* ar1 = agg1 + (size_t)(row0 + l15) * 128;
  const u16* hr1 = h1 + (size_t)(row0 + l15) * 128;
  #pragma unroll
  for (int kk = 0; kk < 4; kk++) {
    a1[kk] = *(const bf16x8*)(ar1 + kk * 32 + g * 8);
    aH1[kk] = *(const bf16x8*)(hr1 + kk * 32 + g * 8);
  }
  if (two) {
    const u16* ar2 = agg2 + (size_t)(row0 + l15) * 128;
    const u16* hr2 = h2 + (size_t)(row0 + l15) * 128;
    #pragma unroll
    for (int kk = 0; kk < 4; kk++) {
      a2[kk] = *(const bf16x8*)(ar2 + kk * 32 + g * 8);
      aH2[kk] = *(const bf16x8*)(hr2 + kk * 32 + g * 8);
    }
  }

  const f32x4 fz = {0.f, 0.f, 0.f, 0.f};
  for (int j0 = 0; j0 < 128; j0 += 16) {
    f32x4 acc = fz;
    const u16* w1 = wl1 + (size_t)(j0 + l15) * 128;
    const u16* w2 = wr1 + (size_t)(j0 + l15) * 128;
    #pragma unroll
    for (int kk = 0; kk < 4; kk++) {
      acc = MFMA(a1[kk], *(const bf16x8*)(w1 + kk * 32 + g * 8), acc);
      acc = MFMA(aH1[kk], *(const bf16x8*)(w2 + kk * 32 + g * 8), acc);
    }
    float bias = bl1[j0 + l15];
    if (two) {
      const u16* w3 = wl2 + (size_t)(j0 + l15) * 128;
      const u16* w4 = wr2 + (size_t)(j0 + l15) * 128;
      #pragma unroll
      for (int kk = 0; kk < 4; kk++) {
        acc = MFMA(a2[kk], *(const bf16x8*)(w3 + kk * 32 + g * 8), acc);
        acc = MFMA(aH2[kk], *(const bf16x8*)(w4 + kk * 32 + g * 8), acc);
      }
      bias += bl2[j0 + l15];
    }
    #pragma unroll
    for (int r = 0; r < 4; r++)
      out[(size_t)(row0 + g * 4 + r) * 768 + j0 + l15] = acc[r] + bias;
  }
}

extern "C" void kernel_launch(void* const* d_in, const int* in_sizes, int n_in,
                              void* d_out, int out_size, void* d_ws, size_t ws_size,
                              hipStream_t stream)
{
  const int D = 128, C = 6;
  const int N = in_sizes[0] / (C * D);   // 8192
  const int E = in_sizes[2] / 2;         // 262144

  const float* xA = (const float*)d_in[0];
  const float* xB = (const float*)d_in[1];
  const int* eiAB = (const int*)d_in[2];
  const int* eiBA = (const int*)d_in[3];
  const int* eiAA = (const int*)d_in[4];
  const float* inW_A  = (const float*)d_in[5];
  const float* inB_A  = (const float*)d_in[6];
  const float* outW_A = (const float*)d_in[7];
  const float* outB_A = (const float*)d_in[8];
  const float* inW_B  = (const float*)d_in[9];
  const float* inB_B  = (const float*)d_in[10];
  const float* outW_B = (const float*)d_in[11];
  const float* outB_B = (const float*)d_in[12];
  const float* wlAB = (const float*)d_in[13];
  const float* blAB = (const float*)d_in[14];
  const float* wrAB = (const float*)d_in[15];
  const float* wlBA = (const float*)d_in[16];
  const float* blBA = (const float*)d_in[17];
  const float* wrBA = (const float*)d_in[18];
  const float* wlAA = (const float*)d_in[19];
  const float* blAA = (const float*)d_in[20];
  const float* wrAA = (const float*)d_in[21];

  // ---- workspace carve ----
  u16* qkvA = (u16*)d_ws;
  u16* qkvB = qkvA + (size_t)N * 256;
  u16* vtA  = qkvB + (size_t)N * 256;
  u16* vtB  = vtA + (size_t)D * N;
  u16* hA   = vtB + (size_t)D * N;
  u16* hB   = hA + (size_t)N * D;
  u16* wbf  = hB + (size_t)N * D;        // bf16 weights
  const int wsz[10] = {3*D*D, 3*D*D, D*D, D*D, D*D, D*D, D*D, D*D, D*D, D*D};
  const float* wsrc[10] = {inW_A, inW_B, outW_A, outW_B, wlAB, wrAB, wlBA, wrBA, wlAA, wrAA};
  WPrepArgs wp; int wtot = 0;
  for (int k = 0; k < 10; k++) { wp.src[k] = wsrc[k]; wp.off[k] = wtot; wtot += wsz[k]; }
  wp.total4 = wtot / 4;
  u16* w_inA  = wbf + wp.off[0];
  u16* w_inB  = wbf + wp.off[1];
  u16* w_outA = wbf + wp.off[2];
  u16* w_outB = wbf + wp.off[3];
  u16* w_wlAB = wbf + wp.off[4];
  u16* w_wrAB = wbf + wp.off[5];
  u16* w_wlBA = wbf + wp.off[6];
  u16* w_wrBA = wbf + wp.off[7];
  u16* w_wlAA = wbf + wp.off[8];
  u16* w_wrAA = wbf + wp.off[9];

  // persistent sort scratch (written before flash, read after)
  int* cnt  = (int*)(wbf + wtot);        // 3*N
  int* off  = cnt + 3 * N;               // 3*(N+1)
  int* work = off + 3 * (N + 1);         // 3*N
  int* ssrc = work + 3 * N;              // 3*E
  // union region: flash partials (phase 1) OR bf16 agg (phase 2)
  char* uni = (char*)(ssrc + 3 * E);
  size_t base_b = (size_t)(uni - (char*)d_ws);
  size_t agg_b = (size_t)3 * N * 128 * 2;
  auto part_b = [&](int S){ return (size_t)2 * S * N * 128 * 2 + (size_t)2 * S * N * 2 * 4; };
  int SEG = 4;
  while (SEG > 1 && ws_size < base_b + (part_b(SEG) > agg_b ? part_b(SEG) : agg_b)) SEG >>= 1;
  const int segsz = N / SEG;
  u16* part_acc = (u16*)uni;
  float* part_ml = (float*)(part_acc + (size_t)2 * SEG * N * 128);
  u16* aggAB = (u16*)uni;
  u16* aggBA = aggAB + (size_t)N * D;
  u16* aggAA = aggBA + (size_t)N * D;

  float* outA = (float*)d_out;
  float* outB = outA + (size_t)N * C * D;

  dim3 blk(256);
  const int W = (wp.total4 + 255) / 256;
  const int HB = (E + 255) / 256;
  const int TB = (N * 160 + 255) / 256;
  // 0. zero histogram, then fused prelude: wprep + hist + tail copy
  (void)hipMemsetAsync(cnt, 0, (size_t)3 * N * sizeof(int), stream);
  prelude_kernel<<<dim3(W + 3 * HB + 2 * TB), blk, 0, stream>>>(
      wp, wbf, eiAB, eiBA, eiAA, cnt, xA, outA, xB, outB, N, E, W, HB, TB);
  // 1. edge sort chain (independent of h) runs early
  scan_kernel<<<dim3(3), dim3(1024), 0, stream>>>(cnt, off, work, N);
  sortedges_kernel<<<dim3(HB, 3), blk, 0, stream>>>(eiAB, eiBA, eiAA, work, ssrc, N, E);
  // 2. qkv = x0 @ inW^T + inB ; V written transposed into vt
  linear_kernel<0><<<dim3(N / 64, 2), blk, 0, stream>>>(xA, w_inA, inB_A, qkvA,
                                                        xB, w_inB, inB_B, qkvB,
                                                        vtA, vtB, C * D, 256, 384, N);
  // 3. flash attention partials
  flash_kernel<<<dim3(N / 128, SEG, 2), blk, 0, stream>>>(qkvA, vtA, qkvB, vtB,
                                                          part_acc, part_ml, N, segsz, SEG);
  // 4. combine partials + h-projection (fused)
  combine_hproj_kernel<<<dim3(N / 64, 2), blk, 0, stream>>>(part_acc, part_ml,
                                                            w_outA, outB_A, hA,
                                                            w_outB, outB_B, hB, N, SEG);
  // 5. aggregate (bf16 out; types: 0=AB(h=A), 1=BA(h=B), 2=AA(h=A))
  aggregate_kernel<<<dim3(N / 4, 3), blk, 0, stream>>>(hA, hB, hA, off, ssrc, aggAB, N, E);
  // 6. sage outputs into column 0 (f32)
  sage_out_kernel<<<dim3(N / 64), blk, 0, stream>>>(aggAB, w_wlAB, blAB, hB, w_wrAB,
                                                    nullptr, nullptr, nullptr, nullptr, nullptr, outB);
  sage_out_kernel<<<dim3(N / 64), blk, 0, stream>>>(aggBA, w_wlBA, blBA, hA, w_wrBA,
                                                    aggAA, w_wlAA, blAA, hA, w_wrAA, outA);
}

// Round 9
// 236.133 us; speedup vs baseline: 13.3383x; 1.1446x over previous
//
#include <hip/hip_runtime.h>
#include <hip/hip_bf16.h>

typedef unsigned short u16;
typedef unsigned int u32;
typedef __attribute__((ext_vector_type(8))) short bf16x8;
typedef __attribute__((ext_vector_type(4))) short bf16x4;
typedef __attribute__((ext_vector_type(4))) float f32x4;
typedef __attribute__((ext_vector_type(16))) float f32x16;

#define MFMA(a,b,c)   __builtin_amdgcn_mfma_f32_16x16x32_bf16((a),(b),(c),0,0,0)
#define MFMA32(a,b,c) __builtin_amdgcn_mfma_f32_32x32x16_bf16((a),(b),(c),0,0,0)

__device__ __forceinline__ float bf2f(u16 u){
  union { float f; u32 i; } c; c.i = ((u32)u) << 16; return c.f;
}
__device__ __forceinline__ u16 f2bf(float f){
  __hip_bfloat16 h = __float2bfloat16(f);
  u16 u; __builtin_memcpy(&u, &h, 2); return u;
}
__device__ __forceinline__ bf16x8 ld8f(const float* p){
  bf16x8 r;
  #pragma unroll
  for (int i = 0; i < 8; i++) r[i] = (short)f2bf(p[i]);
  return r;
}
__device__ __forceinline__ u32 cvtpk(float a, float b){
  u32 r; asm volatile("v_cvt_pk_bf16_f32 %0, %1, %2" : "=v"(r) : "v"(a), "v"(b)); return r;
}
__device__ __forceinline__ void pl32swap(u32 &a, u32 &b){
  asm volatile("v_permlane32_swap_b32 %0, %1" : "+v"(a), "+v"(b));
}

// scale * log2(e), folded into Q at projection time
#define QSCALE 0.12751741528681559f

// ---- prelude: wprep (f32->bf16 weights) + hist (3 types) + tail copy, one flat grid ----
struct WPrepArgs { const float* src[10]; int off[10]; int total4; };
__global__ __launch_bounds__(256) void prelude_kernel(
    WPrepArgs a, u16* __restrict__ wdst,
    const int* __restrict__ e0, const int* __restrict__ e1, const int* __restrict__ e2,
    int* __restrict__ cnt,
    const float* __restrict__ xA, float* __restrict__ outA,
    const float* __restrict__ xB, float* __restrict__ outB,
    int Nn, int E, int W, int HB, int TB)
{
  const int tid = threadIdx.x;
  int b = blockIdx.x;
  if (b < W) {                      // weight convert
    int i = b * 256 + tid;
    if (i >= a.total4) return;
    int e = i * 4;
    int j = 0;
    #pragma unroll
    for (int k = 1; k < 10; k++) if (e >= a.off[k]) j = k;
    f32x4 v = *(const f32x4*)(a.src[j] + (e - a.off[j]));
    bf16x4 o;
    #pragma unroll
    for (int r = 0; r < 4; r++) o[r] = (short)f2bf(v[r]);
    *(bf16x4*)(wdst + e) = o;
    return;
  }
  b -= W;
  if (b < 3 * HB) {                 // destination histogram
    int t = b / HB;
    int e = (b % HB) * 256 + tid;
    if (e >= E) return;
    const int* ei = t == 0 ? e0 : (t == 1 ? e1 : e2);
    atomicAdd(&cnt[t * Nn + ei[E + e]], 1);
    return;
  }
  b -= 3 * HB;
  {                                 // tail copy x[:,1:6,:] -> out[:,1:6,:]
    int t = b / TB;
    int idx = (b % TB) * 256 + tid;
    if (idx >= Nn * 160) return;
    const float* x = t ? xB : xA;
    float* o = t ? outB : outA;
    int n = idx / 160, r = idx % 160;
    size_t off = (size_t)n * 768 + 128 + (size_t)r * 4;
    *(f32x4*)(o + off) = *(const f32x4*)(x + off);
  }
}

// QKV projection (q pre-scaled by QSCALE, V written transposed) + 256-thread scan.
// grid = 2*LB + 3 ; blocks [0,2LB) do GEMM (x=b>>1, type=b&1), [2LB,2LB+3) do scan.
__global__ __launch_bounds__(256) void qkv_scan_kernel(
    const float* __restrict__ xA, const u16* __restrict__ wA, const float* __restrict__ bA, u16* __restrict__ yA,
    const float* __restrict__ xB, const u16* __restrict__ wB, const float* __restrict__ bB, u16* __restrict__ yB,
    u16* __restrict__ vtA_, u16* __restrict__ vtB_,
    const int* __restrict__ cnt, int* __restrict__ off, int* __restrict__ work,
    int Nn, int N, int LB)
{
  const int tid = threadIdx.x;
  int b = blockIdx.x;
  if (b >= 2 * LB) {
    // ---- exclusive scan, 256 threads, 32 bins each ----
    const int t = b - 2 * LB;
    const int* c = cnt + t * Nn;
    int* o = off + t * (Nn + 1);
    int* w = work + t * Nn;
    __shared__ int part[256];
    const int base = tid * 32;
    int loc[32], s = 0;
    #pragma unroll
    for (int i = 0; i < 32; i++) { loc[i] = s; s += c[base + i]; }
    part[tid] = s;
    __syncthreads();
    #pragma unroll
    for (int st = 1; st < 256; st <<= 1) {
      int v = (tid >= st) ? part[tid - st] : 0;
      __syncthreads();
      part[tid] += v;
      __syncthreads();
    }
    int pre = (tid == 0) ? 0 : part[tid - 1];
    #pragma unroll
    for (int i = 0; i < 32; i++) { int p = pre + loc[i]; o[base + i] = p; w[base + i] = p; }
    if (tid == 255) o[Nn] = part[255];
    return;
  }
  const int yb = b & 1, xb = b >> 1;
  const float* x = yb ? xB : xA;
  const u16* w = yb ? wB : wA;
  const float* bb = yb ? bB : bA;
  u16* y = yb ? yB : yA;
  u16* vt = yb ? vtB_ : vtA_;
  const int lane = tid & 63, wid = tid >> 6;
  const int g = lane >> 4, l15 = lane & 15;
  const int row0 = xb * 64 + wid * 16;

  bf16x8 a[4];
  const float* xr = x + (size_t)(row0 + l15) * 768;
  #pragma unroll
  for (int kk = 0; kk < 4; kk++) a[kk] = ld8f(xr + kk * 32 + g * 8);

  const f32x4 fz = {0.f, 0.f, 0.f, 0.f};
  for (int j0 = 0; j0 < 384; j0 += 16) {
    f32x4 acc = fz;
    const u16* wr_ = w + (size_t)(j0 + l15) * 128;
    #pragma unroll
    for (int kk = 0; kk < 4; kk++)
      acc = MFMA(a[kk], *(const bf16x8*)(wr_ + kk * 32 + g * 8), acc);
    float bv = bb[j0 + l15];
    if (j0 < 128) {        // Q block, pre-scaled
      #pragma unroll
      for (int r = 0; r < 4; r++)
        y[(size_t)(row0 + g * 4 + r) * 256 + j0 + l15] = f2bf((acc[r] + bv) * QSCALE);
    } else if (j0 < 256) { // K block
      #pragma unroll
      for (int r = 0; r < 4; r++)
        y[(size_t)(row0 + g * 4 + r) * 256 + j0 + l15] = f2bf(acc[r] + bv);
    } else {               // V block, transposed
      bf16x4 o4;
      #pragma unroll
      for (int r = 0; r < 4; r++) o4[r] = (short)f2bf(acc[r] + bv);
      *(bf16x4*)(vt + (size_t)(j0 - 256 + l15) * N + row0 + g * 4) = o4;
    }
  }
}

// Flash attention (software-pipelined QK(t+1) || softmax(t)+PV(t)) + sortedges tail-fill.
// Flash blocks [0,FB): K dbuf + V tri-buf (80KB LDS), 1 barrier/tile, 2 blocks/CU.
__global__ __launch_bounds__(256, 2) void flash_sort_kernel(
    const u16* __restrict__ qkvA, const u16* __restrict__ vtA,
    const u16* __restrict__ qkvB, const u16* __restrict__ vtB,
    u16* __restrict__ part_acc, float* __restrict__ part_ml,
    const int* __restrict__ e0, const int* __restrict__ e1, const int* __restrict__ e2,
    int* __restrict__ work, int* __restrict__ ssrc,
    int N, int segsz, int SEG, int NB128, int FB, int HB, int E)
{
  __shared__ __align__(16) u16 Kt[2][64 * 128];   // idx = r*128 + (c ^ ((r&7)<<3))
  __shared__ __align__(16) u16 Vtt[3][128 * 64];  // idx = r*64  + (c ^ ((r&7)<<3))
  const int tid = threadIdx.x;
  int b = blockIdx.x;
  if (b >= FB) {
    // ---- sortedges: scatter srcs into dst-sorted order ----
    int sb = b - FB;
    int t = sb / HB;
    int e = (sb % HB) * 256 + tid;
    if (e >= E) return;
    const int* ei = t == 0 ? e0 : (t == 1 ? e1 : e2);
    int s = ei[e], d = ei[E + e];
    int pos = atomicAdd(&work[t * N + d], 1);
    ssrc[(size_t)t * E + pos] = s;
    return;
  }
  const int x = b % NB128;
  const int rest = b / NB128;
  const int seg = rest % SEG;
  const int ty = rest / SEG;
  const u16* qkv = ty ? qkvB : qkvA;
  const u16* vt  = ty ? vtB  : vtA;
  const int lane = tid & 63, wid = tid >> 6;
  const int l31 = lane & 31, h = lane >> 5, l7 = lane & 7;
  const int q = x * 128 + wid * 32 + l31;
  const int kvbase = seg * segsz;
  const int nt = segsz >> 6;   // tiles of 64; always even (N=8192, SEG in {1,2,4})

  int rk[4], ck[4], cks[4], rv[4], cv[4], cvs[4];
  #pragma unroll
  for (int i = 0; i < 4; i++) {
    int ch = tid + i * 256;
    rk[i] = ch >> 4; ck[i] = (ch & 15) * 8; cks[i] = ck[i] ^ ((rk[i] & 7) << 3);
    rv[i] = ch >> 3; cv[i] = (ch & 7) * 8;  cvs[i] = cv[i] ^ ((rv[i] & 7) << 3);
  }

  bf16x8 aQ[8];
  const u16* qr = qkv + (size_t)q * 256;
  #pragma unroll
  for (int kk = 0; kk < 8; kk++) aQ[kk] = *(const bf16x8*)(qr + kk * 16 + h * 8);

  f32x16 accO[4];
  #pragma unroll
  for (int d = 0; d < 4; d++) accO[d] = (f32x16)0.f;
  float m_ = -INFINITY, l_ = 0.f;
  f32x16 scA[2], scB[2];
  bf16x8 kreg[4], vreg[4];

  // prologue: stage tile 0, QK(0) -> scA, issue loads tile 1
  #pragma unroll
  for (int i = 0; i < 4; i++) {
    kreg[i] = *(const bf16x8*)(qkv + 128 + (size_t)(kvbase + rk[i]) * 256 + ck[i]);
    vreg[i] = *(const bf16x8*)(vt + (size_t)rv[i] * N + kvbase + cv[i]);
  }
  #pragma unroll
  for (int i = 0; i < 4; i++) {
    *(bf16x8*)&Kt[0][rk[i] * 128 + cks[i]] = kreg[i];
    *(bf16x8*)&Vtt[0][rv[i] * 64 + cvs[i]] = vreg[i];
  }
  __syncthreads();
  if (nt > 1) {
    const int kv1 = kvbase + 64;
    #pragma unroll
    for (int i = 0; i < 4; i++) {
      kreg[i] = *(const bf16x8*)(qkv + 128 + (size_t)(kv1 + rk[i]) * 256 + ck[i]);
      vreg[i] = *(const bf16x8*)(vt + (size_t)rv[i] * N + kv1 + cv[i]);
    }
  }
  scA[0] = (f32x16)0.f; scA[1] = (f32x16)0.f;
  #pragma unroll
  for (int kk = 0; kk < 8; kk++) {
    const int co = ((kk * 2 + h) * 8) ^ (l7 << 3);
    bf16x8 aK0 = *(bf16x8*)&Kt[0][l31 * 128 + co];
    bf16x8 aK1 = *(bf16x8*)&Kt[0][(32 + l31) * 128 + co];
    scA[0] = MFMA32(aK0, aQ[kk], scA[0]);
    scA[1] = MFMA32(aK1, aQ[kk], scA[1]);
  }

  int t = 0, vb = 0;
  auto fstep = [&](f32x16* scIn, f32x16* scOut) {
    const bool hasN = (t + 1 < nt);
    const int kbN = (t + 1) & 1;
    const int vbN = (vb + 1 == 3) ? 0 : vb + 1;
    if (hasN) {
      #pragma unroll
      for (int i = 0; i < 4; i++) {
        *(bf16x8*)&Kt[kbN][rk[i] * 128 + cks[i]] = kreg[i];
        *(bf16x8*)&Vtt[vbN][rv[i] * 64 + cvs[i]] = vreg[i];
      }
    }
    __syncthreads();
    if (t + 2 < nt) {
      const int kv0n = kvbase + (t + 2) * 64;
      #pragma unroll
      for (int i = 0; i < 4; i++) {
        kreg[i] = *(const bf16x8*)(qkv + 128 + (size_t)(kv0n + rk[i]) * 256 + ck[i]);
        vreg[i] = *(const bf16x8*)(vt + (size_t)rv[i] * N + kv0n + cv[i]);
      }
    }
    // QK(t+1) -> scOut ; overlaps with softmax(t) below (independent)
    if (hasN) {
      scOut[0] = (f32x16)0.f; scOut[1] = (f32x16)0.f;
      #pragma unroll
      for (int kk = 0; kk < 8; kk++) {
        const int co = ((kk * 2 + h) * 8) ^ (l7 << 3);
        bf16x8 aK0 = *(bf16x8*)&Kt[kbN][l31 * 128 + co];
        bf16x8 aK1 = *(bf16x8*)&Kt[kbN][(32 + l31) * 128 + co];
        scOut[0] = MFMA32(aK0, aQ[kk], scOut[0]);
        scOut[1] = MFMA32(aK1, aQ[kk], scOut[1]);
      }
    }
    // softmax(t) on scIn — Q pre-scaled, pure exp2 domain
    float pmax = scIn[0][0];
    #pragma unroll
    for (int i = 1; i < 16; i++) pmax = fmaxf(pmax, scIn[0][i]);
    #pragma unroll
    for (int i = 0; i < 16; i++) pmax = fmaxf(pmax, scIn[1][i]);
    pmax = fmaxf(pmax, __shfl_xor(pmax, 32));
    if (!__all(pmax - m_ <= 8.0f)) {
      float nm = fmaxf(m_, pmax);
      float corr = __builtin_exp2f(m_ - nm);
      m_ = nm; l_ *= corr;
      #pragma unroll
      for (int d = 0; d < 4; d++)
        #pragma unroll
        for (int i = 0; i < 16; i++) accO[d][i] *= corr;
    }
    float sum = 0.f;
    #pragma unroll
    for (int i = 0; i < 16; i++) {
      float e0 = __builtin_exp2f(scIn[0][i] - m_);
      float e1 = __builtin_exp2f(scIn[1][i] - m_);
      scIn[0][i] = e0; scIn[1][i] = e1; sum += e0 + e1;
    }
    sum += __shfl_xor(sum, 32);
    l_ += sum;
    // PV(t) from Vtt[vb]
    #pragma unroll
    for (int tt = 0; tt < 4; tt++) {
      const f32x16& s_ = scIn[tt >> 1];
      const int jA = (tt & 1) * 2, jB = jA + 1;
      u32 a0 = cvtpk(s_[jA * 4 + 0], s_[jA * 4 + 1]);
      u32 b0 = cvtpk(s_[jB * 4 + 0], s_[jB * 4 + 1]);
      u32 a1 = cvtpk(s_[jA * 4 + 2], s_[jA * 4 + 3]);
      u32 b1 = cvtpk(s_[jB * 4 + 2], s_[jB * 4 + 3]);
      pl32swap(a0, b0); pl32swap(a1, b1);
      union { u32 w[4]; bf16x8 v; } pf;
      pf.w[0] = a0; pf.w[1] = a1; pf.w[2] = b0; pf.w[3] = b1;
      #pragma unroll
      for (int db = 0; db < 4; db++) {
        bf16x8 aV = *(bf16x8*)&Vtt[vb][(db * 32 + l31) * 64 + (((tt * 2 + h) * 8) ^ (l7 << 3))];
        accO[db] = MFMA32(aV, pf.v, accO[db]);
      }
    }
    vb = vbN; ++t;
  };
  while (t < nt) { fstep(scA, scB); fstep(scB, scA); }

  const size_t pbase = ((size_t)(ty * SEG + seg) * N + q) * 128;
  #pragma unroll
  for (int d = 0; d < 4; d++)
    #pragma unroll
    for (int j = 0; j < 4; j++) {
      bf16x4 o4;
      #pragma unroll
      for (int r = 0; r < 4; r++) o4[r] = (short)f2bf(accO[d][j * 4 + r]);
      *(bf16x4*)(part_acc + pbase + d * 32 + j * 8 + h * 4) = o4;
    }
  if (h == 0) {
    float2 ml; ml.x = m_; ml.y = l_;
    *(float2*)(part_ml + ((size_t)(ty * SEG + seg) * N + q) * 2) = ml;
  }
}

// combine SEG partials -> o-tile in LDS, then h = o @ outW^T + outB (fused).
__global__ __launch_bounds__(256) void combine_hproj_kernel(
    const u16* __restrict__ part_acc, const float* __restrict__ part_ml,
    const u16* __restrict__ woutA, const float* __restrict__ boutA, u16* __restrict__ hA,
    const u16* __restrict__ woutB, const float* __restrict__ boutB, u16* __restrict__ hB,
    int N, int SEG)
{
  __shared__ __align__(16) u16 ot[64 * 136];
  const int t = blockIdx.y;
  const u16* w = t ? woutB : woutA;
  const float* bb = t ? boutB : boutA;
  u16* hOut = t ? hB : hA;
  const int tid = threadIdx.x;
  const int row = tid >> 2, qt = tid & 3;
  const int grow = blockIdx.x * 64 + row;

  float m = -INFINITY;
  for (int s = 0; s < SEG; s++)
    m = fmaxf(m, part_ml[((size_t)(t * SEG + s) * N + grow) * 2]);
  float l = 0.f;
  float acc[32];
  #pragma unroll
  for (int i = 0; i < 32; i++) acc[i] = 0.f;
  for (int s = 0; s < SEG; s++) {
    const float* ml = part_ml + ((size_t)(t * SEG + s) * N + grow) * 2;
    float w8 = __builtin_exp2f(ml[0] - m);   // scaled domain
    l += w8 * ml[1];
    const u16* pa = part_acc + ((size_t)(t * SEG + s) * N + grow) * 128 + qt * 32;
    #pragma unroll
    for (int j = 0; j < 4; j++) {
      bf16x8 vch = *(const bf16x8*)(pa + j * 8);
      #pragma unroll
      for (int i = 0; i < 8; i++) acc[j * 8 + i] += w8 * bf2f((u16)vch[i]);
    }
  }
  const float inv = 1.f / l;
  #pragma unroll
  for (int j = 0; j < 4; j++) {
    bf16x8 oc;
    #pragma unroll
    for (int i = 0; i < 8; i++) oc[i] = (short)f2bf(acc[j * 8 + i] * inv);
    *(bf16x8*)&ot[row * 136 + qt * 32 + j * 8] = oc;
  }
  __syncthreads();

  const int lane = tid & 63, wid = tid >> 6;
  const int g = lane >> 4, l15 = lane & 15;
  const int row0 = wid * 16;
  bf16x8 a[4];
  #pragma unroll
  for (int kk = 0; kk < 4; kk++) a[kk] = *(bf16x8*)&ot[(row0 + l15) * 136 + kk * 32 + g * 8];
  const f32x4 fz = {0.f, 0.f, 0.f, 0.f};
  for (int j0 = 0; j0 < 128; j0 += 16) {
    f32x4 acc2 = fz;
    const u16* wr_ = w + (size_t)(j0 + l15) * 128;
    #pragma unroll
    for (int kk = 0; kk < 4; kk++)
      acc2 = MFMA(a[kk], *(const bf16x8*)(wr_ + kk * 32 + g * 8), acc2);
    float bv = bb[j0 + l15];
    #pragma unroll
    for (int r = 0; r < 4; r++)
      hOut[(size_t)(blockIdx.x * 64 + row0 + g * 4 + r) * 128 + j0 + l15] = f2bf(acc2[r] + bv);
  }
}

// one wave per 1 of 4 destinations/block: sum h[src] rows -> agg row (bf16), single write
__global__ __launch_bounds__(256) void aggregate_kernel(
    const u16* __restrict__ h0, const u16* __restrict__ h1, const u16* __restrict__ h2,
    const int* __restrict__ off, const int* __restrict__ ssrc,
    u16* __restrict__ agg, int Nn, int E)
{
  const int t = blockIdx.y;
  const u16* h = t == 0 ? h0 : (t == 1 ? h1 : h2);
  const int* o = off + t * (Nn + 1);
  const int* ss = ssrc + (size_t)t * E;
  u16* a = agg + (size_t)t * Nn * 128;
  const int wid = threadIdx.x >> 6, lane = threadIdx.x & 63;
  const int d = blockIdx.x * 4 + wid;
  const int s0 = o[d], s1 = o[d + 1];
  float a0 = 0.f, a1 = 0.f;
  int e = s0;
  for (; e + 3 < s1; e += 4) {
    int r0 = ss[e], r1 = ss[e + 1], r2 = ss[e + 2], r3 = ss[e + 3];
    u32 v0 = *(const u32*)(h + (size_t)r0 * 128 + lane * 2);
    u32 v1 = *(const u32*)(h + (size_t)r1 * 128 + lane * 2);
    u32 v2 = *(const u32*)(h + (size_t)r2 * 128 + lane * 2);
    u32 v3 = *(const u32*)(h + (size_t)r3 * 128 + lane * 2);
    a0 += bf2f((u16)(v0 & 0xffff)) + bf2f((u16)(v1 & 0xffff)) + bf2f((u16)(v2 & 0xffff)) + bf2f((u16)(v3 & 0xffff));
    a1 += bf2f((u16)(v0 >> 16)) + bf2f((u16)(v1 >> 16)) + bf2f((u16)(v2 >> 16)) + bf2f((u16)(v3 >> 16));
  }
  for (; e < s1; e++) {
    u32 v = *(const u32*)(h + (size_t)ss[e] * 128 + lane * 2);
    a0 += bf2f((u16)(v & 0xffff));
    a1 += bf2f((u16)(v >> 16));
  }
  *(u32*)(a + (size_t)d * 128 + lane * 2) = cvtpk(a0, a1);
}

// merged sage epilogue: blockIdx.y==0 -> outB (1 term); ==1 -> outA (2 terms); bf16 operands
__global__ __launch_bounds__(256) void sage_out_kernel(
    const u16* __restrict__ aggAB, const u16* __restrict__ wlAB, const float* __restrict__ blAB,
    const u16* __restrict__ hB, const u16* __restrict__ wrAB,
    const u16* __restrict__ aggBA, const u16* __restrict__ wlBA, const float* __restrict__ blBA,
    const u16* __restrict__ hA, const u16* __restrict__ wrBA,
    const u16* __restrict__ aggAA, const u16* __restrict__ wlAA, const float* __restrict__ blAA,
    const u16* __restrict__ wrAA,
    float* __restrict__ outA, float* __restrict__ outB)
{
  const bool two = (blockIdx.y == 1);
  const u16* agg1 = two ? aggBA : aggAB;
  const u16* wl1  = two ? wlBA  : wlAB;
  const float* bl1 = two ? blBA : blAB;
  const u16* h1   = two ? hA : hB;
  const u16* wr1  = two ? wrBA : wrAB;
  float* out = two ? outA : outB;

  const int lane = threadIdx.x & 63, wid = threadIdx.x >> 6;
  const int g = lane >> 4, l15 = lane & 15;
  const int row0 = blockIdx.x * 64 + wid * 16;

  bf16x8 a1[4], aH1[4], a2[4];
  const u16* ar1 = agg1 + (size_t)(row0 + l15) * 128;
  const u16* hr1 = h1 + (size_t)(row0 + l15) * 128;
  #pragma unroll
  for (int kk = 0; kk < 4; kk++) {
    a1[kk] = *(const bf16x8*)(ar1 + kk * 32 + g * 8);
    aH1[kk] = *(const bf16x8*)(hr1 + kk * 32 + g * 8);
  }
  if (two) {
    const u16* ar2 = aggAA + (size_t)(row0 + l15) * 128;
    #pragma unroll
    for (int kk = 0; kk < 4; kk++)
      a2[kk] = *(const bf16x8*)(ar2 + kk * 32 + g * 8);
  }

  const f32x4 fz = {0.f, 0.f, 0.f, 0.f};
  for (int j0 = 0; j0 < 128; j0 += 16) {
    f32x4 acc = fz;
    const u16* w1 = wl1 + (size_t)(j0 + l15) * 128;
    const u16* w2 = wr1 + (size_t)(j0 + l15) * 128;
    #pragma unroll
    for (int kk = 0; kk < 4; kk++) {
      acc = MFMA(a1[kk], *(const bf16x8*)(w1 + kk * 32 + g * 8), acc);
      acc = MFMA(aH1[kk], *(const bf16x8*)(w2 + kk * 32 + g * 8), acc);
    }
    float bias = bl1[j0 + l15];
    if (two) {
      const u16* w3 = wlAA + (size_t)(j0 + l15) * 128;
      const u16* w4 = wrAA + (size_t)(j0 + l15) * 128;
      #pragma unroll
      for (int kk = 0; kk < 4; kk++) {
        acc = MFMA(a2[kk], *(const bf16x8*)(w3 + kk * 32 + g * 8), acc);
        acc = MFMA(aH1[kk], *(const bf16x8*)(w4 + kk * 32 + g * 8), acc);
      }
      bias += blAA[j0 + l15];
    }
    #pragma unroll
    for (int r = 0; r < 4; r++)
      out[(size_t)(row0 + g * 4 + r) * 768 + j0 + l15] = acc[r] + bias;
  }
}

extern "C" void kernel_launch(void* const* d_in, const int* in_sizes, int n_in,
                              void* d_out, int out_size, void* d_ws, size_t ws_size,
                              hipStream_t stream)
{
  const int D = 128, C = 6;
  const int N = in_sizes[0] / (C * D);   // 8192
  const int E = in_sizes[2] / 2;         // 262144

  const float* xA = (const float*)d_in[0];
  const float* xB = (const float*)d_in[1];
  const int* eiAB = (const int*)d_in[2];
  const int* eiBA = (const int*)d_in[3];
  const int* eiAA = (const int*)d_in[4];
  const float* inW_A  = (const float*)d_in[5];
  const float* inB_A  = (const float*)d_in[6];
  const float* outW_A = (const float*)d_in[7];
  const float* outB_A = (const float*)d_in[8];
  const float* inW_B  = (const float*)d_in[9];
  const float* inB_B  = (const float*)d_in[10];
  const float* outW_B = (const float*)d_in[11];
  const float* outB_B = (const float*)d_in[12];
  const float* wlAB = (const float*)d_in[13];
  const float* blAB = (const float*)d_in[14];
  const float* wrAB = (const float*)d_in[15];
  const float* wlBA = (const float*)d_in[16];
  const float* blBA = (const float*)d_in[17];
  const float* wrBA = (const float*)d_in[18];
  const float* wlAA = (const float*)d_in[19];
  const float* blAA = (const float*)d_in[20];
  const float* wrAA = (const float*)d_in[21];

  // ---- workspace carve ----
  u16* qkvA = (u16*)d_ws;
  u16* qkvB = qkvA + (size_t)N * 256;
  u16* vtA  = qkvB + (size_t)N * 256;
  u16* vtB  = vtA + (size_t)D * N;
  u16* hA   = vtB + (size_t)D * N;
  u16* hB   = hA + (size_t)N * D;
  u16* wbf  = hB + (size_t)N * D;        // bf16 weights
  const int wsz[10] = {3*D*D, 3*D*D, D*D, D*D, D*D, D*D, D*D, D*D, D*D, D*D};
  const float* wsrc[10] = {inW_A, inW_B, outW_A, outW_B, wlAB, wrAB, wlBA, wrBA, wlAA, wrAA};
  WPrepArgs wp; int wtot = 0;
  for (int k = 0; k < 10; k++) { wp.src[k] = wsrc[k]; wp.off[k] = wtot; wtot += wsz[k]; }
  wp.total4 = wtot / 4;
  u16* w_inA  = wbf + wp.off[0];
  u16* w_inB  = wbf + wp.off[1];
  u16* w_outA = wbf + wp.off[2];
  u16* w_outB = wbf + wp.off[3];
  u16* w_wlAB = wbf + wp.off[4];
  u16* w_wrAB = wbf + wp.off[5];
  u16* w_wlBA = wbf + wp.off[6];
  u16* w_wrBA = wbf + wp.off[7];
  u16* w_wlAA = wbf + wp.off[8];
  u16* w_wrAA = wbf + wp.off[9];

  // persistent sort scratch
  int* cnt  = (int*)(wbf + wtot);        // 3*N
  int* off  = cnt + 3 * N;               // 3*(N+1)
  int* work = off + 3 * (N + 1);         // 3*N
  int* ssrc = work + 3 * N;              // 3*E
  // union region: flash partials (phase 1) OR bf16 agg (phase 2)
  char* uni = (char*)(ssrc + 3 * E);
  size_t base_b = (size_t)(uni - (char*)d_ws);
  size_t agg_b = (size_t)3 * N * 128 * 2;
  auto part_b = [&](int S){ return (size_t)2 * S * N * 128 * 2 + (size_t)2 * S * N * 2 * 4; };
  int SEG = 4;
  while (SEG > 1 && ws_size < base_b + (part_b(SEG) > agg_b ? part_b(SEG) : agg_b)) SEG >>= 1;
  const int segsz = N / SEG;
  u16* part_acc = (u16*)uni;
  float* part_ml = (float*)(part_acc + (size_t)2 * SEG * N * 128);
  u16* aggAB = (u16*)uni;
  u16* aggBA = aggAB + (size_t)N * D;
  u16* aggAA = aggBA + (size_t)N * D;

  float* outA = (float*)d_out;
  float* outB = outA + (size_t)N * C * D;

  dim3 blk(256);
  const int W = (wp.total4 + 255) / 256;
  const int HB = (E + 255) / 256;
  const int TB = (N * 160 + 255) / 256;
  const int LB = N / 64;
  const int NB128 = N / 128;
  const int FB = NB128 * SEG * 2;
  // 0. zero histogram, then fused prelude: wprep + hist + tail copy
  (void)hipMemsetAsync(cnt, 0, (size_t)3 * N * sizeof(int), stream);
  prelude_kernel<<<dim3(W + 3 * HB + 2 * TB), blk, 0, stream>>>(
      wp, wbf, eiAB, eiBA, eiAA, cnt, xA, outA, xB, outB, N, E, W, HB, TB);
  // 1. qkv projection (+ V^T, Q pre-scaled) with scan tail-merged
  qkv_scan_kernel<<<dim3(2 * LB + 3), blk, 0, stream>>>(
      xA, w_inA, inB_A, qkvA, xB, w_inB, inB_B, qkvB, vtA, vtB,
      cnt, off, work, N, N, LB);
  // 2. flash attention (pipelined) + sortedges tail-fill
  flash_sort_kernel<<<dim3(FB + 3 * HB), blk, 0, stream>>>(
      qkvA, vtA, qkvB, vtB, part_acc, part_ml,
      eiAB, eiBA, eiAA, work, ssrc, N, segsz, SEG, NB128, FB, HB, E);
  // 3. combine partials + h-projection (fused)
  combine_hproj_kernel<<<dim3(N / 64, 2), blk, 0, stream>>>(part_acc, part_ml,
                                                            w_outA, outB_A, hA,
                                                            w_outB, outB_B, hB, N, SEG);
  // 4. aggregate (bf16 out; types: 0=AB(h=A), 1=BA(h=B), 2=AA(h=A))
  aggregate_kernel<<<dim3(N / 4, 3), blk, 0, stream>>>(hA, hB, hA, off, ssrc, aggAB, N, E);
  // 5. merged sage outputs into column 0 (f32)
  sage_out_kernel<<<dim3(N / 64, 2), blk, 0, stream>>>(
      aggAB, w_wlAB, blAB, hB, w_wrAB,
      aggBA, w_wlBA, blBA, hA, w_wrBA,
      aggAA, w_wlAA, blAA, w_wrAA, outA, outB);
}